// Round 3
// baseline (2466.667 us; speedup 1.0000x reference)
//
#include <hip/hip_runtime.h>
#include <hip/hip_bf16.h>
#include <cstdint>

typedef unsigned short u16;
typedef __bf16 bf16x4_t __attribute__((ext_vector_type(4)));
typedef __bf16 bf16x8_t __attribute__((ext_vector_type(8)));
typedef float f32x4_t __attribute__((ext_vector_type(4)));
typedef unsigned short us4_t __attribute__((ext_vector_type(4)));

#define BATCH 2
#define SEQ 1024
#define HID 2048
#define NHEAD 32
#define NEXP 8
#define MDIM 1024
#define T_TOK (BATCH*SEQ)   // 2048

// ---------- helpers ----------

__device__ __forceinline__ void gload16(const void* g, void* l){
  __builtin_amdgcn_global_load_lds((__attribute__((address_space(1))) void*)(uintptr_t)g,
                                   (__attribute__((address_space(3))) void*)l, 16, 0, 0);
}

// 8-bf16 MFMA fragment as two b64 halves: k = fg*4+e and +16 (bijective k-map,
// used identically on A and B sides -> product invariant to the permutation).
__device__ __forceinline__ bf16x8_t ldfrag(const u16* lo){
  bf16x4_t a = *(const bf16x4_t*)lo;
  bf16x4_t b = *(const bf16x4_t*)(lo + 16);
  return __builtin_shufflevector(a, b, 0,1,2,3,4,5,6,7);
}

__device__ __forceinline__ f32x4_t mfma16(bf16x8_t a, bf16x8_t b, f32x4_t c){
  return __builtin_amdgcn_mfma_f32_16x16x32_bf16(a, b, c, 0, 0, 0);
}

__device__ __forceinline__ u16 f2b(float f){
  __hip_bfloat16 h = __float2bfloat16(f);
  return __builtin_bit_cast(u16, h);
}
__device__ __forceinline__ float b2f(u16 b){
  return __builtin_bit_cast(float, (unsigned int)b << 16);
}
// 3-way bf16 split: v ~= b1 + b2 + b3 with |residual| <= 2^-27 |v|
__device__ __forceinline__ void split3v(float v, u16& b1, u16& b2, u16& b3){
  b1 = f2b(v); float f1 = b2f(b1);
  float r1 = v - f1;
  b2 = f2b(r1); float f2 = b2f(b2);
  b3 = f2b(r1 - f2);
}

// ---------- weight convert+transpose (single bf16, MoE): f32 [R][C] -> bf16 [C][R] ----------

__global__ __launch_bounds__(256)
void convT(const float* __restrict__ in, u16* __restrict__ out, int R, int C)
{
  __shared__ float tile[32][33];
  int bz = blockIdx.z;
  const float* ip = in + (size_t)bz * R * C;
  u16* op = out + (size_t)bz * R * C;
  int tx = threadIdx.x, ty = threadIdx.y;   // block (32,8)
  int c0 = blockIdx.x*32, r0 = blockIdx.y*32;
  #pragma unroll
  for (int i = 0; i < 4; i++)
    tile[ty + i*8][tx] = ip[(size_t)(r0 + ty + i*8) * C + c0 + tx];
  __syncthreads();
  #pragma unroll
  for (int i = 0; i < 4; i++)
    op[(size_t)(c0 + ty + i*8) * R + r0 + tx] = f2b(tile[tx][ty + i*8]);
}

// ---------- weight convert+transpose, 3-way split (attention weights) ----------

__global__ __launch_bounds__(256)
void convT3(const float* __restrict__ in, u16* __restrict__ o1, u16* __restrict__ o2,
            u16* __restrict__ o3, int R, int C)
{
  __shared__ float tile[32][33];
  const float* ip = in;
  int tx = threadIdx.x, ty = threadIdx.y;
  int c0 = blockIdx.x*32, r0 = blockIdx.y*32;
  #pragma unroll
  for (int i = 0; i < 4; i++)
    tile[ty + i*8][tx] = ip[(size_t)(r0 + ty + i*8) * C + c0 + tx];
  __syncthreads();
  #pragma unroll
  for (int i = 0; i < 4; i++){
    u16 b1, b2, b3;
    split3v(tile[tx][ty + i*8], b1, b2, b3);
    size_t idx = (size_t)(c0 + ty + i*8) * R + r0 + tx;
    o1[idx] = b1; o2[idx] = b2; o3[idx] = b3;
  }
}

// ---------- RMSNorm -> 3-way split (attention input) ----------

__global__ __launch_bounds__(256)
void rmsnorm3_k(const float* __restrict__ x, const float* __restrict__ w,
                u16* __restrict__ o1, u16* __restrict__ o2, u16* __restrict__ o3)
{
  int row = blockIdx.x;
  const float* xr = x + (size_t)row * HID;
  int base = threadIdx.x * 8;
  float4 a = *(const float4*)(xr + base);
  float4 b = *(const float4*)(xr + base + 4);
  float ss = a.x*a.x + a.y*a.y + a.z*a.z + a.w*a.w
           + b.x*b.x + b.y*b.y + b.z*b.z + b.w*b.w;
  #pragma unroll
  for (int off = 32; off; off >>= 1) ss += __shfl_down(ss, off);
  __shared__ float red[4];
  if ((threadIdx.x & 63) == 0) red[threadIdx.x >> 6] = ss;
  __syncthreads();
  float tot = red[0] + red[1] + red[2] + red[3];
  float rs = (float)(1.0 / sqrt((double)tot * (1.0/2048.0) + 1e-5));
  float4 wa = *(const float4*)(w + base);
  float4 wb = *(const float4*)(w + base + 4);
  float o[8];
  o[0]=a.x*rs*wa.x; o[1]=a.y*rs*wa.y; o[2]=a.z*rs*wa.z; o[3]=a.w*rs*wa.w;
  o[4]=b.x*rs*wb.x; o[5]=b.y*rs*wb.y; o[6]=b.z*rs*wb.z; o[7]=b.w*rs*wb.w;
  us4_t v1[2], v2[2], v3[2];
  #pragma unroll
  for (int j = 0; j < 8; j++){
    u16 b1, b2, b3; split3v(o[j], b1, b2, b3);
    v1[j>>2][j&3] = b1; v2[j>>2][j&3] = b2; v3[j>>2][j&3] = b3;
  }
  size_t idx = (size_t)row*HID + base;
  *(us4_t*)&o1[idx] = v1[0]; *(us4_t*)&o1[idx+4] = v1[1];
  *(us4_t*)&o2[idx] = v2[0]; *(us4_t*)&o2[idx+4] = v2[1];
  *(us4_t*)&o3[idx] = v3[0]; *(us4_t*)&o3[idx+4] = v3[1];
}

// ---------- RMSNorm (MoE): bf16 out + f32 out ----------

__global__ __launch_bounds__(256)
void rmsnorm_k(const float* __restrict__ x, const float* __restrict__ w,
               u16* __restrict__ ob, float* __restrict__ of)
{
  int row = blockIdx.x;
  const float* xr = x + (size_t)row * HID;
  int base = threadIdx.x * 8;
  float4 a = *(const float4*)(xr + base);
  float4 b = *(const float4*)(xr + base + 4);
  float ss = a.x*a.x + a.y*a.y + a.z*a.z + a.w*a.w
           + b.x*b.x + b.y*b.y + b.z*b.z + b.w*b.w;
  #pragma unroll
  for (int off = 32; off; off >>= 1) ss += __shfl_down(ss, off);
  __shared__ float red[4];
  if ((threadIdx.x & 63) == 0) red[threadIdx.x >> 6] = ss;
  __syncthreads();
  float tot = red[0] + red[1] + red[2] + red[3];
  float rs = (float)(1.0 / sqrt((double)tot * (1.0/2048.0) + 1e-5));
  float4 wa = *(const float4*)(w + base);
  float4 wb = *(const float4*)(w + base + 4);
  float o[8];
  o[0]=a.x*rs*wa.x; o[1]=a.y*rs*wa.y; o[2]=a.z*rs*wa.z; o[3]=a.w*rs*wa.w;
  o[4]=b.x*rs*wb.x; o[5]=b.y*rs*wb.y; o[6]=b.z*rs*wb.z; o[7]=b.w*rs*wb.w;
  us4_t p0, p1;
  p0.x=f2b(o[0]); p0.y=f2b(o[1]); p0.z=f2b(o[2]); p0.w=f2b(o[3]);
  p1.x=f2b(o[4]); p1.y=f2b(o[5]); p1.z=f2b(o[6]); p1.w=f2b(o[7]);
  *(us4_t*)&ob[(size_t)row*HID + base] = p0;
  *(us4_t*)&ob[(size_t)row*HID + base + 4] = p1;
  float* orow = of + (size_t)row*HID + base;
  *(float4*)orow = make_float4(o[0],o[1],o[2],o[3]);
  *(float4*)(orow+4) = make_float4(o[4],o[5],o[6],o[7]);
}

// ---------- RoPE table (f64 math -> f32) ----------

__global__ void rope_table_k(float* ct, float* st){
  int i = blockIdx.x*256 + threadIdx.x;   // SEQ*32
  int s = i >> 5, j = i & 31;
  double invf = exp(-(double)j / 32.0 * log(10000.0));
  double ang = (double)s * invf;
  ct[i] = (float)cos(ang);
  st[i] = (float)sin(ang);
}

// ---------- split GEMM: C = A @ Bt^T with 3-way bf16 splits (6 products) ----------
// EPI: 0 = f32 out; 1 = rope + 3-way-split out; 2 = f32 + residual

template<int EPI>
__global__ __launch_bounds__(256, 2)
void gemm128s(const u16* __restrict__ A1, const u16* __restrict__ A2, const u16* __restrict__ A3,
              const u16* __restrict__ B1, const u16* __restrict__ B2, const u16* __restrict__ B3,
              float* __restrict__ Cf, u16* __restrict__ O1, u16* __restrict__ O2, u16* __restrict__ O3,
              const float* __restrict__ ct, const float* __restrict__ st,
              const float* __restrict__ Res)
{
  __shared__ u16 As[3][128*32];
  __shared__ u16 Bs[3][128*32];
  const int tid = threadIdx.x;
  const int lane = tid & 63;
  const int wave = tid >> 6;
  const int wr = wave >> 1, wc = wave & 1;
  const int fr = lane & 15, fg = lane >> 4;
  const int bm = blockIdx.y * 128, bn = blockIdx.x * 128;

  f32x4_t acc[4][4] = {};

  const int srow = tid >> 2, skb = tid & 3;
  const u16* Ap[3] = {A1, A2, A3};
  const u16* Bp[3] = {B1, B2, B3};
  const u16* gA[3]; const u16* gB[3];
  #pragma unroll
  for (int t = 0; t < 3; t++){
    gA[t] = Ap[t] + (size_t)(bm + srow) * HID + skb * 8;
    gB[t] = Bp[t] + (size_t)(bn + srow) * HID + skb * 8;
  }

  for (int kk = 0; kk < HID; kk += 32){
    #pragma unroll
    for (int t = 0; t < 3; t++){
      gload16(gA[t] + kk,                    &As[t][tid*8]);
      gload16(gA[t] + (size_t)64*HID + kk,   &As[t][2048 + tid*8]);
      gload16(gB[t] + kk,                    &Bs[t][tid*8]);
      gload16(gB[t] + (size_t)64*HID + kk,   &Bs[t][2048 + tid*8]);
    }
    __syncthreads();
    bf16x8_t af[3][4], bfv[3][4];
    #pragma unroll
    for (int t = 0; t < 3; t++)
      #pragma unroll
      for (int i = 0; i < 4; i++){
        af[t][i]  = ldfrag(&As[t][(wr*64 + i*16 + fr)*32 + fg*4]);
        bfv[t][i] = ldfrag(&Bs[t][(wc*64 + i*16 + fr)*32 + fg*4]);
      }
    // 6 products, smallest first: a3b1, a2b2, a1b3, a2b1, a1b2, a1b1
    const int pA[6] = {2,1,0,1,0,0};
    const int pB[6] = {0,1,2,0,1,0};
    #pragma unroll
    for (int p = 0; p < 6; p++)
      #pragma unroll
      for (int mi = 0; mi < 4; mi++)
        #pragma unroll
        for (int ni = 0; ni < 4; ni++)
          acc[mi][ni] = mfma16(af[pA[p]][mi], bfv[pB[p]][ni], acc[mi][ni]);
    __syncthreads();
  }

  if (EPI == 1){
    #pragma unroll
    for (int mi = 0; mi < 4; mi++)
      #pragma unroll
      for (int r = 0; r < 4; r++){
        int row = bm + wr*64 + mi*16 + fg*4 + r;
        int s = row & (SEQ-1);
        #pragma unroll
        for (int ni = 0; ni < 2; ni++){
          int dlo = ni*16 + fr;   // 0..31 within head
          float c  = ct[s*32 + dlo];
          float sn = st[s*32 + dlo];
          float xl = acc[mi][ni][r], xh = acc[mi][ni+2][r];
          float ol = xl*c - xh*sn;
          float oh = xh*c + xl*sn;
          size_t idx = (size_t)row * HID + bn + wc*64 + ni*16 + fr;
          u16 b1, b2, b3;
          split3v(ol, b1, b2, b3); O1[idx] = b1;    O2[idx] = b2;    O3[idx] = b3;
          split3v(oh, b1, b2, b3); O1[idx+32] = b1; O2[idx+32] = b2; O3[idx+32] = b3;
        }
      }
  } else {
    #pragma unroll
    for (int mi = 0; mi < 4; mi++)
      #pragma unroll
      for (int ni = 0; ni < 4; ni++)
        #pragma unroll
        for (int r = 0; r < 4; r++){
          int row = bm + wr*64 + mi*16 + fg*4 + r;
          int col = bn + wc*64 + ni*16 + fr;
          size_t idx = (size_t)row * HID + col;
          if (EPI == 0) Cf[idx] = acc[mi][ni][r];
          else          Cf[idx] = acc[mi][ni][r] + Res[idx];
        }
  }
}

// ---------- elementwise 3-way split (attention output) ----------

__global__ __launch_bounds__(256)
void split3_k(const float* __restrict__ in, u16* __restrict__ o1, u16* __restrict__ o2,
              u16* __restrict__ o3)
{
  size_t i = ((size_t)blockIdx.x*256 + threadIdx.x) * 4;
  float4 v = *(const float4*)(in + i);
  us4_t v1, v2, v3;
  u16 b1, b2, b3;
  split3v(v.x, b1,b2,b3); v1.x=b1; v2.x=b2; v3.x=b3;
  split3v(v.y, b1,b2,b3); v1.y=b1; v2.y=b2; v3.y=b3;
  split3v(v.z, b1,b2,b3); v1.z=b1; v2.z=b2; v3.z=b3;
  split3v(v.w, b1,b2,b3); v1.w=b1; v2.w=b2; v3.w=b3;
  *(us4_t*)&o1[i] = v1; *(us4_t*)&o2[i] = v2; *(us4_t*)&o3[i] = v3;
}

// ---------- V transpose + split: f32 [T][H] -> per (b,h) bf16x3 [64 d][1024 s] ----------

__global__ __launch_bounds__(256)
void vtrans3_k(const float* __restrict__ vf, u16* __restrict__ t1, u16* __restrict__ t2,
               u16* __restrict__ t3)
{
  __shared__ float t[64][65];
  int st0 = blockIdx.x * 64;
  int bh = blockIdx.y;
  int b = bh >> 5, h = bh & 31;
  int tid = threadIdx.x;
  #pragma unroll
  for (int i = 0; i < 4; i++){
    int idx = tid + i*256;                // 1024 float4 chunks
    int s = idx >> 4, dc = (idx & 15) * 4;
    float4 v = *(const float4*)&vf[(size_t)(b*SEQ + st0 + s) * HID + h*64 + dc];
    t[dc+0][s] = v.x; t[dc+1][s] = v.y; t[dc+2][s] = v.z; t[dc+3][s] = v.w;
  }
  __syncthreads();
  #pragma unroll
  for (int i = 0; i < 4; i++){
    int idx = tid + i*256;
    int d = idx >> 4, sc = (idx & 15) * 4;
    us4_t v1, v2, v3;
    #pragma unroll
    for (int j = 0; j < 4; j++){
      u16 b1, b2, b3; split3v(t[d][sc+j], b1, b2, b3);
      v1[j]=b1; v2[j]=b2; v3[j]=b3;
    }
    size_t base = ((size_t)bh*64 + d)*SEQ + st0 + sc;
    *(us4_t*)&t1[base] = v1; *(us4_t*)&t2[base] = v2; *(us4_t*)&t3[base] = v3;
  }
}

// ---------- flash attention, split-precision (causal), f32 out ----------

__global__ __launch_bounds__(256)
void fattn3_k(const u16* __restrict__ q1, const u16* __restrict__ q2, const u16* __restrict__ q3,
              const u16* __restrict__ k1, const u16* __restrict__ k2, const u16* __restrict__ k3,
              const u16* __restrict__ v1, const u16* __restrict__ v2, const u16* __restrict__ v3,
              float* __restrict__ aof)
{
  __shared__ u16 Ks[3][64*64];     // 24KB
  __shared__ u16 Vs[3][64*64];     // 24KB
  __shared__ u16 Ps[2][4][16*64];  // 16KB  -> 64KB total
  const int bh = blockIdx.x, qt = blockIdx.y;
  const int b = bh >> 5, h = bh & 31;
  const int tid = threadIdx.x, lane = tid & 63, wave = tid >> 6;
  const int fr = lane & 15, fg = lane >> 4;

  const size_t qrow = (size_t)(b*SEQ + qt*64 + wave*16 + fr);
  const u16* qp[3] = { q1 + qrow*HID + h*64, q2 + qrow*HID + h*64, q3 + qrow*HID + h*64 };
  bf16x8_t aq[3][2];
  #pragma unroll
  for (int t = 0; t < 3; t++)
    #pragma unroll
    for (int ks = 0; ks < 2; ks++) aq[t][ks] = ldfrag(qp[t] + ks*32 + fg*4);

  f32x4_t oacc[4] = {};
  float m_r[4], l_r[4];
  #pragma unroll
  for (int r = 0; r < 4; r++){ m_r[r] = -1e30f; l_r[r] = 0.f; }

  const int sr = tid >> 3, sp = tid & 7;
  const u16* kb[3] = { k1 + ((size_t)(b*SEQ) + sr)*HID + h*64 + sp*8,
                       k2 + ((size_t)(b*SEQ) + sr)*HID + h*64 + sp*8,
                       k3 + ((size_t)(b*SEQ) + sr)*HID + h*64 + sp*8 };
  const u16* vb[3] = { v1 + ((size_t)bh*64 + sr)*SEQ + sp*8,
                       v2 + ((size_t)bh*64 + sr)*SEQ + sp*8,
                       v3 + ((size_t)bh*64 + sr)*SEQ + sp*8 };

  for (int kt = 0; kt <= qt; kt++){
    #pragma unroll
    for (int t = 0; t < 3; t++){
      gload16(kb[t] + (size_t)(kt*64) * HID,    &Ks[t][tid*8]);
      gload16(kb[t] + (size_t)(kt*64+32) * HID, &Ks[t][2048 + tid*8]);
      gload16(vb[t] + kt*64,                    &Vs[t][tid*8]);
      gload16(vb[t] + (size_t)32*SEQ + kt*64,   &Vs[t][2048 + tid*8]);
    }
    __syncthreads();

    f32x4_t sc[4] = {};
    #pragma unroll
    for (int nf = 0; nf < 4; nf++)
      #pragma unroll
      for (int ks = 0; ks < 2; ks++){
        bf16x8_t bk0 = ldfrag(&Ks[0][(nf*16+fr)*64 + ks*32 + fg*4]);
        bf16x8_t bk1 = ldfrag(&Ks[1][(nf*16+fr)*64 + ks*32 + fg*4]);
        bf16x8_t bk2 = ldfrag(&Ks[2][(nf*16+fr)*64 + ks*32 + fg*4]);
        sc[nf] = mfma16(aq[2][ks], bk0, sc[nf]);
        sc[nf] = mfma16(aq[1][ks], bk1, sc[nf]);
        sc[nf] = mfma16(aq[0][ks], bk2, sc[nf]);
        sc[nf] = mfma16(aq[1][ks], bk0, sc[nf]);
        sc[nf] = mfma16(aq[0][ks], bk1, sc[nf]);
        sc[nf] = mfma16(aq[0][ks], bk0, sc[nf]);
      }

    float nm[4] = {-1e30f,-1e30f,-1e30f,-1e30f};
    #pragma unroll
    for (int nf = 0; nf < 4; nf++)
      #pragma unroll
      for (int r = 0; r < 4; r++){
        float v = sc[nf][r] * 0.125f;
        if (kt == qt && nf*16 + fr > wave*16 + fg*4 + r) v = -1e30f;
        sc[nf][r] = v;
        nm[r] = fmaxf(nm[r], v);
      }
    #pragma unroll
    for (int r = 0; r < 4; r++)
      #pragma unroll
      for (int msk = 8; msk; msk >>= 1) nm[r] = fmaxf(nm[r], __shfl_xor(nm[r], msk));

    #pragma unroll
    for (int r = 0; r < 4; r++){
      float mn = fmaxf(m_r[r], nm[r]);
      float f = __expf(m_r[r] - mn);
      m_r[r] = mn;
      float rsum = 0.f;
      #pragma unroll
      for (int nf = 0; nf < 4; nf++){
        float pv = __expf(sc[nf][r] - mn);
        sc[nf][r] = pv;
        rsum += pv;
      }
      #pragma unroll
      for (int msk = 8; msk; msk >>= 1) rsum += __shfl_xor(rsum, msk);
      l_r[r] = l_r[r]*f + rsum;
      #pragma unroll
      for (int df = 0; df < 4; df++) oacc[df][r] *= f;
    }

    // P 2-way split to LDS
    #pragma unroll
    for (int nf = 0; nf < 4; nf++)
      #pragma unroll
      for (int r = 0; r < 4; r++){
        float pv = sc[nf][r];
        u16 b1 = f2b(pv);
        float f1 = b2f(b1);
        u16 b2 = f2b(pv - f1);
        Ps[0][wave][(fg*4+r)*64 + nf*16 + fr] = b1;
        Ps[1][wave][(fg*4+r)*64 + nf*16 + fr] = b2;
      }

    #pragma unroll
    for (int ks = 0; ks < 2; ks++){
      bf16x8_t pa0 = ldfrag(&Ps[0][wave][fr*64 + ks*32 + fg*4]);
      bf16x8_t pa1 = ldfrag(&Ps[1][wave][fr*64 + ks*32 + fg*4]);
      #pragma unroll
      for (int df = 0; df < 4; df++){
        bf16x8_t bv0 = ldfrag(&Vs[0][(df*16+fr)*64 + ks*32 + fg*4]);
        bf16x8_t bv1 = ldfrag(&Vs[1][(df*16+fr)*64 + ks*32 + fg*4]);
        bf16x8_t bv2 = ldfrag(&Vs[2][(df*16+fr)*64 + ks*32 + fg*4]);
        oacc[df] = mfma16(pa0, bv2, oacc[df]);   // p1 v3
        oacc[df] = mfma16(pa1, bv1, oacc[df]);   // p2 v2
        oacc[df] = mfma16(pa1, bv0, oacc[df]);   // p2 v1
        oacc[df] = mfma16(pa0, bv1, oacc[df]);   // p1 v2
        oacc[df] = mfma16(pa0, bv0, oacc[df]);   // p1 v1
      }
    }
    __syncthreads();
  }

  #pragma unroll
  for (int r = 0; r < 4; r++){
    float inv = 1.f / l_r[r];
    int orow = b*SEQ + qt*64 + wave*16 + fg*4 + r;
    #pragma unroll
    for (int df = 0; df < 4; df++)
      aof[(size_t)orow * HID + h*64 + df*16 + fr] = oacc[df][r] * inv;
  }
}

// ---------- router: f64 accumulation, softmax, top-2, normalized combine weights ----------

__global__ __launch_bounds__(64)
void router_k(const float* __restrict__ yn, const float* __restrict__ Wr, float* __restrict__ cw){
  int row = blockIdx.x;
  int lane = threadIdx.x;
  const float* xr = yn + (size_t)row * HID;
  double acc[8] = {};
  for (int j = lane; j < HID; j += 64){
    double xv = (double)xr[j];
    const float* wr = Wr + (size_t)j*8;
    float4 w0 = *(const float4*)wr;
    float4 w1 = *(const float4*)(wr + 4);
    acc[0] += xv*w0.x; acc[1] += xv*w0.y; acc[2] += xv*w0.z; acc[3] += xv*w0.w;
    acc[4] += xv*w1.x; acc[5] += xv*w1.y; acc[6] += xv*w1.z; acc[7] += xv*w1.w;
  }
  #pragma unroll
  for (int e = 0; e < 8; e++)
    #pragma unroll
    for (int off = 32; off; off >>= 1) acc[e] += __shfl_down(acc[e], off);
  if (lane == 0){
    double mx = acc[0];
    #pragma unroll
    for (int e = 1; e < 8; e++) mx = fmax(mx, acc[e]);
    double p[8];
    #pragma unroll
    for (int e = 0; e < 8; e++) p[e] = exp(acc[e] - mx);
    int i1 = 0;
    #pragma unroll
    for (int e = 1; e < 8; e++) if (p[e] > p[i1]) i1 = e;
    int i2 = (i1 == 0) ? 1 : 0;
    #pragma unroll
    for (int e = 0; e < 8; e++) if (e != i1 && p[e] > p[i2]) i2 = e;
    double s2 = p[i1] + p[i2];
    float* o = cw + (size_t)row * 8;
    #pragma unroll
    for (int e = 0; e < 8; e++) o[e] = 0.f;
    o[i1] = (float)(p[i1] / s2);
    o[i2] = (float)(p[i2] / s2);
  }
}

// ---------- fused gate+up GEMM, writes h = silu(g)*u*cw (bf16) ----------

__global__ __launch_bounds__(256, 2)
void gemm_gateup(const u16* __restrict__ A, const u16* __restrict__ WgT, const u16* __restrict__ WuT,
                 const float* __restrict__ cw, u16* __restrict__ Hb)
{
  __shared__ u16 As[128*32];
  __shared__ u16 Bg[64*32];
  __shared__ u16 Bu[64*32];
  const int e = blockIdx.z;
  const int tid = threadIdx.x;
  const int lane = tid & 63;
  const int wave = tid >> 6;
  const int wr = wave >> 1, wc = wave & 1;
  const int fr = lane & 15, fg = lane >> 4;
  const int bm = blockIdx.y * 128;   // token rows
  const int bn = blockIdx.x * 64;    // M cols

  f32x4_t ag[4][2] = {}, au[4][2] = {};

  const int srow = tid >> 2, skb = tid & 3;
  const u16* ga0 = A + (size_t)(bm + srow) * HID + skb * 8;
  const u16* gg0 = WgT + ((size_t)e*MDIM + bn + srow) * HID + skb * 8;
  const u16* gu0 = WuT + ((size_t)e*MDIM + bn + srow) * HID + skb * 8;

  for (int kk = 0; kk < HID; kk += 32){
    gload16(ga0 + kk, &As[tid*8]);
    gload16(ga0 + (size_t)64*HID + kk, &As[2048 + tid*8]);
    gload16(gg0 + kk, &Bg[tid*8]);
    gload16(gu0 + kk, &Bu[tid*8]);
    __syncthreads();
    bf16x8_t af[4], bg[2], bu[2];
    #pragma unroll
    for (int i = 0; i < 4; i++) af[i] = ldfrag(&As[(wr*64 + i*16 + fr)*32 + fg*4]);
    #pragma unroll
    for (int j = 0; j < 2; j++){
      bg[j] = ldfrag(&Bg[(wc*32 + j*16 + fr)*32 + fg*4]);
      bu[j] = ldfrag(&Bu[(wc*32 + j*16 + fr)*32 + fg*4]);
    }
    #pragma unroll
    for (int mi = 0; mi < 4; mi++)
      #pragma unroll
      for (int nj = 0; nj < 2; nj++){
        ag[mi][nj] = mfma16(af[mi], bg[nj], ag[mi][nj]);
        au[mi][nj] = mfma16(af[mi], bu[nj], au[mi][nj]);
      }
    __syncthreads();
  }

  #pragma unroll
  for (int mi = 0; mi < 4; mi++)
    #pragma unroll
    for (int nj = 0; nj < 2; nj++)
      #pragma unroll
      for (int r = 0; r < 4; r++){
        int row = bm + wr*64 + mi*16 + fg*4 + r;
        int col = bn + wc*32 + nj*16 + fr;
        float g = ag[mi][nj][r], u = au[mi][nj][r];
        float h = g / (1.0f + __expf(-g)) * u * cw[(size_t)row*8 + e];
        Hb[((size_t)e*T_TOK + row)*MDIM + col] = f2b(h);
      }
}

// ---------- down GEMM: sum over experts, + residual, f32 out ----------

__global__ __launch_bounds__(256, 2)
void gemm_down(const u16* __restrict__ Hb, const u16* __restrict__ WdT,
               const float* __restrict__ Res, float* __restrict__ Out)
{
  __shared__ u16 As[128*32];
  __shared__ u16 Bs[128*32];
  const int tid = threadIdx.x;
  const int lane = tid & 63;
  const int wave = tid >> 6;
  const int wr = wave >> 1, wc = wave & 1;
  const int fr = lane & 15, fg = lane >> 4;
  const int bm = blockIdx.y * 128, bn = blockIdx.x * 128;
  const int srow = tid >> 2, skb = tid & 3;

  f32x4_t acc[4][4] = {};

  for (int e = 0; e < NEXP; e++){
    const u16* A  = Hb  + (size_t)e * T_TOK * MDIM;
    const u16* Bt = WdT + (size_t)e * HID * MDIM;
    const u16* ga0 = A + (size_t)(bm + srow) * MDIM + skb * 8;
    const u16* gb0 = Bt + (size_t)(bn + srow) * MDIM + skb * 8;
    for (int kk = 0; kk < MDIM; kk += 32){
      gload16(ga0 + kk, &As[tid*8]);
      gload16(ga0 + (size_t)64*MDIM + kk, &As[2048 + tid*8]);
      gload16(gb0 + kk, &Bs[tid*8]);
      gload16(gb0 + (size_t)64*MDIM + kk, &Bs[2048 + tid*8]);
      __syncthreads();
      bf16x8_t af[4], bfv[4];
      #pragma unroll
      for (int i = 0; i < 4; i++) af[i]  = ldfrag(&As[(wr*64 + i*16 + fr)*32 + fg*4]);
      #pragma unroll
      for (int i = 0; i < 4; i++) bfv[i] = ldfrag(&Bs[(wc*64 + i*16 + fr)*32 + fg*4]);
      #pragma unroll
      for (int mi = 0; mi < 4; mi++)
        #pragma unroll
        for (int ni = 0; ni < 4; ni++)
          acc[mi][ni] = mfma16(af[mi], bfv[ni], acc[mi][ni]);
      __syncthreads();
    }
  }

  #pragma unroll
  for (int mi = 0; mi < 4; mi++)
    #pragma unroll
    for (int ni = 0; ni < 4; ni++)
      #pragma unroll
      for (int r = 0; r < 4; r++){
        int row = bm + wr*64 + mi*16 + fg*4 + r;
        int col = bn + wc*64 + ni*16 + fr;
        size_t idx = (size_t)row * HID + col;
        Out[idx] = acc[mi][ni][r] + Res[idx];
      }
}

// ---------- launch ----------
// Workspace plan (peak 184.5 MB; ws budget appears to be ~256 MB — round 2's
// 280.6 MB layout core-dumped, round 0's 232 MB ran):
//   R0  96MB: Wq/Wk/Wv/Wo 3-way splits  -> (after O-proj) WgT/WuT/WdT
//   R1  24MB: xn1..3 -> vt1..3 -> ynb(8MB)+yn(16MB f32)
//   R2  24MB: q1..3  -> hb[0..24MB)
//   R3  24MB: k1..3  -> ao1..3 -> hb[24..32MB)
//   R4  16MB: vf(f32) -> aof(f32) -> x1(f32, lives to end)

extern "C" void kernel_launch(void* const* d_in, const int* in_sizes, int n_in,
                              void* d_out, int out_size, void* d_ws, size_t ws_size,
                              hipStream_t stream)
{
  const float* hs     = (const float*)d_in[0];
  const float* w_attn = (const float*)d_in[1];
  const float* Wq = (const float*)d_in[2];
  const float* Wk = (const float*)d_in[3];
  const float* Wv = (const float*)d_in[4];
  const float* Wo = (const float*)d_in[5];
  const float* w_moe = (const float*)d_in[6];
  const float* Wr = (const float*)d_in[7];
  const float* Wg = (const float*)d_in[8];
  const float* Wu = (const float*)d_in[9];
  const float* Wd = (const float*)d_in[10];
  float* out = (float*)d_out;
  (void)in_sizes; (void)n_in; (void)out_size; (void)ws_size;

  char* ws = (char*)d_ws;
  const size_t MB = 1024*1024;
  char* R0 = ws;                 // 96 MB
  char* R1 = ws + 96*MB;         // 24 MB
  char* R2 = ws + 120*MB;        // 24 MB
  char* R3 = ws + 144*MB;        // 24 MB
  char* R4 = ws + 168*MB;        // 16 MB
  char* RS = ws + 184*MB;        // small: cw, ct, st

  // phase A pointers (attention)
  const size_t WSLB = (size_t)HID*HID;   // elements per split slab (8 MB)
  u16* W0 = (u16*)R0;
  u16 *Wq1 = W0,          *Wq2 = W0 + WSLB,    *Wq3 = W0 + 2*WSLB;
  u16 *Wk1 = W0 + 3*WSLB, *Wk2 = W0 + 4*WSLB,  *Wk3 = W0 + 5*WSLB;
  u16 *Wv1 = W0 + 6*WSLB, *Wv2 = W0 + 7*WSLB,  *Wv3 = W0 + 8*WSLB;
  u16 *Wo1 = W0 + 9*WSLB, *Wo2 = W0 + 10*WSLB, *Wo3 = W0 + 11*WSLB;
  const size_t TSLB = (size_t)T_TOK*HID;  // elements per activation slab (8 MB)
  u16 *xn1 = (u16*)R1, *xn2 = (u16*)R1 + TSLB, *xn3 = (u16*)R1 + 2*TSLB;
  u16 *q1  = (u16*)R2, *q2  = (u16*)R2 + TSLB, *q3  = (u16*)R2 + 2*TSLB;
  u16 *k1  = (u16*)R3, *k2  = (u16*)R3 + TSLB, *k3  = (u16*)R3 + 2*TSLB;
  u16 *vt1 = xn1, *vt2 = xn2, *vt3 = xn3;        // reuse R1 after xn is dead
  float* vf  = (float*)R4;
  float* aof = (float*)R4;                        // reuse after vtrans
  u16 *ao1 = k1, *ao2 = k2, *ao3 = k3;            // reuse R3 after fattn
  float* x1  = (float*)R4;                        // reuse after split3 (O-proj out)
  // phase B pointers (MoE)
  u16* WgT = (u16*)R0;                            // 32 MB
  u16* WuT = (u16*)R0 + (size_t)NEXP*MDIM*HID;    // 32 MB
  u16* WdT = (u16*)R0 + 2*(size_t)NEXP*MDIM*HID;  // 32 MB
  u16* ynb = (u16*)R1;                            // 8 MB
  float* yn = (float*)(R1 + 8*MB);                // 16 MB
  u16* hb  = (u16*)R2;                            // 32 MB spans R2 + first 8MB of R3
  float* cw = (float*)RS;
  float* ct = (float*)(RS + 256*1024);
  float* stab = (float*)(RS + 512*1024);

  dim3 blk256(256), blkT(32,8), g16(16,16), g64(64,64);

  rope_table_k<<<dim3(SEQ*32/256), blk256, 0, stream>>>(ct, stab);
  convT3<<<g64, blkT, 0, stream>>>(Wq, Wq1, Wq2, Wq3, HID, HID);
  convT3<<<g64, blkT, 0, stream>>>(Wk, Wk1, Wk2, Wk3, HID, HID);
  convT3<<<g64, blkT, 0, stream>>>(Wv, Wv1, Wv2, Wv3, HID, HID);
  convT3<<<g64, blkT, 0, stream>>>(Wo, Wo1, Wo2, Wo3, HID, HID);

  rmsnorm3_k<<<dim3(T_TOK), blk256, 0, stream>>>(hs, w_attn, xn1, xn2, xn3);

  // Q, K with fused rope + split epilogue; V -> f32
  gemm128s<1><<<g16, blk256, 0, stream>>>(xn1,xn2,xn3, Wq1,Wq2,Wq3, nullptr, q1,q2,q3, ct, stab, nullptr);
  gemm128s<1><<<g16, blk256, 0, stream>>>(xn1,xn2,xn3, Wk1,Wk2,Wk3, nullptr, k1,k2,k3, ct, stab, nullptr);
  gemm128s<0><<<g16, blk256, 0, stream>>>(xn1,xn2,xn3, Wv1,Wv2,Wv3, vf, nullptr,nullptr,nullptr, nullptr, nullptr, nullptr);

  vtrans3_k<<<dim3(SEQ/64, BATCH*NHEAD), blk256, 0, stream>>>(vf, vt1, vt2, vt3);   // xn dead

  fattn3_k<<<dim3(BATCH*NHEAD, SEQ/64), blk256, 0, stream>>>(q1,q2,q3, k1,k2,k3, vt1,vt2,vt3, aof);  // vf dead

  split3_k<<<dim3(T_TOK*HID/1024), blk256, 0, stream>>>(aof, ao1, ao2, ao3);        // k dead

  gemm128s<2><<<g16, blk256, 0, stream>>>(ao1,ao2,ao3, Wo1,Wo2,Wo3, x1, nullptr,nullptr,nullptr, nullptr, nullptr, hs);  // aof dead

  // attention weights dead -> convert MoE weights into R0
  convT<<<dim3(MDIM/32, HID/32, NEXP), blkT, 0, stream>>>(Wg, WgT, HID, MDIM);
  convT<<<dim3(MDIM/32, HID/32, NEXP), blkT, 0, stream>>>(Wu, WuT, HID, MDIM);
  convT<<<dim3(HID/32, MDIM/32, NEXP), blkT, 0, stream>>>(Wd, WdT, MDIM, HID);

  rmsnorm_k<<<dim3(T_TOK), blk256, 0, stream>>>(x1, w_moe, ynb, yn);   // vt dead
  router_k<<<dim3(T_TOK), dim3(64), 0, stream>>>(yn, Wr, cw);

  gemm_gateup<<<dim3(MDIM/64, T_TOK/128, NEXP), blk256, 0, stream>>>(ynb, WgT, WuT, cw, hb);  // q, ao dead
  gemm_down<<<g16, blk256, 0, stream>>>(hb, WdT, x1, out);
}

// Round 4
// 1493.965 us; speedup vs baseline: 1.6511x; 1.6511x over previous
//
#include <hip/hip_runtime.h>
#include <hip/hip_bf16.h>
#include <cstdint>

typedef unsigned short u16;
typedef __bf16 bf16x4_t __attribute__((ext_vector_type(4)));
typedef __bf16 bf16x8_t __attribute__((ext_vector_type(8)));
typedef float f32x4_t __attribute__((ext_vector_type(4)));
typedef unsigned short us4_t __attribute__((ext_vector_type(4)));

#define BATCH 2
#define SEQ 1024
#define HID 2048
#define NHEAD 32
#define NEXP 8
#define MDIM 1024
#define T_TOK (BATCH*SEQ)   // 2048

// ---------- helpers ----------

__device__ __forceinline__ void gload16(const void* g, void* l){
  __builtin_amdgcn_global_load_lds((__attribute__((address_space(1))) void*)(uintptr_t)g,
                                   (__attribute__((address_space(3))) void*)l, 16, 0, 0);
}

// 8-bf16 MFMA fragment as two b64 halves (k = fg*4+e and +16; bijective k-map
// used identically on A and B sides -> product invariant).
__device__ __forceinline__ bf16x8_t ldfrag(const u16* lo){
  bf16x4_t a = *(const bf16x4_t*)lo;
  bf16x4_t b = *(const bf16x4_t*)(lo + 16);
  return __builtin_shufflevector(a, b, 0,1,2,3,4,5,6,7);
}

// Swizzled fragment read, 128B LDS rows (fattn K/V/P): byte ^= (row&7)<<4.
// Pairs with staging-source chunk permute sp^=(row&7). 16-way -> 4-way conflict.
__device__ __forceinline__ bf16x8_t ldfsw128(const u16* base, int row, int colbyte){
  const char* p = (const char*)base + row*128;
  int sw = (row & 7) << 4;
  bf16x4_t a = *(const bf16x4_t*)(p + (colbyte ^ sw));
  bf16x4_t b = *(const bf16x4_t*)(p + ((colbyte + 32) ^ sw));
  return __builtin_shufflevector(a, b, 0,1,2,3,4,5,6,7);
}

// Swizzled fragment read, 64B LDS rows (GEMM tiles, BK=32): byte ^= (row&3)<<4.
// Pairs with staging-source chunk permute skb^=(row&3). 8-way -> 4-way conflict.
__device__ __forceinline__ bf16x8_t ldfsw64(const u16* base, int row, int colbyte){
  const char* p = (const char*)base + row*64;
  int sw = (row & 3) << 4;
  bf16x4_t a = *(const bf16x4_t*)(p + (colbyte ^ sw));
  bf16x4_t b = *(const bf16x4_t*)(p + ((colbyte + 32) ^ sw));
  return __builtin_shufflevector(a, b, 0,1,2,3,4,5,6,7);
}

__device__ __forceinline__ f32x4_t mfma16(bf16x8_t a, bf16x8_t b, f32x4_t c){
  return __builtin_amdgcn_mfma_f32_16x16x32_bf16(a, b, c, 0, 0, 0);
}

__device__ __forceinline__ u16 f2b(float f){
  __hip_bfloat16 h = __float2bfloat16(f);
  return __builtin_bit_cast(u16, h);
}
__device__ __forceinline__ float b2f(u16 b){
  return __builtin_bit_cast(float, (unsigned int)b << 16);
}
// 3-way bf16 split: v ~= b1 + b2 + b3 with |residual| <= 2^-27 |v|
__device__ __forceinline__ void split3v(float v, u16& b1, u16& b2, u16& b3){
  b1 = f2b(v); float f1 = b2f(b1);
  float r1 = v - f1;
  b2 = f2b(r1); float f2 = b2f(b2);
  b3 = f2b(r1 - f2);
}

// ---------- weight convert+transpose (single bf16, MoE): f32 [R][C] -> bf16 [C][R] ----------

__global__ __launch_bounds__(256)
void convT(const float* __restrict__ in, u16* __restrict__ out, int R, int C)
{
  __shared__ float tile[32][33];
  int bz = blockIdx.z;
  const float* ip = in + (size_t)bz * R * C;
  u16* op = out + (size_t)bz * R * C;
  int tx = threadIdx.x, ty = threadIdx.y;   // block (32,8)
  int c0 = blockIdx.x*32, r0 = blockIdx.y*32;
  #pragma unroll
  for (int i = 0; i < 4; i++)
    tile[ty + i*8][tx] = ip[(size_t)(r0 + ty + i*8) * C + c0 + tx];
  __syncthreads();
  #pragma unroll
  for (int i = 0; i < 4; i++)
    op[(size_t)(c0 + ty + i*8) * R + r0 + tx] = f2b(tile[tx][ty + i*8]);
}

// ---------- weight convert+transpose, 3-way split (attention weights) ----------

__global__ __launch_bounds__(256)
void convT3(const float* __restrict__ in, u16* __restrict__ o1, u16* __restrict__ o2,
            u16* __restrict__ o3, int R, int C)
{
  __shared__ float tile[32][33];
  const float* ip = in;
  int tx = threadIdx.x, ty = threadIdx.y;
  int c0 = blockIdx.x*32, r0 = blockIdx.y*32;
  #pragma unroll
  for (int i = 0; i < 4; i++)
    tile[ty + i*8][tx] = ip[(size_t)(r0 + ty + i*8) * C + c0 + tx];
  __syncthreads();
  #pragma unroll
  for (int i = 0; i < 4; i++){
    u16 b1, b2, b3;
    split3v(tile[tx][ty + i*8], b1, b2, b3);
    size_t idx = (size_t)(c0 + ty + i*8) * R + r0 + tx;
    o1[idx] = b1; o2[idx] = b2; o3[idx] = b3;
  }
}

// ---------- RMSNorm -> 3-way split (attention input) ----------

__global__ __launch_bounds__(256)
void rmsnorm3_k(const float* __restrict__ x, const float* __restrict__ w,
                u16* __restrict__ o1, u16* __restrict__ o2, u16* __restrict__ o3)
{
  int row = blockIdx.x;
  const float* xr = x + (size_t)row * HID;
  int base = threadIdx.x * 8;
  float4 a = *(const float4*)(xr + base);
  float4 b = *(const float4*)(xr + base + 4);
  float ss = a.x*a.x + a.y*a.y + a.z*a.z + a.w*a.w
           + b.x*b.x + b.y*b.y + b.z*b.z + b.w*b.w;
  #pragma unroll
  for (int off = 32; off; off >>= 1) ss += __shfl_down(ss, off);
  __shared__ float red[4];
  if ((threadIdx.x & 63) == 0) red[threadIdx.x >> 6] = ss;
  __syncthreads();
  float tot = red[0] + red[1] + red[2] + red[3];
  float rs = (float)(1.0 / sqrt((double)tot * (1.0/2048.0) + 1e-5));
  float4 wa = *(const float4*)(w + base);
  float4 wb = *(const float4*)(w + base + 4);
  float o[8];
  o[0]=a.x*rs*wa.x; o[1]=a.y*rs*wa.y; o[2]=a.z*rs*wa.z; o[3]=a.w*rs*wa.w;
  o[4]=b.x*rs*wb.x; o[5]=b.y*rs*wb.y; o[6]=b.z*rs*wb.z; o[7]=b.w*rs*wb.w;
  us4_t v1[2], v2[2], v3[2];
  #pragma unroll
  for (int j = 0; j < 8; j++){
    u16 b1, b2, b3; split3v(o[j], b1, b2, b3);
    v1[j>>2][j&3] = b1; v2[j>>2][j&3] = b2; v3[j>>2][j&3] = b3;
  }
  size_t idx = (size_t)row*HID + base;
  *(us4_t*)&o1[idx] = v1[0]; *(us4_t*)&o1[idx+4] = v1[1];
  *(us4_t*)&o2[idx] = v2[0]; *(us4_t*)&o2[idx+4] = v2[1];
  *(us4_t*)&o3[idx] = v3[0]; *(us4_t*)&o3[idx+4] = v3[1];
}

// ---------- RMSNorm (MoE): bf16 out + f32 out ----------

__global__ __launch_bounds__(256)
void rmsnorm_k(const float* __restrict__ x, const float* __restrict__ w,
               u16* __restrict__ ob, float* __restrict__ of)
{
  int row = blockIdx.x;
  const float* xr = x + (size_t)row * HID;
  int base = threadIdx.x * 8;
  float4 a = *(const float4*)(xr + base);
  float4 b = *(const float4*)(xr + base + 4);
  float ss = a.x*a.x + a.y*a.y + a.z*a.z + a.w*a.w
           + b.x*b.x + b.y*b.y + b.z*b.z + b.w*b.w;
  #pragma unroll
  for (int off = 32; off; off >>= 1) ss += __shfl_down(ss, off);
  __shared__ float red[4];
  if ((threadIdx.x & 63) == 0) red[threadIdx.x >> 6] = ss;
  __syncthreads();
  float tot = red[0] + red[1] + red[2] + red[3];
  float rs = (float)(1.0 / sqrt((double)tot * (1.0/2048.0) + 1e-5));
  float4 wa = *(const float4*)(w + base);
  float4 wb = *(const float4*)(w + base + 4);
  float o[8];
  o[0]=a.x*rs*wa.x; o[1]=a.y*rs*wa.y; o[2]=a.z*rs*wa.z; o[3]=a.w*rs*wa.w;
  o[4]=b.x*rs*wb.x; o[5]=b.y*rs*wb.y; o[6]=b.z*rs*wb.z; o[7]=b.w*rs*wb.w;
  us4_t p0, p1;
  p0.x=f2b(o[0]); p0.y=f2b(o[1]); p0.z=f2b(o[2]); p0.w=f2b(o[3]);
  p1.x=f2b(o[4]); p1.y=f2b(o[5]); p1.z=f2b(o[6]); p1.w=f2b(o[7]);
  *(us4_t*)&ob[(size_t)row*HID + base] = p0;
  *(us4_t*)&ob[(size_t)row*HID + base + 4] = p1;
  float* orow = of + (size_t)row*HID + base;
  *(float4*)orow = make_float4(o[0],o[1],o[2],o[3]);
  *(float4*)(orow+4) = make_float4(o[4],o[5],o[6],o[7]);
}

// ---------- RoPE table (f64 math -> f32) ----------

__global__ void rope_table_k(float* ct, float* st){
  int i = blockIdx.x*256 + threadIdx.x;   // SEQ*32
  int s = i >> 5, j = i & 31;
  double invf = exp(-(double)j / 32.0 * log(10000.0));
  double ang = (double)s * invf;
  ct[i] = (float)cos(ang);
  st[i] = (float)sin(ang);
}

// ---------- split GEMM: C = A @ Bt^T with 3-way bf16 splits (6 products) ----------
// EPI: 0 = f32 out; 1 = rope + 3-way-split out; 2 = f32 + residual

template<int EPI>
__global__ __launch_bounds__(256, 2)
void gemm128s(const u16* __restrict__ A1, const u16* __restrict__ A2, const u16* __restrict__ A3,
              const u16* __restrict__ B1, const u16* __restrict__ B2, const u16* __restrict__ B3,
              float* __restrict__ Cf, u16* __restrict__ O1, u16* __restrict__ O2, u16* __restrict__ O3,
              const float* __restrict__ ct, const float* __restrict__ st,
              const float* __restrict__ Res)
{
  __shared__ u16 As[3][128*32];
  __shared__ u16 Bs[3][128*32];
  const int tid = threadIdx.x;
  const int lane = tid & 63;
  const int wave = tid >> 6;
  const int wr = wave >> 1, wc = wave & 1;
  const int fr = lane & 15, fg = lane >> 4;
  const int bm = blockIdx.y * 128, bn = blockIdx.x * 128;

  f32x4_t acc[4][4] = {};

  const int srow = tid >> 2, skb = (tid & 3) ^ (srow & 3);   // swizzled source chunk
  const u16* Ap[3] = {A1, A2, A3};
  const u16* Bp[3] = {B1, B2, B3};
  const u16* gA[3]; const u16* gB[3];
  #pragma unroll
  for (int t = 0; t < 3; t++){
    gA[t] = Ap[t] + (size_t)(bm + srow) * HID + skb * 8;
    gB[t] = Bp[t] + (size_t)(bn + srow) * HID + skb * 8;
  }

  for (int kk = 0; kk < HID; kk += 32){
    #pragma unroll
    for (int t = 0; t < 3; t++){
      gload16(gA[t] + kk,                    &As[t][tid*8]);
      gload16(gA[t] + (size_t)64*HID + kk,   &As[t][2048 + tid*8]);
      gload16(gB[t] + kk,                    &Bs[t][tid*8]);
      gload16(gB[t] + (size_t)64*HID + kk,   &Bs[t][2048 + tid*8]);
    }
    __syncthreads();
    bf16x8_t af[3][4], bfv[3][4];
    #pragma unroll
    for (int t = 0; t < 3; t++)
      #pragma unroll
      for (int i = 0; i < 4; i++){
        af[t][i]  = ldfsw64(As[t], wr*64 + i*16 + fr, fg*8);
        bfv[t][i] = ldfsw64(Bs[t], wc*64 + i*16 + fr, fg*8);
      }
    // 6 products, smallest first: a3b1, a2b2, a1b3, a2b1, a1b2, a1b1
    const int pA[6] = {2,1,0,1,0,0};
    const int pB[6] = {0,1,2,0,1,0};
    #pragma unroll
    for (int p = 0; p < 6; p++)
      #pragma unroll
      for (int mi = 0; mi < 4; mi++)
        #pragma unroll
        for (int ni = 0; ni < 4; ni++)
          acc[mi][ni] = mfma16(af[pA[p]][mi], bfv[pB[p]][ni], acc[mi][ni]);
    __syncthreads();
  }

  if (EPI == 1){
    #pragma unroll
    for (int mi = 0; mi < 4; mi++)
      #pragma unroll
      for (int r = 0; r < 4; r++){
        int row = bm + wr*64 + mi*16 + fg*4 + r;
        int s = row & (SEQ-1);
        #pragma unroll
        for (int ni = 0; ni < 2; ni++){
          int dlo = ni*16 + fr;   // 0..31 within head
          float c  = ct[s*32 + dlo];
          float sn = st[s*32 + dlo];
          float xl = acc[mi][ni][r], xh = acc[mi][ni+2][r];
          float ol = xl*c - xh*sn;
          float oh = xh*c + xl*sn;
          size_t idx = (size_t)row * HID + bn + wc*64 + ni*16 + fr;
          u16 b1, b2, b3;
          split3v(ol, b1, b2, b3); O1[idx] = b1;    O2[idx] = b2;    O3[idx] = b3;
          split3v(oh, b1, b2, b3); O1[idx+32] = b1; O2[idx+32] = b2; O3[idx+32] = b3;
        }
      }
  } else {
    #pragma unroll
    for (int mi = 0; mi < 4; mi++)
      #pragma unroll
      for (int ni = 0; ni < 4; ni++)
        #pragma unroll
        for (int r = 0; r < 4; r++){
          int row = bm + wr*64 + mi*16 + fg*4 + r;
          int col = bn + wc*64 + ni*16 + fr;
          size_t idx = (size_t)row * HID + col;
          if (EPI == 0) Cf[idx] = acc[mi][ni][r];
          else          Cf[idx] = acc[mi][ni][r] + Res[idx];
        }
  }
}

// ---------- elementwise 3-way split (attention output) ----------

__global__ __launch_bounds__(256)
void split3_k(const float* __restrict__ in, u16* __restrict__ o1, u16* __restrict__ o2,
              u16* __restrict__ o3)
{
  size_t i = ((size_t)blockIdx.x*256 + threadIdx.x) * 4;
  float4 v = *(const float4*)(in + i);
  us4_t v1, v2, v3;
  u16 b1, b2, b3;
  split3v(v.x, b1,b2,b3); v1.x=b1; v2.x=b2; v3.x=b3;
  split3v(v.y, b1,b2,b3); v1.y=b1; v2.y=b2; v3.y=b3;
  split3v(v.z, b1,b2,b3); v1.z=b1; v2.z=b2; v3.z=b3;
  split3v(v.w, b1,b2,b3); v1.w=b1; v2.w=b2; v3.w=b3;
  *(us4_t*)&o1[i] = v1; *(us4_t*)&o2[i] = v2; *(us4_t*)&o3[i] = v3;
}

// ---------- V transpose + split: f32 [T][H] -> per (b,h) bf16x3 [64 d][1024 s] ----------

__global__ __launch_bounds__(256)
void vtrans3_k(const float* __restrict__ vf, u16* __restrict__ t1, u16* __restrict__ t2,
               u16* __restrict__ t3)
{
  __shared__ float t[64][65];
  int st0 = blockIdx.x * 64;
  int bh = blockIdx.y;
  int b = bh >> 5, h = bh & 31;
  int tid = threadIdx.x;
  #pragma unroll
  for (int i = 0; i < 4; i++){
    int idx = tid + i*256;                // 1024 float4 chunks
    int s = idx >> 4, dc = (idx & 15) * 4;
    float4 v = *(const float4*)&vf[(size_t)(b*SEQ + st0 + s) * HID + h*64 + dc];
    t[dc+0][s] = v.x; t[dc+1][s] = v.y; t[dc+2][s] = v.z; t[dc+3][s] = v.w;
  }
  __syncthreads();
  #pragma unroll
  for (int i = 0; i < 4; i++){
    int idx = tid + i*256;
    int d = idx >> 4, sc = (idx & 15) * 4;
    us4_t v1, v2, v3;
    #pragma unroll
    for (int j = 0; j < 4; j++){
      u16 b1, b2, b3; split3v(t[d][sc+j], b1, b2, b3);
      v1[j]=b1; v2[j]=b2; v3[j]=b3;
    }
    size_t base = ((size_t)bh*64 + d)*SEQ + st0 + sc;
    *(us4_t*)&t1[base] = v1; *(us4_t*)&t2[base] = v2; *(us4_t*)&t3[base] = v3;
  }
}

// ---------- flash attention, split-precision (causal), f32 out ----------

__global__ __launch_bounds__(256)
void fattn3_k(const u16* __restrict__ q1, const u16* __restrict__ q2, const u16* __restrict__ q3,
              const u16* __restrict__ k1, const u16* __restrict__ k2, const u16* __restrict__ k3,
              const u16* __restrict__ v1, const u16* __restrict__ v2, const u16* __restrict__ v3,
              float* __restrict__ aof)
{
  __shared__ u16 Ks[3][64*64];     // 24KB
  __shared__ u16 Vs[3][64*64];     // 24KB
  __shared__ u16 Ps[2][4][16*64];  // 16KB  -> 64KB total
  const int bh = blockIdx.x, qt = blockIdx.y;
  const int b = bh >> 5, h = bh & 31;
  const int tid = threadIdx.x, lane = tid & 63, wave = tid >> 6;
  const int fr = lane & 15, fg = lane >> 4;

  const size_t qrow = (size_t)(b*SEQ + qt*64 + wave*16 + fr);
  const u16* qp[3] = { q1 + qrow*HID + h*64, q2 + qrow*HID + h*64, q3 + qrow*HID + h*64 };
  bf16x8_t aq[3][2];
  #pragma unroll
  for (int t = 0; t < 3; t++)
    #pragma unroll
    for (int ks = 0; ks < 2; ks++) aq[t][ks] = ldfrag(qp[t] + ks*32 + fg*4);

  f32x4_t oacc[4] = {};
  float m_r[4], l_r[4];
  #pragma unroll
  for (int r = 0; r < 4; r++){ m_r[r] = -1e30f; l_r[r] = 0.f; }

  const int sr = tid >> 3, sp = (tid & 7) ^ (sr & 7);   // swizzled source chunk
  const u16* kb[3] = { k1 + ((size_t)(b*SEQ) + sr)*HID + h*64 + sp*8,
                       k2 + ((size_t)(b*SEQ) + sr)*HID + h*64 + sp*8,
                       k3 + ((size_t)(b*SEQ) + sr)*HID + h*64 + sp*8 };
  const u16* vb[3] = { v1 + ((size_t)bh*64 + sr)*SEQ + sp*8,
                       v2 + ((size_t)bh*64 + sr)*SEQ + sp*8,
                       v3 + ((size_t)bh*64 + sr)*SEQ + sp*8 };

  for (int kt = 0; kt <= qt; kt++){
    #pragma unroll
    for (int t = 0; t < 3; t++){
      gload16(kb[t] + (size_t)(kt*64) * HID,    &Ks[t][tid*8]);
      gload16(kb[t] + (size_t)(kt*64+32) * HID, &Ks[t][2048 + tid*8]);
      gload16(vb[t] + kt*64,                    &Vs[t][tid*8]);
      gload16(vb[t] + (size_t)32*SEQ + kt*64,   &Vs[t][2048 + tid*8]);
    }
    __syncthreads();

    f32x4_t sc[4] = {};
    #pragma unroll
    for (int nf = 0; nf < 4; nf++)
      #pragma unroll
      for (int ks = 0; ks < 2; ks++){
        int krow = nf*16 + fr, kcb = ks*64 + fg*8;
        bf16x8_t bk0 = ldfsw128(Ks[0], krow, kcb);
        bf16x8_t bk1 = ldfsw128(Ks[1], krow, kcb);
        bf16x8_t bk2 = ldfsw128(Ks[2], krow, kcb);
        sc[nf] = mfma16(aq[2][ks], bk0, sc[nf]);
        sc[nf] = mfma16(aq[1][ks], bk1, sc[nf]);
        sc[nf] = mfma16(aq[0][ks], bk2, sc[nf]);
        sc[nf] = mfma16(aq[1][ks], bk0, sc[nf]);
        sc[nf] = mfma16(aq[0][ks], bk1, sc[nf]);
        sc[nf] = mfma16(aq[0][ks], bk0, sc[nf]);
      }

    float nm[4] = {-1e30f,-1e30f,-1e30f,-1e30f};
    #pragma unroll
    for (int nf = 0; nf < 4; nf++)
      #pragma unroll
      for (int r = 0; r < 4; r++){
        float v = sc[nf][r] * 0.125f;
        if (kt == qt && nf*16 + fr > wave*16 + fg*4 + r) v = -1e30f;
        sc[nf][r] = v;
        nm[r] = fmaxf(nm[r], v);
      }
    #pragma unroll
    for (int r = 0; r < 4; r++)
      #pragma unroll
      for (int msk = 8; msk; msk >>= 1) nm[r] = fmaxf(nm[r], __shfl_xor(nm[r], msk));

    #pragma unroll
    for (int r = 0; r < 4; r++){
      float mn = fmaxf(m_r[r], nm[r]);
      float f = __expf(m_r[r] - mn);
      m_r[r] = mn;
      float rsum = 0.f;
      #pragma unroll
      for (int nf = 0; nf < 4; nf++){
        float pv = __expf(sc[nf][r] - mn);
        sc[nf][r] = pv;
        rsum += pv;
      }
      #pragma unroll
      for (int msk = 8; msk; msk >>= 1) rsum += __shfl_xor(rsum, msk);
      l_r[r] = l_r[r]*f + rsum;
      #pragma unroll
      for (int df = 0; df < 4; df++) oacc[df][r] *= f;
    }

    // P 2-way split to LDS (swizzled writes matching ldfsw128 reads)
    #pragma unroll
    for (int nf = 0; nf < 4; nf++)
      #pragma unroll
      for (int r = 0; r < 4; r++){
        float pv = sc[nf][r];
        u16 b1 = f2b(pv);
        float f1 = b2f(b1);
        u16 b2 = f2b(pv - f1);
        int prow = fg*4 + r;
        int pbyte = (nf*32 + fr*2) ^ ((prow & 7) << 4);
        *(u16*)((char*)&Ps[0][wave][0] + prow*128 + pbyte) = b1;
        *(u16*)((char*)&Ps[1][wave][0] + prow*128 + pbyte) = b2;
      }

    #pragma unroll
    for (int ks = 0; ks < 2; ks++){
      bf16x8_t pa0 = ldfsw128(&Ps[0][wave][0], fr, ks*64 + fg*8);
      bf16x8_t pa1 = ldfsw128(&Ps[1][wave][0], fr, ks*64 + fg*8);
      #pragma unroll
      for (int df = 0; df < 4; df++){
        int vrow = df*16 + fr, vcb = ks*64 + fg*8;
        bf16x8_t bv0 = ldfsw128(Vs[0], vrow, vcb);
        bf16x8_t bv1 = ldfsw128(Vs[1], vrow, vcb);
        bf16x8_t bv2 = ldfsw128(Vs[2], vrow, vcb);
        oacc[df] = mfma16(pa0, bv2, oacc[df]);   // p1 v3
        oacc[df] = mfma16(pa1, bv1, oacc[df]);   // p2 v2
        oacc[df] = mfma16(pa1, bv0, oacc[df]);   // p2 v1
        oacc[df] = mfma16(pa0, bv1, oacc[df]);   // p1 v2
        oacc[df] = mfma16(pa0, bv0, oacc[df]);   // p1 v1
      }
    }
    __syncthreads();
  }

  #pragma unroll
  for (int r = 0; r < 4; r++){
    float inv = 1.f / l_r[r];
    int orow = b*SEQ + qt*64 + wave*16 + fg*4 + r;
    #pragma unroll
    for (int df = 0; df < 4; df++)
      aof[(size_t)orow * HID + h*64 + df*16 + fr] = oacc[df][r] * inv;
  }
}

// ---------- router: f64 accumulation, softmax, top-2, normalized combine weights ----------

__global__ __launch_bounds__(64)
void router_k(const float* __restrict__ yn, const float* __restrict__ Wr, float* __restrict__ cw){
  int row = blockIdx.x;
  int lane = threadIdx.x;
  const float* xr = yn + (size_t)row * HID;
  double acc[8] = {};
  for (int j = lane; j < HID; j += 64){
    double xv = (double)xr[j];
    const float* wr = Wr + (size_t)j*8;
    float4 w0 = *(const float4*)wr;
    float4 w1 = *(const float4*)(wr + 4);
    acc[0] += xv*w0.x; acc[1] += xv*w0.y; acc[2] += xv*w0.z; acc[3] += xv*w0.w;
    acc[4] += xv*w1.x; acc[5] += xv*w1.y; acc[6] += xv*w1.z; acc[7] += xv*w1.w;
  }
  #pragma unroll
  for (int e = 0; e < 8; e++)
    #pragma unroll
    for (int off = 32; off; off >>= 1) acc[e] += __shfl_down(acc[e], off);
  if (lane == 0){
    double mx = acc[0];
    #pragma unroll
    for (int e = 1; e < 8; e++) mx = fmax(mx, acc[e]);
    double p[8];
    #pragma unroll
    for (int e = 0; e < 8; e++) p[e] = exp(acc[e] - mx);
    int i1 = 0;
    #pragma unroll
    for (int e = 1; e < 8; e++) if (p[e] > p[i1]) i1 = e;
    int i2 = (i1 == 0) ? 1 : 0;
    #pragma unroll
    for (int e = 0; e < 8; e++) if (e != i1 && p[e] > p[i2]) i2 = e;
    double s2 = p[i1] + p[i2];
    float* o = cw + (size_t)row * 8;
    #pragma unroll
    for (int e = 0; e < 8; e++) o[e] = 0.f;
    o[i1] = (float)(p[i1] / s2);
    o[i2] = (float)(p[i2] / s2);
  }
}

// ---------- fused gate+up GEMM, writes h = silu(g)*u*cw (bf16) ----------

__global__ __launch_bounds__(256, 2)
void gemm_gateup(const u16* __restrict__ A, const u16* __restrict__ WgT, const u16* __restrict__ WuT,
                 const float* __restrict__ cw, u16* __restrict__ Hb)
{
  __shared__ u16 As[128*32];
  __shared__ u16 Bg[64*32];
  __shared__ u16 Bu[64*32];
  const int e = blockIdx.z;
  const int tid = threadIdx.x;
  const int lane = tid & 63;
  const int wave = tid >> 6;
  const int wr = wave >> 1, wc = wave & 1;
  const int fr = lane & 15, fg = lane >> 4;
  const int bm = blockIdx.y * 128;   // token rows
  const int bn = blockIdx.x * 64;    // M cols

  f32x4_t ag[4][2] = {}, au[4][2] = {};

  const int srow = tid >> 2, skb = (tid & 3) ^ (srow & 3);   // swizzled source chunk
  const u16* ga0 = A + (size_t)(bm + srow) * HID + skb * 8;
  const u16* gg0 = WgT + ((size_t)e*MDIM + bn + srow) * HID + skb * 8;
  const u16* gu0 = WuT + ((size_t)e*MDIM + bn + srow) * HID + skb * 8;

  for (int kk = 0; kk < HID; kk += 32){
    gload16(ga0 + kk, &As[tid*8]);
    gload16(ga0 + (size_t)64*HID + kk, &As[2048 + tid*8]);
    gload16(gg0 + kk, &Bg[tid*8]);
    gload16(gu0 + kk, &Bu[tid*8]);
    __syncthreads();
    bf16x8_t af[4], bg[2], bu[2];
    #pragma unroll
    for (int i = 0; i < 4; i++) af[i] = ldfsw64(As, wr*64 + i*16 + fr, fg*8);
    #pragma unroll
    for (int j = 0; j < 2; j++){
      bg[j] = ldfsw64(Bg, wc*32 + j*16 + fr, fg*8);
      bu[j] = ldfsw64(Bu, wc*32 + j*16 + fr, fg*8);
    }
    #pragma unroll
    for (int mi = 0; mi < 4; mi++)
      #pragma unroll
      for (int nj = 0; nj < 2; nj++){
        ag[mi][nj] = mfma16(af[mi], bg[nj], ag[mi][nj]);
        au[mi][nj] = mfma16(af[mi], bu[nj], au[mi][nj]);
      }
    __syncthreads();
  }

  #pragma unroll
  for (int mi = 0; mi < 4; mi++)
    #pragma unroll
    for (int nj = 0; nj < 2; nj++)
      #pragma unroll
      for (int r = 0; r < 4; r++){
        int row = bm + wr*64 + mi*16 + fg*4 + r;
        int col = bn + wc*32 + nj*16 + fr;
        float g = ag[mi][nj][r], u = au[mi][nj][r];
        float h = g / (1.0f + __expf(-g)) * u * cw[(size_t)row*8 + e];
        Hb[((size_t)e*T_TOK + row)*MDIM + col] = f2b(h);
      }
}

// ---------- down GEMM: sum over experts, + residual, f32 out ----------

__global__ __launch_bounds__(256, 2)
void gemm_down(const u16* __restrict__ Hb, const u16* __restrict__ WdT,
               const float* __restrict__ Res, float* __restrict__ Out)
{
  __shared__ u16 As[128*32];
  __shared__ u16 Bs[128*32];
  const int tid = threadIdx.x;
  const int lane = tid & 63;
  const int wave = tid >> 6;
  const int wr = wave >> 1, wc = wave & 1;
  const int fr = lane & 15, fg = lane >> 4;
  const int bm = blockIdx.y * 128, bn = blockIdx.x * 128;
  const int srow = tid >> 2, skb = (tid & 3) ^ (srow & 3);   // swizzled source chunk

  f32x4_t acc[4][4] = {};

  for (int e = 0; e < NEXP; e++){
    const u16* A  = Hb  + (size_t)e * T_TOK * MDIM;
    const u16* Bt = WdT + (size_t)e * HID * MDIM;
    const u16* ga0 = A + (size_t)(bm + srow) * MDIM + skb * 8;
    const u16* gb0 = Bt + (size_t)(bn + srow) * MDIM + skb * 8;
    for (int kk = 0; kk < MDIM; kk += 32){
      gload16(ga0 + kk, &As[tid*8]);
      gload16(ga0 + (size_t)64*MDIM + kk, &As[2048 + tid*8]);
      gload16(gb0 + kk, &Bs[tid*8]);
      gload16(gb0 + (size_t)64*MDIM + kk, &Bs[2048 + tid*8]);
      __syncthreads();
      bf16x8_t af[4], bfv[4];
      #pragma unroll
      for (int i = 0; i < 4; i++) af[i]  = ldfsw64(As, wr*64 + i*16 + fr, fg*8);
      #pragma unroll
      for (int i = 0; i < 4; i++) bfv[i] = ldfsw64(Bs, wc*64 + i*16 + fr, fg*8);
      #pragma unroll
      for (int mi = 0; mi < 4; mi++)
        #pragma unroll
        for (int ni = 0; ni < 4; ni++)
          acc[mi][ni] = mfma16(af[mi], bfv[ni], acc[mi][ni]);
      __syncthreads();
    }
  }

  #pragma unroll
  for (int mi = 0; mi < 4; mi++)
    #pragma unroll
    for (int ni = 0; ni < 4; ni++)
      #pragma unroll
      for (int r = 0; r < 4; r++){
        int row = bm + wr*64 + mi*16 + fg*4 + r;
        int col = bn + wc*64 + ni*16 + fr;
        size_t idx = (size_t)row * HID + col;
        Out[idx] = acc[mi][ni][r] + Res[idx];
      }
}

// ---------- launch ----------
// Workspace plan (peak 184.5 MB; ws budget ~256 MB):
//   R0  96MB: Wq/Wk/Wv/Wo 3-way splits  -> (after O-proj) WgT/WuT/WdT
//   R1  24MB: xn1..3 -> vt1..3 -> ynb(8MB)+yn(16MB f32)
//   R2  24MB: q1..3  -> hb[0..24MB)
//   R3  24MB: k1..3  -> ao1..3 -> hb[24..32MB)
//   R4  16MB: vf(f32) -> aof(f32) -> x1(f32, lives to end)

extern "C" void kernel_launch(void* const* d_in, const int* in_sizes, int n_in,
                              void* d_out, int out_size, void* d_ws, size_t ws_size,
                              hipStream_t stream)
{
  const float* hs     = (const float*)d_in[0];
  const float* w_attn = (const float*)d_in[1];
  const float* Wq = (const float*)d_in[2];
  const float* Wk = (const float*)d_in[3];
  const float* Wv = (const float*)d_in[4];
  const float* Wo = (const float*)d_in[5];
  const float* w_moe = (const float*)d_in[6];
  const float* Wr = (const float*)d_in[7];
  const float* Wg = (const float*)d_in[8];
  const float* Wu = (const float*)d_in[9];
  const float* Wd = (const float*)d_in[10];
  float* out = (float*)d_out;
  (void)in_sizes; (void)n_in; (void)out_size; (void)ws_size;

  char* ws = (char*)d_ws;
  const size_t MB = 1024*1024;
  char* R0 = ws;                 // 96 MB
  char* R1 = ws + 96*MB;         // 24 MB
  char* R2 = ws + 120*MB;        // 24 MB
  char* R3 = ws + 144*MB;        // 24 MB
  char* R4 = ws + 168*MB;        // 16 MB
  char* RS = ws + 184*MB;        // small: cw, ct, st

  // phase A pointers (attention)
  const size_t WSLB = (size_t)HID*HID;   // elements per split slab (8 MB)
  u16* W0 = (u16*)R0;
  u16 *Wq1 = W0,          *Wq2 = W0 + WSLB,    *Wq3 = W0 + 2*WSLB;
  u16 *Wk1 = W0 + 3*WSLB, *Wk2 = W0 + 4*WSLB,  *Wk3 = W0 + 5*WSLB;
  u16 *Wv1 = W0 + 6*WSLB, *Wv2 = W0 + 7*WSLB,  *Wv3 = W0 + 8*WSLB;
  u16 *Wo1 = W0 + 9*WSLB, *Wo2 = W0 + 10*WSLB, *Wo3 = W0 + 11*WSLB;
  const size_t TSLB = (size_t)T_TOK*HID;  // elements per activation slab (8 MB)
  u16 *xn1 = (u16*)R1, *xn2 = (u16*)R1 + TSLB, *xn3 = (u16*)R1 + 2*TSLB;
  u16 *q1  = (u16*)R2, *q2  = (u16*)R2 + TSLB, *q3  = (u16*)R2 + 2*TSLB;
  u16 *k1  = (u16*)R3, *k2  = (u16*)R3 + TSLB, *k3  = (u16*)R3 + 2*TSLB;
  u16 *vt1 = xn1, *vt2 = xn2, *vt3 = xn3;        // reuse R1 after xn is dead
  float* vf  = (float*)R4;
  float* aof = (float*)R4;                        // reuse after vtrans
  u16 *ao1 = k1, *ao2 = k2, *ao3 = k3;            // reuse R3 after fattn
  float* x1  = (float*)R4;                        // reuse after split3 (O-proj out)
  // phase B pointers (MoE)
  u16* WgT = (u16*)R0;                            // 32 MB
  u16* WuT = (u16*)R0 + (size_t)NEXP*MDIM*HID;    // 32 MB
  u16* WdT = (u16*)R0 + 2*(size_t)NEXP*MDIM*HID;  // 32 MB
  u16* ynb = (u16*)R1;                            // 8 MB
  float* yn = (float*)(R1 + 8*MB);                // 16 MB
  u16* hb  = (u16*)R2;                            // 32 MB spans R2 + first 8MB of R3
  float* cw = (float*)RS;
  float* ct = (float*)(RS + 256*1024);
  float* stab = (float*)(RS + 512*1024);

  dim3 blk256(256), blkT(32,8), g16(16,16), g64(64,64);

  rope_table_k<<<dim3(SEQ*32/256), blk256, 0, stream>>>(ct, stab);
  convT3<<<g64, blkT, 0, stream>>>(Wq, Wq1, Wq2, Wq3, HID, HID);
  convT3<<<g64, blkT, 0, stream>>>(Wk, Wk1, Wk2, Wk3, HID, HID);
  convT3<<<g64, blkT, 0, stream>>>(Wv, Wv1, Wv2, Wv3, HID, HID);
  convT3<<<g64, blkT, 0, stream>>>(Wo, Wo1, Wo2, Wo3, HID, HID);

  rmsnorm3_k<<<dim3(T_TOK), blk256, 0, stream>>>(hs, w_attn, xn1, xn2, xn3);

  // Q, K with fused rope + split epilogue; V -> f32
  gemm128s<1><<<g16, blk256, 0, stream>>>(xn1,xn2,xn3, Wq1,Wq2,Wq3, nullptr, q1,q2,q3, ct, stab, nullptr);
  gemm128s<1><<<g16, blk256, 0, stream>>>(xn1,xn2,xn3, Wk1,Wk2,Wk3, nullptr, k1,k2,k3, ct, stab, nullptr);
  gemm128s<0><<<g16, blk256, 0, stream>>>(xn1,xn2,xn3, Wv1,Wv2,Wv3, vf, nullptr,nullptr,nullptr, nullptr, nullptr, nullptr);

  vtrans3_k<<<dim3(SEQ/64, BATCH*NHEAD), blk256, 0, stream>>>(vf, vt1, vt2, vt3);   // xn dead

  fattn3_k<<<dim3(BATCH*NHEAD, SEQ/64), blk256, 0, stream>>>(q1,q2,q3, k1,k2,k3, vt1,vt2,vt3, aof);  // vf dead

  split3_k<<<dim3(T_TOK*HID/1024), blk256, 0, stream>>>(aof, ao1, ao2, ao3);        // k dead

  gemm128s<2><<<g16, blk256, 0, stream>>>(ao1,ao2,ao3, Wo1,Wo2,Wo3, x1, nullptr,nullptr,nullptr, nullptr, nullptr, hs);  // aof dead

  // attention weights dead -> convert MoE weights into R0
  convT<<<dim3(MDIM/32, HID/32, NEXP), blkT, 0, stream>>>(Wg, WgT, HID, MDIM);
  convT<<<dim3(MDIM/32, HID/32, NEXP), blkT, 0, stream>>>(Wu, WuT, HID, MDIM);
  convT<<<dim3(HID/32, MDIM/32, NEXP), blkT, 0, stream>>>(Wd, WdT, MDIM, HID);

  rmsnorm_k<<<dim3(T_TOK), blk256, 0, stream>>>(x1, w_moe, ynb, yn);   // vt dead
  router_k<<<dim3(T_TOK), dim3(64), 0, stream>>>(yn, Wr, cw);

  gemm_gateup<<<dim3(MDIM/64, T_TOK/128, NEXP), blk256, 0, stream>>>(ynb, WgT, WuT, cw, hb);  // q, ao dead
  gemm_down<<<g16, blk256, 0, stream>>>(hb, WdT, x1, out);
}

// Round 5
// 1338.090 us; speedup vs baseline: 1.8434x; 1.1165x over previous
//
#include <hip/hip_runtime.h>
#include <hip/hip_bf16.h>
#include <cstdint>

typedef unsigned short u16;
typedef __bf16 bf16x4_t __attribute__((ext_vector_type(4)));
typedef __bf16 bf16x8_t __attribute__((ext_vector_type(8)));
typedef float f32x4_t __attribute__((ext_vector_type(4)));
typedef unsigned short us4_t __attribute__((ext_vector_type(4)));

#define BATCH 2
#define SEQ 1024
#define HID 2048
#define NHEAD 32
#define NEXP 8
#define MDIM 1024
#define T_TOK (BATCH*SEQ)   // 2048

// ---------- helpers ----------

__device__ __forceinline__ void gload16(const void* g, void* l){
  __builtin_amdgcn_global_load_lds((__attribute__((address_space(1))) void*)(uintptr_t)g,
                                   (__attribute__((address_space(3))) void*)l, 16, 0, 0);
}

// 8-bf16 MFMA fragment as two b64 halves (k = fg*4+e and +16; bijective k-map
// used identically on A and B sides -> product invariant).
__device__ __forceinline__ bf16x8_t ldfrag(const u16* lo){
  bf16x4_t a = *(const bf16x4_t*)lo;
  bf16x4_t b = *(const bf16x4_t*)(lo + 16);
  return __builtin_shufflevector(a, b, 0,1,2,3,4,5,6,7);
}

// Swizzled fragment read, 128B LDS rows (fattn K/V/P): byte ^= (row&7)<<4.
// Pairs with staging-source chunk permute sp^=(row&7). 16-way -> 4-way conflict.
__device__ __forceinline__ bf16x8_t ldfsw128(const u16* base, int row, int colbyte){
  const char* p = (const char*)base + row*128;
  int sw = (row & 7) << 4;
  bf16x4_t a = *(const bf16x4_t*)(p + (colbyte ^ sw));
  bf16x4_t b = *(const bf16x4_t*)(p + ((colbyte + 32) ^ sw));
  return __builtin_shufflevector(a, b, 0,1,2,3,4,5,6,7);
}

// Swizzled fragment read, 64B LDS rows (GEMM tiles, BK=32): byte ^= (row&3)<<4.
// Pairs with staging-source chunk permute skb^=(row&3). 8-way -> 4-way conflict.
__device__ __forceinline__ bf16x8_t ldfsw64(const u16* base, int row, int colbyte){
  const char* p = (const char*)base + row*64;
  int sw = (row & 3) << 4;
  bf16x4_t a = *(const bf16x4_t*)(p + (colbyte ^ sw));
  bf16x4_t b = *(const bf16x4_t*)(p + ((colbyte + 32) ^ sw));
  return __builtin_shufflevector(a, b, 0,1,2,3,4,5,6,7);
}

__device__ __forceinline__ f32x4_t mfma16(bf16x8_t a, bf16x8_t b, f32x4_t c){
  return __builtin_amdgcn_mfma_f32_16x16x32_bf16(a, b, c, 0, 0, 0);
}

__device__ __forceinline__ u16 f2b(float f){
  __hip_bfloat16 h = __float2bfloat16(f);
  return __builtin_bit_cast(u16, h);
}
__device__ __forceinline__ float b2f(u16 b){
  return __builtin_bit_cast(float, (unsigned int)b << 16);
}
// 3-way bf16 split: v ~= b1 + b2 + b3 with |residual| <= 2^-27 |v|
__device__ __forceinline__ void split3v(float v, u16& b1, u16& b2, u16& b3){
  b1 = f2b(v); float f1 = b2f(b1);
  float r1 = v - f1;
  b2 = f2b(r1); float f2 = b2f(b2);
  b3 = f2b(r1 - f2);
}

// ---------- weight convert+transpose (single bf16, MoE): f32 [R][C] -> bf16 [C][R] ----------

__global__ __launch_bounds__(256)
void convT(const float* __restrict__ in, u16* __restrict__ out, int R, int C)
{
  __shared__ float tile[32][33];
  int bz = blockIdx.z;
  const float* ip = in + (size_t)bz * R * C;
  u16* op = out + (size_t)bz * R * C;
  int tx = threadIdx.x, ty = threadIdx.y;   // block (32,8)
  int c0 = blockIdx.x*32, r0 = blockIdx.y*32;
  #pragma unroll
  for (int i = 0; i < 4; i++)
    tile[ty + i*8][tx] = ip[(size_t)(r0 + ty + i*8) * C + c0 + tx];
  __syncthreads();
  #pragma unroll
  for (int i = 0; i < 4; i++)
    op[(size_t)(c0 + ty + i*8) * R + r0 + tx] = f2b(tile[tx][ty + i*8]);
}

// ---------- weight convert+transpose, 3-way split (attention weights) ----------

__global__ __launch_bounds__(256)
void convT3(const float* __restrict__ in, u16* __restrict__ o1, u16* __restrict__ o2,
            u16* __restrict__ o3, int R, int C)
{
  __shared__ float tile[32][33];
  const float* ip = in;
  int tx = threadIdx.x, ty = threadIdx.y;
  int c0 = blockIdx.x*32, r0 = blockIdx.y*32;
  #pragma unroll
  for (int i = 0; i < 4; i++)
    tile[ty + i*8][tx] = ip[(size_t)(r0 + ty + i*8) * C + c0 + tx];
  __syncthreads();
  #pragma unroll
  for (int i = 0; i < 4; i++){
    u16 b1, b2, b3;
    split3v(tile[tx][ty + i*8], b1, b2, b3);
    size_t idx = (size_t)(c0 + ty + i*8) * R + r0 + tx;
    o1[idx] = b1; o2[idx] = b2; o3[idx] = b3;
  }
}

// ---------- RMSNorm -> 3-way split (attention input) ----------

__global__ __launch_bounds__(256)
void rmsnorm3_k(const float* __restrict__ x, const float* __restrict__ w,
                u16* __restrict__ o1, u16* __restrict__ o2, u16* __restrict__ o3)
{
  int row = blockIdx.x;
  const float* xr = x + (size_t)row * HID;
  int base = threadIdx.x * 8;
  float4 a = *(const float4*)(xr + base);
  float4 b = *(const float4*)(xr + base + 4);
  float ss = a.x*a.x + a.y*a.y + a.z*a.z + a.w*a.w
           + b.x*b.x + b.y*b.y + b.z*b.z + b.w*b.w;
  #pragma unroll
  for (int off = 32; off; off >>= 1) ss += __shfl_down(ss, off);
  __shared__ float red[4];
  if ((threadIdx.x & 63) == 0) red[threadIdx.x >> 6] = ss;
  __syncthreads();
  float tot = red[0] + red[1] + red[2] + red[3];
  float rs = (float)(1.0 / sqrt((double)tot * (1.0/2048.0) + 1e-5));
  float4 wa = *(const float4*)(w + base);
  float4 wb = *(const float4*)(w + base + 4);
  float o[8];
  o[0]=a.x*rs*wa.x; o[1]=a.y*rs*wa.y; o[2]=a.z*rs*wa.z; o[3]=a.w*rs*wa.w;
  o[4]=b.x*rs*wb.x; o[5]=b.y*rs*wb.y; o[6]=b.z*rs*wb.z; o[7]=b.w*rs*wb.w;
  us4_t v1[2], v2[2], v3[2];
  #pragma unroll
  for (int j = 0; j < 8; j++){
    u16 b1, b2, b3; split3v(o[j], b1, b2, b3);
    v1[j>>2][j&3] = b1; v2[j>>2][j&3] = b2; v3[j>>2][j&3] = b3;
  }
  size_t idx = (size_t)row*HID + base;
  *(us4_t*)&o1[idx] = v1[0]; *(us4_t*)&o1[idx+4] = v1[1];
  *(us4_t*)&o2[idx] = v2[0]; *(us4_t*)&o2[idx+4] = v2[1];
  *(us4_t*)&o3[idx] = v3[0]; *(us4_t*)&o3[idx+4] = v3[1];
}

// ---------- RMSNorm (MoE): bf16 out + f32 out + residual passthrough to Out ----------

__global__ __launch_bounds__(256)
void rmsnorm_k(const float* __restrict__ x, const float* __restrict__ w,
               u16* __restrict__ ob, float* __restrict__ of, float* __restrict__ oi)
{
  int row = blockIdx.x;
  const float* xr = x + (size_t)row * HID;
  int base = threadIdx.x * 8;
  float4 a = *(const float4*)(xr + base);
  float4 b = *(const float4*)(xr + base + 4);
  float ss = a.x*a.x + a.y*a.y + a.z*a.z + a.w*a.w
           + b.x*b.x + b.y*b.y + b.z*b.z + b.w*b.w;
  #pragma unroll
  for (int off = 32; off; off >>= 1) ss += __shfl_down(ss, off);
  __shared__ float red[4];
  if ((threadIdx.x & 63) == 0) red[threadIdx.x >> 6] = ss;
  __syncthreads();
  float tot = red[0] + red[1] + red[2] + red[3];
  float rs = (float)(1.0 / sqrt((double)tot * (1.0/2048.0) + 1e-5));
  float4 wa = *(const float4*)(w + base);
  float4 wb = *(const float4*)(w + base + 4);
  float o[8];
  o[0]=a.x*rs*wa.x; o[1]=a.y*rs*wa.y; o[2]=a.z*rs*wa.z; o[3]=a.w*rs*wa.w;
  o[4]=b.x*rs*wb.x; o[5]=b.y*rs*wb.y; o[6]=b.z*rs*wb.z; o[7]=b.w*rs*wb.w;
  us4_t p0, p1;
  p0.x=f2b(o[0]); p0.y=f2b(o[1]); p0.z=f2b(o[2]); p0.w=f2b(o[3]);
  p1.x=f2b(o[4]); p1.y=f2b(o[5]); p1.z=f2b(o[6]); p1.w=f2b(o[7]);
  *(us4_t*)&ob[(size_t)row*HID + base] = p0;
  *(us4_t*)&ob[(size_t)row*HID + base + 4] = p1;
  float* orow = of + (size_t)row*HID + base;
  *(float4*)orow = make_float4(o[0],o[1],o[2],o[3]);
  *(float4*)(orow+4) = make_float4(o[4],o[5],o[6],o[7]);
  // init final output with the residual (down-GEMM atomically accumulates onto it)
  float* irow = oi + (size_t)row*HID + base;
  *(float4*)irow = a;
  *(float4*)(irow+4) = b;
}

// ---------- RoPE table (f64 math -> f32) ----------

__global__ void rope_table_k(float* ct, float* st){
  int i = blockIdx.x*256 + threadIdx.x;   // SEQ*32
  int s = i >> 5, j = i & 31;
  double invf = exp(-(double)j / 32.0 * log(10000.0));
  double ang = (double)s * invf;
  ct[i] = (float)cos(ang);
  st[i] = (float)sin(ang);
}

// ---------- split GEMM: C = A @ Bt^T with 3-way bf16 splits (6 products) ----------
// EPI: 0 = f32 out; 1 = rope + 3-way-split out; 2 = f32 + residual

template<int EPI>
__global__ __launch_bounds__(256, 2)
void gemm128s(const u16* __restrict__ A1, const u16* __restrict__ A2, const u16* __restrict__ A3,
              const u16* __restrict__ B1, const u16* __restrict__ B2, const u16* __restrict__ B3,
              float* __restrict__ Cf, u16* __restrict__ O1, u16* __restrict__ O2, u16* __restrict__ O3,
              const float* __restrict__ ct, const float* __restrict__ st,
              const float* __restrict__ Res)
{
  __shared__ u16 As[3][128*32];
  __shared__ u16 Bs[3][128*32];
  const int tid = threadIdx.x;
  const int lane = tid & 63;
  const int wave = tid >> 6;
  const int wr = wave >> 1, wc = wave & 1;
  const int fr = lane & 15, fg = lane >> 4;
  const int bm = blockIdx.y * 128, bn = blockIdx.x * 128;

  f32x4_t acc[4][4] = {};

  const int srow = tid >> 2, skb = (tid & 3) ^ (srow & 3);   // swizzled source chunk
  const u16* Ap[3] = {A1, A2, A3};
  const u16* Bp[3] = {B1, B2, B3};
  const u16* gA[3]; const u16* gB[3];
  #pragma unroll
  for (int t = 0; t < 3; t++){
    gA[t] = Ap[t] + (size_t)(bm + srow) * HID + skb * 8;
    gB[t] = Bp[t] + (size_t)(bn + srow) * HID + skb * 8;
  }

  for (int kk = 0; kk < HID; kk += 32){
    #pragma unroll
    for (int t = 0; t < 3; t++){
      gload16(gA[t] + kk,                    &As[t][tid*8]);
      gload16(gA[t] + (size_t)64*HID + kk,   &As[t][2048 + tid*8]);
      gload16(gB[t] + kk,                    &Bs[t][tid*8]);
      gload16(gB[t] + (size_t)64*HID + kk,   &Bs[t][2048 + tid*8]);
    }
    __syncthreads();
    bf16x8_t af[3][4], bfv[3][4];
    #pragma unroll
    for (int t = 0; t < 3; t++)
      #pragma unroll
      for (int i = 0; i < 4; i++){
        af[t][i]  = ldfsw64(As[t], wr*64 + i*16 + fr, fg*8);
        bfv[t][i] = ldfsw64(Bs[t], wc*64 + i*16 + fr, fg*8);
      }
    // 6 products, smallest first: a3b1, a2b2, a1b3, a2b1, a1b2, a1b1
    const int pA[6] = {2,1,0,1,0,0};
    const int pB[6] = {0,1,2,0,1,0};
    #pragma unroll
    for (int p = 0; p < 6; p++)
      #pragma unroll
      for (int mi = 0; mi < 4; mi++)
        #pragma unroll
        for (int ni = 0; ni < 4; ni++)
          acc[mi][ni] = mfma16(af[pA[p]][mi], bfv[pB[p]][ni], acc[mi][ni]);
    __syncthreads();
  }

  if (EPI == 1){
    #pragma unroll
    for (int mi = 0; mi < 4; mi++)
      #pragma unroll
      for (int r = 0; r < 4; r++){
        int row = bm + wr*64 + mi*16 + fg*4 + r;
        int s = row & (SEQ-1);
        #pragma unroll
        for (int ni = 0; ni < 2; ni++){
          int dlo = ni*16 + fr;   // 0..31 within head
          float c  = ct[s*32 + dlo];
          float sn = st[s*32 + dlo];
          float xl = acc[mi][ni][r], xh = acc[mi][ni+2][r];
          float ol = xl*c - xh*sn;
          float oh = xh*c + xl*sn;
          size_t idx = (size_t)row * HID + bn + wc*64 + ni*16 + fr;
          u16 b1, b2, b3;
          split3v(ol, b1, b2, b3); O1[idx] = b1;    O2[idx] = b2;    O3[idx] = b3;
          split3v(oh, b1, b2, b3); O1[idx+32] = b1; O2[idx+32] = b2; O3[idx+32] = b3;
        }
      }
  } else {
    #pragma unroll
    for (int mi = 0; mi < 4; mi++)
      #pragma unroll
      for (int ni = 0; ni < 4; ni++)
        #pragma unroll
        for (int r = 0; r < 4; r++){
          int row = bm + wr*64 + mi*16 + fg*4 + r;
          int col = bn + wc*64 + ni*16 + fr;
          size_t idx = (size_t)row * HID + col;
          if (EPI == 0) Cf[idx] = acc[mi][ni][r];
          else          Cf[idx] = acc[mi][ni][r] + Res[idx];
        }
  }
}

// ---------- elementwise 3-way split (attention output) ----------

__global__ __launch_bounds__(256)
void split3_k(const float* __restrict__ in, u16* __restrict__ o1, u16* __restrict__ o2,
              u16* __restrict__ o3)
{
  size_t i = ((size_t)blockIdx.x*256 + threadIdx.x) * 4;
  float4 v = *(const float4*)(in + i);
  us4_t v1, v2, v3;
  u16 b1, b2, b3;
  split3v(v.x, b1,b2,b3); v1.x=b1; v2.x=b2; v3.x=b3;
  split3v(v.y, b1,b2,b3); v1.y=b1; v2.y=b2; v3.y=b3;
  split3v(v.z, b1,b2,b3); v1.z=b1; v2.z=b2; v3.z=b3;
  split3v(v.w, b1,b2,b3); v1.w=b1; v2.w=b2; v3.w=b3;
  *(us4_t*)&o1[i] = v1; *(us4_t*)&o2[i] = v2; *(us4_t*)&o3[i] = v3;
}

// ---------- V transpose + split: f32 [T][H] -> per (b,h) bf16x3 [64 d][1024 s] ----------

__global__ __launch_bounds__(256)
void vtrans3_k(const float* __restrict__ vf, u16* __restrict__ t1, u16* __restrict__ t2,
               u16* __restrict__ t3)
{
  __shared__ float t[64][65];
  int st0 = blockIdx.x * 64;
  int bh = blockIdx.y;
  int b = bh >> 5, h = bh & 31;
  int tid = threadIdx.x;
  #pragma unroll
  for (int i = 0; i < 4; i++){
    int idx = tid + i*256;                // 1024 float4 chunks
    int s = idx >> 4, dc = (idx & 15) * 4;
    float4 v = *(const float4*)&vf[(size_t)(b*SEQ + st0 + s) * HID + h*64 + dc];
    t[dc+0][s] = v.x; t[dc+1][s] = v.y; t[dc+2][s] = v.z; t[dc+3][s] = v.w;
  }
  __syncthreads();
  #pragma unroll
  for (int i = 0; i < 4; i++){
    int idx = tid + i*256;
    int d = idx >> 4, sc = (idx & 15) * 4;
    us4_t v1, v2, v3;
    #pragma unroll
    for (int j = 0; j < 4; j++){
      u16 b1, b2, b3; split3v(t[d][sc+j], b1, b2, b3);
      v1[j]=b1; v2[j]=b2; v3[j]=b3;
    }
    size_t base = ((size_t)bh*64 + d)*SEQ + st0 + sc;
    *(us4_t*)&t1[base] = v1; *(us4_t*)&t2[base] = v2; *(us4_t*)&t3[base] = v3;
  }
}

// ---------- flash attention, split-precision (causal), f32 out ----------

__global__ __launch_bounds__(256)
void fattn3_k(const u16* __restrict__ q1, const u16* __restrict__ q2, const u16* __restrict__ q3,
              const u16* __restrict__ k1, const u16* __restrict__ k2, const u16* __restrict__ k3,
              const u16* __restrict__ v1, const u16* __restrict__ v2, const u16* __restrict__ v3,
              float* __restrict__ aof)
{
  __shared__ u16 Ks[3][64*64];     // 24KB
  __shared__ u16 Vs[3][64*64];     // 24KB
  __shared__ u16 Ps[2][4][16*64];  // 16KB  -> 64KB total
  const int bh = blockIdx.x, qt = blockIdx.y;
  const int b = bh >> 5, h = bh & 31;
  const int tid = threadIdx.x, lane = tid & 63, wave = tid >> 6;
  const int fr = lane & 15, fg = lane >> 4;

  const size_t qrow = (size_t)(b*SEQ + qt*64 + wave*16 + fr);
  const u16* qp[3] = { q1 + qrow*HID + h*64, q2 + qrow*HID + h*64, q3 + qrow*HID + h*64 };
  bf16x8_t aq[3][2];
  #pragma unroll
  for (int t = 0; t < 3; t++)
    #pragma unroll
    for (int ks = 0; ks < 2; ks++) aq[t][ks] = ldfrag(qp[t] + ks*32 + fg*4);

  f32x4_t oacc[4] = {};
  float m_r[4], l_r[4];
  #pragma unroll
  for (int r = 0; r < 4; r++){ m_r[r] = -1e30f; l_r[r] = 0.f; }

  const int sr = tid >> 3, sp = (tid & 7) ^ (sr & 7);   // swizzled source chunk
  const u16* kb[3] = { k1 + ((size_t)(b*SEQ) + sr)*HID + h*64 + sp*8,
                       k2 + ((size_t)(b*SEQ) + sr)*HID + h*64 + sp*8,
                       k3 + ((size_t)(b*SEQ) + sr)*HID + h*64 + sp*8 };
  const u16* vb[3] = { v1 + ((size_t)bh*64 + sr)*SEQ + sp*8,
                       v2 + ((size_t)bh*64 + sr)*SEQ + sp*8,
                       v3 + ((size_t)bh*64 + sr)*SEQ + sp*8 };

  for (int kt = 0; kt <= qt; kt++){
    #pragma unroll
    for (int t = 0; t < 3; t++){
      gload16(kb[t] + (size_t)(kt*64) * HID,    &Ks[t][tid*8]);
      gload16(kb[t] + (size_t)(kt*64+32) * HID, &Ks[t][2048 + tid*8]);
      gload16(vb[t] + kt*64,                    &Vs[t][tid*8]);
      gload16(vb[t] + (size_t)32*SEQ + kt*64,   &Vs[t][2048 + tid*8]);
    }
    __syncthreads();

    f32x4_t sc[4] = {};
    #pragma unroll
    for (int nf = 0; nf < 4; nf++)
      #pragma unroll
      for (int ks = 0; ks < 2; ks++){
        int krow = nf*16 + fr, kcb = ks*64 + fg*8;
        bf16x8_t bk0 = ldfsw128(Ks[0], krow, kcb);
        bf16x8_t bk1 = ldfsw128(Ks[1], krow, kcb);
        bf16x8_t bk2 = ldfsw128(Ks[2], krow, kcb);
        sc[nf] = mfma16(aq[2][ks], bk0, sc[nf]);
        sc[nf] = mfma16(aq[1][ks], bk1, sc[nf]);
        sc[nf] = mfma16(aq[0][ks], bk2, sc[nf]);
        sc[nf] = mfma16(aq[1][ks], bk0, sc[nf]);
        sc[nf] = mfma16(aq[0][ks], bk1, sc[nf]);
        sc[nf] = mfma16(aq[0][ks], bk0, sc[nf]);
      }

    float nm[4] = {-1e30f,-1e30f,-1e30f,-1e30f};
    #pragma unroll
    for (int nf = 0; nf < 4; nf++)
      #pragma unroll
      for (int r = 0; r < 4; r++){
        float v = sc[nf][r] * 0.125f;
        if (kt == qt && nf*16 + fr > wave*16 + fg*4 + r) v = -1e30f;
        sc[nf][r] = v;
        nm[r] = fmaxf(nm[r], v);
      }
    #pragma unroll
    for (int r = 0; r < 4; r++)
      #pragma unroll
      for (int msk = 8; msk; msk >>= 1) nm[r] = fmaxf(nm[r], __shfl_xor(nm[r], msk));

    #pragma unroll
    for (int r = 0; r < 4; r++){
      float mn = fmaxf(m_r[r], nm[r]);
      float f = __expf(m_r[r] - mn);
      m_r[r] = mn;
      float rsum = 0.f;
      #pragma unroll
      for (int nf = 0; nf < 4; nf++){
        float pv = __expf(sc[nf][r] - mn);
        sc[nf][r] = pv;
        rsum += pv;
      }
      #pragma unroll
      for (int msk = 8; msk; msk >>= 1) rsum += __shfl_xor(rsum, msk);
      l_r[r] = l_r[r]*f + rsum;
      #pragma unroll
      for (int df = 0; df < 4; df++) oacc[df][r] *= f;
    }

    // P 2-way split to LDS (swizzled writes matching ldfsw128 reads)
    #pragma unroll
    for (int nf = 0; nf < 4; nf++)
      #pragma unroll
      for (int r = 0; r < 4; r++){
        float pv = sc[nf][r];
        u16 b1 = f2b(pv);
        float f1 = b2f(b1);
        u16 b2 = f2b(pv - f1);
        int prow = fg*4 + r;
        int pbyte = (nf*32 + fr*2) ^ ((prow & 7) << 4);
        *(u16*)((char*)&Ps[0][wave][0] + prow*128 + pbyte) = b1;
        *(u16*)((char*)&Ps[1][wave][0] + prow*128 + pbyte) = b2;
      }

    #pragma unroll
    for (int ks = 0; ks < 2; ks++){
      bf16x8_t pa0 = ldfsw128(&Ps[0][wave][0], fr, ks*64 + fg*8);
      bf16x8_t pa1 = ldfsw128(&Ps[1][wave][0], fr, ks*64 + fg*8);
      #pragma unroll
      for (int df = 0; df < 4; df++){
        int vrow = df*16 + fr, vcb = ks*64 + fg*8;
        bf16x8_t bv0 = ldfsw128(Vs[0], vrow, vcb);
        bf16x8_t bv1 = ldfsw128(Vs[1], vrow, vcb);
        bf16x8_t bv2 = ldfsw128(Vs[2], vrow, vcb);
        oacc[df] = mfma16(pa0, bv2, oacc[df]);   // p1 v3
        oacc[df] = mfma16(pa1, bv1, oacc[df]);   // p2 v2
        oacc[df] = mfma16(pa1, bv0, oacc[df]);   // p2 v1
        oacc[df] = mfma16(pa0, bv1, oacc[df]);   // p1 v2
        oacc[df] = mfma16(pa0, bv0, oacc[df]);   // p1 v1
      }
    }
    __syncthreads();
  }

  #pragma unroll
  for (int r = 0; r < 4; r++){
    float inv = 1.f / l_r[r];
    int orow = b*SEQ + qt*64 + wave*16 + fg*4 + r;
    #pragma unroll
    for (int df = 0; df < 4; df++)
      aof[(size_t)orow * HID + h*64 + df*16 + fr] = oacc[df][r] * inv;
  }
}

// ---------- router + scatter: f64 logits, top-2, compact per-expert lists ----------

__global__ __launch_bounds__(64)
void router_scatter_k(const float* __restrict__ yn, const float* __restrict__ Wr,
                      int* __restrict__ tok_list, float* __restrict__ w_list,
                      int* __restrict__ cur){
  int row = blockIdx.x;
  int lane = threadIdx.x;
  const float* xr = yn + (size_t)row * HID;
  double acc[8] = {};
  for (int j = lane; j < HID; j += 64){
    double xv = (double)xr[j];
    const float* wr = Wr + (size_t)j*8;
    float4 w0 = *(const float4*)wr;
    float4 w1 = *(const float4*)(wr + 4);
    acc[0] += xv*w0.x; acc[1] += xv*w0.y; acc[2] += xv*w0.z; acc[3] += xv*w0.w;
    acc[4] += xv*w1.x; acc[5] += xv*w1.y; acc[6] += xv*w1.z; acc[7] += xv*w1.w;
  }
  #pragma unroll
  for (int e = 0; e < 8; e++)
    #pragma unroll
    for (int off = 32; off; off >>= 1) acc[e] += __shfl_down(acc[e], off);
  if (lane == 0){
    double mx = acc[0];
    #pragma unroll
    for (int e = 1; e < 8; e++) mx = fmax(mx, acc[e]);
    double p[8];
    #pragma unroll
    for (int e = 0; e < 8; e++) p[e] = exp(acc[e] - mx);
    int i1 = 0;
    #pragma unroll
    for (int e = 1; e < 8; e++) if (p[e] > p[i1]) i1 = e;
    int i2 = (i1 == 0) ? 1 : 0;
    #pragma unroll
    for (int e = 0; e < 8; e++) if (e != i1 && p[e] > p[i2]) i2 = e;
    double s2 = p[i1] + p[i2];
    int pos1 = atomicAdd(&cur[i1], 1);
    tok_list[i1*T_TOK + pos1] = row;
    w_list[i1*T_TOK + pos1] = (float)(p[i1] / s2);
    int pos2 = atomicAdd(&cur[i2], 1);
    tok_list[i2*T_TOK + pos2] = row;
    w_list[i2*T_TOK + pos2] = (float)(p[i2] / s2);
  }
}

// pad each expert's list to a multiple of 128 with (token 0, weight 0)
__global__ __launch_bounds__(128)
void pad_k(const int* __restrict__ cur, int* __restrict__ tok_list,
           float* __restrict__ w_list, int* __restrict__ cnt_pad){
  int e = blockIdx.x;
  int c = cur[e];
  int cp = (c + 127) & ~127;
  for (int i = c + threadIdx.x; i < cp; i += 128){
    tok_list[e*T_TOK + i] = 0;
    w_list[e*T_TOK + i] = 0.f;
  }
  if (threadIdx.x == 0) cnt_pad[e] = cp;
}

// ---------- sparse fused gate+up GEMM: h = silu(g)*u*w over compact token lists ----------

__global__ __launch_bounds__(256, 2)
void gemm_gateup_sp(const u16* __restrict__ A, const u16* __restrict__ WgT, const u16* __restrict__ WuT,
                    const int* __restrict__ tok_list, const float* __restrict__ w_list,
                    const int* __restrict__ cnt_pad, u16* __restrict__ Hb)
{
  const int e = blockIdx.z;
  const int bm = blockIdx.y * 128;   // position within expert list
  if (bm >= cnt_pad[e]) return;
  __shared__ u16 As[128*32];
  __shared__ u16 Bg[64*32];
  __shared__ u16 Bu[64*32];
  const int tid = threadIdx.x;
  const int lane = tid & 63;
  const int wave = tid >> 6;
  const int wr = wave >> 1, wc = wave & 1;
  const int fr = lane & 15, fg = lane >> 4;
  const int bn = blockIdx.x * 64;    // M cols

  f32x4_t ag[4][2] = {}, au[4][2] = {};

  const int srow = tid >> 2, skb = (tid & 3) ^ (srow & 3);   // swizzled source chunk
  const int tok0 = tok_list[e*T_TOK + bm + srow];
  const int tok1 = tok_list[e*T_TOK + bm + srow + 64];
  const u16* ga0 = A + (size_t)tok0 * HID + skb * 8;
  const u16* ga1 = A + (size_t)tok1 * HID + skb * 8;
  const u16* gg0 = WgT + ((size_t)e*MDIM + bn + srow) * HID + skb * 8;
  const u16* gu0 = WuT + ((size_t)e*MDIM + bn + srow) * HID + skb * 8;

  for (int kk = 0; kk < HID; kk += 32){
    gload16(ga0 + kk, &As[tid*8]);
    gload16(ga1 + kk, &As[2048 + tid*8]);
    gload16(gg0 + kk, &Bg[tid*8]);
    gload16(gu0 + kk, &Bu[tid*8]);
    __syncthreads();
    bf16x8_t af[4], bg[2], bu[2];
    #pragma unroll
    for (int i = 0; i < 4; i++) af[i] = ldfsw64(As, wr*64 + i*16 + fr, fg*8);
    #pragma unroll
    for (int j = 0; j < 2; j++){
      bg[j] = ldfsw64(Bg, wc*32 + j*16 + fr, fg*8);
      bu[j] = ldfsw64(Bu, wc*32 + j*16 + fr, fg*8);
    }
    #pragma unroll
    for (int mi = 0; mi < 4; mi++)
      #pragma unroll
      for (int nj = 0; nj < 2; nj++){
        ag[mi][nj] = mfma16(af[mi], bg[nj], ag[mi][nj]);
        au[mi][nj] = mfma16(af[mi], bu[nj], au[mi][nj]);
      }
    __syncthreads();
  }

  #pragma unroll
  for (int mi = 0; mi < 4; mi++)
    #pragma unroll
    for (int nj = 0; nj < 2; nj++)
      #pragma unroll
      for (int r = 0; r < 4; r++){
        int pos = bm + wr*64 + mi*16 + fg*4 + r;
        int col = bn + wc*32 + nj*16 + fr;
        float g = ag[mi][nj][r], u = au[mi][nj][r];
        float h = g / (1.0f + __expf(-g)) * u * w_list[e*T_TOK + pos];
        Hb[((size_t)e*T_TOK + pos)*MDIM + col] = f2b(h);
      }
}

// ---------- sparse down GEMM: atomic-accumulate expert outputs onto Out ----------

__global__ __launch_bounds__(256, 2)
void gemm_down_sp(const u16* __restrict__ Hb, const u16* __restrict__ WdT,
                  const int* __restrict__ tok_list, const int* __restrict__ cnt_pad,
                  float* __restrict__ Out)
{
  const int e = blockIdx.z;
  const int bm = blockIdx.y * 128;
  if (bm >= cnt_pad[e]) return;
  __shared__ u16 As[128*32];
  __shared__ u16 Bs[128*32];
  const int tid = threadIdx.x;
  const int lane = tid & 63;
  const int wave = tid >> 6;
  const int wr = wave >> 1, wc = wave & 1;
  const int fr = lane & 15, fg = lane >> 4;
  const int bn = blockIdx.x * 128;
  const int srow = tid >> 2, skb = (tid & 3) ^ (srow & 3);

  f32x4_t acc[4][4] = {};

  const u16* A  = Hb  + (size_t)e * T_TOK * MDIM;
  const u16* Bt = WdT + (size_t)e * HID * MDIM;
  const u16* ga0 = A + (size_t)(bm + srow) * MDIM + skb * 8;
  const u16* gb0 = Bt + (size_t)(bn + srow) * MDIM + skb * 8;
  for (int kk = 0; kk < MDIM; kk += 32){
    gload16(ga0 + kk, &As[tid*8]);
    gload16(ga0 + (size_t)64*MDIM + kk, &As[2048 + tid*8]);
    gload16(gb0 + kk, &Bs[tid*8]);
    gload16(gb0 + (size_t)64*MDIM + kk, &Bs[2048 + tid*8]);
    __syncthreads();
    bf16x8_t af[4], bfv[4];
    #pragma unroll
    for (int i = 0; i < 4; i++) af[i]  = ldfsw64(As, wr*64 + i*16 + fr, fg*8);
    #pragma unroll
    for (int i = 0; i < 4; i++) bfv[i] = ldfsw64(Bs, wc*64 + i*16 + fr, fg*8);
    #pragma unroll
    for (int mi = 0; mi < 4; mi++)
      #pragma unroll
      for (int ni = 0; ni < 4; ni++)
        acc[mi][ni] = mfma16(af[mi], bfv[ni], acc[mi][ni]);
    __syncthreads();
  }

  #pragma unroll
  for (int mi = 0; mi < 4; mi++)
    #pragma unroll
    for (int r = 0; r < 4; r++){
      int pos = bm + wr*64 + mi*16 + fg*4 + r;
      int tok = tok_list[e*T_TOK + pos];
      #pragma unroll
      for (int ni = 0; ni < 4; ni++){
        int col = bn + wc*64 + ni*16 + fr;
        atomicAdd(&Out[(size_t)tok * HID + col], acc[mi][ni][r]);
      }
    }
}

// ---------- launch ----------
// Workspace plan (peak ~185 MB; ws budget ~256 MB):
//   R0  96MB: Wq/Wk/Wv/Wo 3-way splits  -> (after O-proj) WgT/WuT/WdT
//   R1  24MB: xn1..3 -> vt1..3 -> ynb(8MB)+yn(16MB f32)
//   R2  24MB: q1..3  -> hb[0..24MB)
//   R3  24MB: k1..3  -> ao1..3 -> hb[24..32MB)
//   R4  16MB: vf(f32) -> aof(f32) -> x1(f32, lives to end)
//   RS: tok_list/w_list/cur/cnt_pad/rope tables

extern "C" void kernel_launch(void* const* d_in, const int* in_sizes, int n_in,
                              void* d_out, int out_size, void* d_ws, size_t ws_size,
                              hipStream_t stream)
{
  const float* hs     = (const float*)d_in[0];
  const float* w_attn = (const float*)d_in[1];
  const float* Wq = (const float*)d_in[2];
  const float* Wk = (const float*)d_in[3];
  const float* Wv = (const float*)d_in[4];
  const float* Wo = (const float*)d_in[5];
  const float* w_moe = (const float*)d_in[6];
  const float* Wr = (const float*)d_in[7];
  const float* Wg = (const float*)d_in[8];
  const float* Wu = (const float*)d_in[9];
  const float* Wd = (const float*)d_in[10];
  float* out = (float*)d_out;
  (void)in_sizes; (void)n_in; (void)out_size; (void)ws_size;

  char* ws = (char*)d_ws;
  const size_t MB = 1024*1024;
  char* R0 = ws;                 // 96 MB
  char* R1 = ws + 96*MB;         // 24 MB
  char* R2 = ws + 120*MB;        // 24 MB
  char* R3 = ws + 144*MB;        // 24 MB
  char* R4 = ws + 168*MB;        // 16 MB
  char* RS = ws + 184*MB;        // small buffers

  // phase A pointers (attention)
  const size_t WSLB = (size_t)HID*HID;   // elements per split slab (8 MB)
  u16* W0 = (u16*)R0;
  u16 *Wq1 = W0,          *Wq2 = W0 + WSLB,    *Wq3 = W0 + 2*WSLB;
  u16 *Wk1 = W0 + 3*WSLB, *Wk2 = W0 + 4*WSLB,  *Wk3 = W0 + 5*WSLB;
  u16 *Wv1 = W0 + 6*WSLB, *Wv2 = W0 + 7*WSLB,  *Wv3 = W0 + 8*WSLB;
  u16 *Wo1 = W0 + 9*WSLB, *Wo2 = W0 + 10*WSLB, *Wo3 = W0 + 11*WSLB;
  const size_t TSLB = (size_t)T_TOK*HID;  // elements per activation slab (8 MB)
  u16 *xn1 = (u16*)R1, *xn2 = (u16*)R1 + TSLB, *xn3 = (u16*)R1 + 2*TSLB;
  u16 *q1  = (u16*)R2, *q2  = (u16*)R2 + TSLB, *q3  = (u16*)R2 + 2*TSLB;
  u16 *k1  = (u16*)R3, *k2  = (u16*)R3 + TSLB, *k3  = (u16*)R3 + 2*TSLB;
  u16 *vt1 = xn1, *vt2 = xn2, *vt3 = xn3;        // reuse R1 after xn is dead
  float* vf  = (float*)R4;
  float* aof = (float*)R4;                        // reuse after vtrans
  u16 *ao1 = k1, *ao2 = k2, *ao3 = k3;            // reuse R3 after fattn
  float* x1  = (float*)R4;                        // reuse after split3 (O-proj out)
  // phase B pointers (MoE)
  u16* WgT = (u16*)R0;                            // 32 MB
  u16* WuT = (u16*)R0 + (size_t)NEXP*MDIM*HID;    // 32 MB
  u16* WdT = (u16*)R0 + 2*(size_t)NEXP*MDIM*HID;  // 32 MB
  u16* ynb = (u16*)R1;                            // 8 MB
  float* yn = (float*)(R1 + 8*MB);                // 16 MB
  u16* hb  = (u16*)R2;                            // 32 MB spans R2 + first 8MB of R3
  int*   tok_list = (int*)RS;                     // 64 KB
  float* w_list   = (float*)(RS + 64*1024);       // 64 KB
  int*   cur      = (int*)(RS + 128*1024);
  int*   cnt_pad  = (int*)(RS + 132*1024);
  float* ct   = (float*)(RS + 256*1024);
  float* stab = (float*)(RS + 384*1024);

  dim3 blk256(256), blkT(32,8), g16(16,16), g64(64,64), gMoE(16,16,8);

  rope_table_k<<<dim3(SEQ*32/256), blk256, 0, stream>>>(ct, stab);
  convT3<<<g64, blkT, 0, stream>>>(Wq, Wq1, Wq2, Wq3, HID, HID);
  convT3<<<g64, blkT, 0, stream>>>(Wk, Wk1, Wk2, Wk3, HID, HID);
  convT3<<<g64, blkT, 0, stream>>>(Wv, Wv1, Wv2, Wv3, HID, HID);
  convT3<<<g64, blkT, 0, stream>>>(Wo, Wo1, Wo2, Wo3, HID, HID);

  rmsnorm3_k<<<dim3(T_TOK), blk256, 0, stream>>>(hs, w_attn, xn1, xn2, xn3);

  // Q, K with fused rope + split epilogue; V -> f32
  gemm128s<1><<<g16, blk256, 0, stream>>>(xn1,xn2,xn3, Wq1,Wq2,Wq3, nullptr, q1,q2,q3, ct, stab, nullptr);
  gemm128s<1><<<g16, blk256, 0, stream>>>(xn1,xn2,xn3, Wk1,Wk2,Wk3, nullptr, k1,k2,k3, ct, stab, nullptr);
  gemm128s<0><<<g16, blk256, 0, stream>>>(xn1,xn2,xn3, Wv1,Wv2,Wv3, vf, nullptr,nullptr,nullptr, nullptr, nullptr, nullptr);

  vtrans3_k<<<dim3(SEQ/64, BATCH*NHEAD), blk256, 0, stream>>>(vf, vt1, vt2, vt3);   // xn dead

  fattn3_k<<<dim3(BATCH*NHEAD, SEQ/64), blk256, 0, stream>>>(q1,q2,q3, k1,k2,k3, vt1,vt2,vt3, aof);  // vf dead

  split3_k<<<dim3(T_TOK*HID/1024), blk256, 0, stream>>>(aof, ao1, ao2, ao3);        // k dead

  gemm128s<2><<<g16, blk256, 0, stream>>>(ao1,ao2,ao3, Wo1,Wo2,Wo3, x1, nullptr,nullptr,nullptr, nullptr, nullptr, hs);  // aof dead

  // attention weights dead -> convert MoE weights into R0
  convT<<<dim3(MDIM/32, HID/32, NEXP), blkT, 0, stream>>>(Wg, WgT, HID, MDIM);
  convT<<<dim3(MDIM/32, HID/32, NEXP), blkT, 0, stream>>>(Wu, WuT, HID, MDIM);
  convT<<<dim3(HID/32, MDIM/32, NEXP), blkT, 0, stream>>>(Wd, WdT, MDIM, HID);

  // MoE norm also initializes Out with the residual x1
  rmsnorm_k<<<dim3(T_TOK), blk256, 0, stream>>>(x1, w_moe, ynb, yn, out);   // vt dead

  hipMemsetAsync(cur, 0, NEXP*sizeof(int), stream);
  router_scatter_k<<<dim3(T_TOK), dim3(64), 0, stream>>>(yn, Wr, tok_list, w_list, cur);
  pad_k<<<dim3(NEXP), dim3(128), 0, stream>>>(cur, tok_list, w_list, cnt_pad);

  gemm_gateup_sp<<<gMoE, blk256, 0, stream>>>(ynb, WgT, WuT, tok_list, w_list, cnt_pad, hb);  // q, ao dead
  gemm_down_sp<<<gMoE, blk256, 0, stream>>>(hb, WdT, tok_list, cnt_pad, out);
}

// Round 6
// 1101.978 us; speedup vs baseline: 2.2384x; 1.2143x over previous
//
#include <hip/hip_runtime.h>
#include <hip/hip_bf16.h>
#include <cstdint>

typedef unsigned short u16;
typedef __bf16 bf16x4_t __attribute__((ext_vector_type(4)));
typedef __bf16 bf16x8_t __attribute__((ext_vector_type(8)));
typedef float f32x4_t __attribute__((ext_vector_type(4)));
typedef unsigned short us4_t __attribute__((ext_vector_type(4)));

#define BATCH 2
#define SEQ 1024
#define HID 2048
#define NHEAD 32
#define NEXP 8
#define MDIM 1024
#define T_TOK (BATCH*SEQ)   // 2048

// ---------- helpers ----------

__device__ __forceinline__ void gload16(const void* g, void* l){
  __builtin_amdgcn_global_load_lds((__attribute__((address_space(1))) void*)(uintptr_t)g,
                                   (__attribute__((address_space(3))) void*)l, 16, 0, 0);
}

// 8-bf16 MFMA fragment as two b64 halves (k = fg*4+e and +16; bijective k-map
// used identically on A and B sides -> product invariant).
__device__ __forceinline__ bf16x8_t ldfrag(const u16* lo){
  bf16x4_t a = *(const bf16x4_t*)lo;
  bf16x4_t b = *(const bf16x4_t*)(lo + 16);
  return __builtin_shufflevector(a, b, 0,1,2,3,4,5,6,7);
}

// Swizzled fragment read, 128B LDS rows (fattn K/V/P): byte ^= (row&7)<<4.
// Pairs with staging-source chunk permute sp^=(row&7). 16-way -> 4-way conflict.
__device__ __forceinline__ bf16x8_t ldfsw128(const u16* base, int row, int colbyte){
  const char* p = (const char*)base + row*128;
  int sw = (row & 7) << 4;
  bf16x4_t a = *(const bf16x4_t*)(p + (colbyte ^ sw));
  bf16x4_t b = *(const bf16x4_t*)(p + ((colbyte + 32) ^ sw));
  return __builtin_shufflevector(a, b, 0,1,2,3,4,5,6,7);
}

// Swizzled fragment read, 64B LDS rows (GEMM tiles, BK=32): byte ^= (row&3)<<4.
// Pairs with staging-source chunk permute skb^=(row&3). 8-way -> 4-way conflict.
__device__ __forceinline__ bf16x8_t ldfsw64(const u16* base, int row, int colbyte){
  const char* p = (const char*)base + row*64;
  int sw = (row & 3) << 4;
  bf16x4_t a = *(const bf16x4_t*)(p + (colbyte ^ sw));
  bf16x4_t b = *(const bf16x4_t*)(p + ((colbyte + 32) ^ sw));
  return __builtin_shufflevector(a, b, 0,1,2,3,4,5,6,7);
}

__device__ __forceinline__ f32x4_t mfma16(bf16x8_t a, bf16x8_t b, f32x4_t c){
  return __builtin_amdgcn_mfma_f32_16x16x32_bf16(a, b, c, 0, 0, 0);
}

__device__ __forceinline__ u16 f2b(float f){
  __hip_bfloat16 h = __float2bfloat16(f);
  return __builtin_bit_cast(u16, h);
}
__device__ __forceinline__ float b2f(u16 b){
  return __builtin_bit_cast(float, (unsigned int)b << 16);
}
// 3-way bf16 split: v ~= b1 + b2 + b3 with |residual| <= 2^-27 |v|
__device__ __forceinline__ void split3v(float v, u16& b1, u16& b2, u16& b3){
  b1 = f2b(v); float f1 = b2f(b1);
  float r1 = v - f1;
  b2 = f2b(r1); float f2 = b2f(b2);
  b3 = f2b(r1 - f2);
}

// ---------- weight convert+transpose (single bf16, MoE): f32 [R][C] -> bf16 [C][R] ----------

__global__ __launch_bounds__(256)
void convT(const float* __restrict__ in, u16* __restrict__ out, int R, int C)
{
  __shared__ float tile[32][33];
  int bz = blockIdx.z;
  const float* ip = in + (size_t)bz * R * C;
  u16* op = out + (size_t)bz * R * C;
  int tx = threadIdx.x, ty = threadIdx.y;   // block (32,8)
  int c0 = blockIdx.x*32, r0 = blockIdx.y*32;
  #pragma unroll
  for (int i = 0; i < 4; i++)
    tile[ty + i*8][tx] = ip[(size_t)(r0 + ty + i*8) * C + c0 + tx];
  __syncthreads();
  #pragma unroll
  for (int i = 0; i < 4; i++)
    op[(size_t)(c0 + ty + i*8) * R + r0 + tx] = f2b(tile[tx][ty + i*8]);
}

// ---------- weight convert+transpose, 3-way split (attention weights) ----------

__global__ __launch_bounds__(256)
void convT3(const float* __restrict__ in, u16* __restrict__ o1, u16* __restrict__ o2,
            u16* __restrict__ o3, int R, int C)
{
  __shared__ float tile[32][33];
  const float* ip = in;
  int tx = threadIdx.x, ty = threadIdx.y;
  int c0 = blockIdx.x*32, r0 = blockIdx.y*32;
  #pragma unroll
  for (int i = 0; i < 4; i++)
    tile[ty + i*8][tx] = ip[(size_t)(r0 + ty + i*8) * C + c0 + tx];
  __syncthreads();
  #pragma unroll
  for (int i = 0; i < 4; i++){
    u16 b1, b2, b3;
    split3v(tile[tx][ty + i*8], b1, b2, b3);
    size_t idx = (size_t)(c0 + ty + i*8) * R + r0 + tx;
    o1[idx] = b1; o2[idx] = b2; o3[idx] = b3;
  }
}

// ---------- RMSNorm -> 3-way split (attention input) ----------

__global__ __launch_bounds__(256)
void rmsnorm3_k(const float* __restrict__ x, const float* __restrict__ w,
                u16* __restrict__ o1, u16* __restrict__ o2, u16* __restrict__ o3)
{
  int row = blockIdx.x;
  const float* xr = x + (size_t)row * HID;
  int base = threadIdx.x * 8;
  float4 a = *(const float4*)(xr + base);
  float4 b = *(const float4*)(xr + base + 4);
  float ss = a.x*a.x + a.y*a.y + a.z*a.z + a.w*a.w
           + b.x*b.x + b.y*b.y + b.z*b.z + b.w*b.w;
  #pragma unroll
  for (int off = 32; off; off >>= 1) ss += __shfl_down(ss, off);
  __shared__ float red[4];
  if ((threadIdx.x & 63) == 0) red[threadIdx.x >> 6] = ss;
  __syncthreads();
  float tot = red[0] + red[1] + red[2] + red[3];
  float rs = (float)(1.0 / sqrt((double)tot * (1.0/2048.0) + 1e-5));
  float4 wa = *(const float4*)(w + base);
  float4 wb = *(const float4*)(w + base + 4);
  float o[8];
  o[0]=a.x*rs*wa.x; o[1]=a.y*rs*wa.y; o[2]=a.z*rs*wa.z; o[3]=a.w*rs*wa.w;
  o[4]=b.x*rs*wb.x; o[5]=b.y*rs*wb.y; o[6]=b.z*rs*wb.z; o[7]=b.w*rs*wb.w;
  us4_t v1[2], v2[2], v3[2];
  #pragma unroll
  for (int j = 0; j < 8; j++){
    u16 b1, b2, b3; split3v(o[j], b1, b2, b3);
    v1[j>>2][j&3] = b1; v2[j>>2][j&3] = b2; v3[j>>2][j&3] = b3;
  }
  size_t idx = (size_t)row*HID + base;
  *(us4_t*)&o1[idx] = v1[0]; *(us4_t*)&o1[idx+4] = v1[1];
  *(us4_t*)&o2[idx] = v2[0]; *(us4_t*)&o2[idx+4] = v2[1];
  *(us4_t*)&o3[idx] = v3[0]; *(us4_t*)&o3[idx+4] = v3[1];
}

// ---------- RMSNorm (MoE): bf16 out + f32 out + residual passthrough to Out ----------

__global__ __launch_bounds__(256)
void rmsnorm_k(const float* __restrict__ x, const float* __restrict__ w,
               u16* __restrict__ ob, float* __restrict__ of, float* __restrict__ oi)
{
  int row = blockIdx.x;
  const float* xr = x + (size_t)row * HID;
  int base = threadIdx.x * 8;
  float4 a = *(const float4*)(xr + base);
  float4 b = *(const float4*)(xr + base + 4);
  float ss = a.x*a.x + a.y*a.y + a.z*a.z + a.w*a.w
           + b.x*b.x + b.y*b.y + b.z*b.z + b.w*b.w;
  #pragma unroll
  for (int off = 32; off; off >>= 1) ss += __shfl_down(ss, off);
  __shared__ float red[4];
  if ((threadIdx.x & 63) == 0) red[threadIdx.x >> 6] = ss;
  __syncthreads();
  float tot = red[0] + red[1] + red[2] + red[3];
  float rs = (float)(1.0 / sqrt((double)tot * (1.0/2048.0) + 1e-5));
  float4 wa = *(const float4*)(w + base);
  float4 wb = *(const float4*)(w + base + 4);
  float o[8];
  o[0]=a.x*rs*wa.x; o[1]=a.y*rs*wa.y; o[2]=a.z*rs*wa.z; o[3]=a.w*rs*wa.w;
  o[4]=b.x*rs*wb.x; o[5]=b.y*rs*wb.y; o[6]=b.z*rs*wb.z; o[7]=b.w*rs*wb.w;
  us4_t p0, p1;
  p0.x=f2b(o[0]); p0.y=f2b(o[1]); p0.z=f2b(o[2]); p0.w=f2b(o[3]);
  p1.x=f2b(o[4]); p1.y=f2b(o[5]); p1.z=f2b(o[6]); p1.w=f2b(o[7]);
  *(us4_t*)&ob[(size_t)row*HID + base] = p0;
  *(us4_t*)&ob[(size_t)row*HID + base + 4] = p1;
  float* orow = of + (size_t)row*HID + base;
  *(float4*)orow = make_float4(o[0],o[1],o[2],o[3]);
  *(float4*)(orow+4) = make_float4(o[4],o[5],o[6],o[7]);
  // init final output with the residual (down-GEMM atomically accumulates onto it)
  float* irow = oi + (size_t)row*HID + base;
  *(float4*)irow = a;
  *(float4*)(irow+4) = b;
}

// ---------- RoPE table (f64 math -> f32) ----------

__global__ void rope_table_k(float* ct, float* st){
  int i = blockIdx.x*256 + threadIdx.x;   // SEQ*32
  int s = i >> 5, j = i & 31;
  double invf = exp(-(double)j / 32.0 * log(10000.0));
  double ang = (double)s * invf;
  ct[i] = (float)cos(ang);
  st[i] = (float)sin(ang);
}

// ---------- fused Q/K/V split GEMM: z=0 -> Q(rope+split), z=1 -> K(rope+split), z=2 -> V(f32) ----------
// 768 blocks -> 3 co-resident blocks/CU (48KB LDS) for cross-block load/MFMA overlap.

__global__ __launch_bounds__(256, 2)
void gemm_qkv(const u16* __restrict__ A1, const u16* __restrict__ A2, const u16* __restrict__ A3,
              const u16* __restrict__ Wq1, const u16* __restrict__ Wq2, const u16* __restrict__ Wq3,
              const u16* __restrict__ Wk1, const u16* __restrict__ Wk2, const u16* __restrict__ Wk3,
              const u16* __restrict__ Wv1, const u16* __restrict__ Wv2, const u16* __restrict__ Wv3,
              u16* __restrict__ oq1, u16* __restrict__ oq2, u16* __restrict__ oq3,
              u16* __restrict__ ok1, u16* __restrict__ ok2, u16* __restrict__ ok3,
              float* __restrict__ vf,
              const float* __restrict__ ct, const float* __restrict__ st)
{
  __shared__ u16 As[3][128*32];
  __shared__ u16 Bs[3][128*32];
  const int z = blockIdx.z;
  const int tid = threadIdx.x;
  const int lane = tid & 63;
  const int wave = tid >> 6;
  const int wr = wave >> 1, wc = wave & 1;
  const int fr = lane & 15, fg = lane >> 4;
  const int bm = blockIdx.y * 128, bn = blockIdx.x * 128;

  f32x4_t acc[4][4] = {};

  const int srow = tid >> 2, skb = (tid & 3) ^ (srow & 3);   // swizzled source chunk
  const u16* Ap[3] = {A1, A2, A3};
  const u16* Bp[3];
  if (z == 0)      { Bp[0] = Wq1; Bp[1] = Wq2; Bp[2] = Wq3; }
  else if (z == 1) { Bp[0] = Wk1; Bp[1] = Wk2; Bp[2] = Wk3; }
  else             { Bp[0] = Wv1; Bp[1] = Wv2; Bp[2] = Wv3; }
  const u16* gA[3]; const u16* gB[3];
  #pragma unroll
  for (int t = 0; t < 3; t++){
    gA[t] = Ap[t] + (size_t)(bm + srow) * HID + skb * 8;
    gB[t] = Bp[t] + (size_t)(bn + srow) * HID + skb * 8;
  }

  for (int kk = 0; kk < HID; kk += 32){
    #pragma unroll
    for (int t = 0; t < 3; t++){
      gload16(gA[t] + kk,                    &As[t][tid*8]);
      gload16(gA[t] + (size_t)64*HID + kk,   &As[t][2048 + tid*8]);
      gload16(gB[t] + kk,                    &Bs[t][tid*8]);
      gload16(gB[t] + (size_t)64*HID + kk,   &Bs[t][2048 + tid*8]);
    }
    __syncthreads();
    bf16x8_t af[3][4], bfv[3][4];
    #pragma unroll
    for (int t = 0; t < 3; t++)
      #pragma unroll
      for (int i = 0; i < 4; i++){
        af[t][i]  = ldfsw64(As[t], wr*64 + i*16 + fr, fg*8);
        bfv[t][i] = ldfsw64(Bs[t], wc*64 + i*16 + fr, fg*8);
      }
    // 6 products, smallest first: a3b1, a2b2, a1b3, a2b1, a1b2, a1b1
    const int pA[6] = {2,1,0,1,0,0};
    const int pB[6] = {0,1,2,0,1,0};
    #pragma unroll
    for (int p = 0; p < 6; p++)
      #pragma unroll
      for (int mi = 0; mi < 4; mi++)
        #pragma unroll
        for (int ni = 0; ni < 4; ni++)
          acc[mi][ni] = mfma16(af[pA[p]][mi], bfv[pB[p]][ni], acc[mi][ni]);
    __syncthreads();
  }

  if (z < 2){
    u16* O1 = z ? ok1 : oq1;
    u16* O2 = z ? ok2 : oq2;
    u16* O3 = z ? ok3 : oq3;
    #pragma unroll
    for (int mi = 0; mi < 4; mi++)
      #pragma unroll
      for (int r = 0; r < 4; r++){
        int row = bm + wr*64 + mi*16 + fg*4 + r;
        int s = row & (SEQ-1);
        #pragma unroll
        for (int ni = 0; ni < 2; ni++){
          int dlo = ni*16 + fr;   // 0..31 within head
          float c  = ct[s*32 + dlo];
          float sn = st[s*32 + dlo];
          float xl = acc[mi][ni][r], xh = acc[mi][ni+2][r];
          float ol = xl*c - xh*sn;
          float oh = xh*c + xl*sn;
          size_t idx = (size_t)row * HID + bn + wc*64 + ni*16 + fr;
          u16 b1, b2, b3;
          split3v(ol, b1, b2, b3); O1[idx] = b1;    O2[idx] = b2;    O3[idx] = b3;
          split3v(oh, b1, b2, b3); O1[idx+32] = b1; O2[idx+32] = b2; O3[idx+32] = b3;
        }
      }
  } else {
    #pragma unroll
    for (int mi = 0; mi < 4; mi++)
      #pragma unroll
      for (int ni = 0; ni < 4; ni++)
        #pragma unroll
        for (int r = 0; r < 4; r++){
          int row = bm + wr*64 + mi*16 + fg*4 + r;
          int col = bn + wc*64 + ni*16 + fr;
          vf[(size_t)row * HID + col] = acc[mi][ni][r];
        }
  }
}

// ---------- O-projection split GEMM, 128x64 tiles (512 blocks -> 2/CU), +residual ----------

__global__ __launch_bounds__(256, 2)
void gemm_o(const u16* __restrict__ A1, const u16* __restrict__ A2, const u16* __restrict__ A3,
            const u16* __restrict__ B1, const u16* __restrict__ B2, const u16* __restrict__ B3,
            float* __restrict__ Cf, const float* __restrict__ Res)
{
  __shared__ u16 As[3][128*32];   // 24KB
  __shared__ u16 Bs[3][64*32];    // 12KB
  const int tid = threadIdx.x;
  const int lane = tid & 63;
  const int wave = tid >> 6;
  const int wr = wave >> 1, wc = wave & 1;
  const int fr = lane & 15, fg = lane >> 4;
  const int bm = blockIdx.y * 128, bn = blockIdx.x * 64;

  f32x4_t acc[4][2] = {};

  const int srow = tid >> 2, skb = (tid & 3) ^ (srow & 3);
  const u16* Ap[3] = {A1, A2, A3};
  const u16* Bp[3] = {B1, B2, B3};
  const u16* gA[3]; const u16* gB[3];
  #pragma unroll
  for (int t = 0; t < 3; t++){
    gA[t] = Ap[t] + (size_t)(bm + srow) * HID + skb * 8;
    gB[t] = Bp[t] + (size_t)(bn + srow) * HID + skb * 8;
  }

  for (int kk = 0; kk < HID; kk += 32){
    #pragma unroll
    for (int t = 0; t < 3; t++){
      gload16(gA[t] + kk,                    &As[t][tid*8]);
      gload16(gA[t] + (size_t)64*HID + kk,   &As[t][2048 + tid*8]);
      gload16(gB[t] + kk,                    &Bs[t][tid*8]);
    }
    __syncthreads();
    bf16x8_t af[3][4], bfv[3][2];
    #pragma unroll
    for (int t = 0; t < 3; t++){
      #pragma unroll
      for (int i = 0; i < 4; i++)
        af[t][i]  = ldfsw64(As[t], wr*64 + i*16 + fr, fg*8);
      #pragma unroll
      for (int j = 0; j < 2; j++)
        bfv[t][j] = ldfsw64(Bs[t], wc*32 + j*16 + fr, fg*8);
    }
    const int pA[6] = {2,1,0,1,0,0};
    const int pB[6] = {0,1,2,0,1,0};
    #pragma unroll
    for (int p = 0; p < 6; p++)
      #pragma unroll
      for (int mi = 0; mi < 4; mi++)
        #pragma unroll
        for (int nj = 0; nj < 2; nj++)
          acc[mi][nj] = mfma16(af[pA[p]][mi], bfv[pB[p]][nj], acc[mi][nj]);
    __syncthreads();
  }

  #pragma unroll
  for (int mi = 0; mi < 4; mi++)
    #pragma unroll
    for (int nj = 0; nj < 2; nj++)
      #pragma unroll
      for (int r = 0; r < 4; r++){
        int row = bm + wr*64 + mi*16 + fg*4 + r;
        int col = bn + wc*32 + nj*16 + fr;
        size_t idx = (size_t)row * HID + col;
        Cf[idx] = acc[mi][nj][r] + Res[idx];
      }
}

// ---------- elementwise 3-way split (attention output) ----------

__global__ __launch_bounds__(256)
void split3_k(const float* __restrict__ in, u16* __restrict__ o1, u16* __restrict__ o2,
              u16* __restrict__ o3)
{
  size_t i = ((size_t)blockIdx.x*256 + threadIdx.x) * 4;
  float4 v = *(const float4*)(in + i);
  us4_t v1, v2, v3;
  u16 b1, b2, b3;
  split3v(v.x, b1,b2,b3); v1.x=b1; v2.x=b2; v3.x=b3;
  split3v(v.y, b1,b2,b3); v1.y=b1; v2.y=b2; v3.y=b3;
  split3v(v.z, b1,b2,b3); v1.z=b1; v2.z=b2; v3.z=b3;
  split3v(v.w, b1,b2,b3); v1.w=b1; v2.w=b2; v3.w=b3;
  *(us4_t*)&o1[i] = v1; *(us4_t*)&o2[i] = v2; *(us4_t*)&o3[i] = v3;
}

// ---------- V transpose + split: f32 [T][H] -> per (b,h) bf16x3 [64 d][1024 s] ----------

__global__ __launch_bounds__(256)
void vtrans3_k(const float* __restrict__ vf, u16* __restrict__ t1, u16* __restrict__ t2,
               u16* __restrict__ t3)
{
  __shared__ float t[64][65];
  int st0 = blockIdx.x * 64;
  int bh = blockIdx.y;
  int b = bh >> 5, h = bh & 31;
  int tid = threadIdx.x;
  #pragma unroll
  for (int i = 0; i < 4; i++){
    int idx = tid + i*256;                // 1024 float4 chunks
    int s = idx >> 4, dc = (idx & 15) * 4;
    float4 v = *(const float4*)&vf[(size_t)(b*SEQ + st0 + s) * HID + h*64 + dc];
    t[dc+0][s] = v.x; t[dc+1][s] = v.y; t[dc+2][s] = v.z; t[dc+3][s] = v.w;
  }
  __syncthreads();
  #pragma unroll
  for (int i = 0; i < 4; i++){
    int idx = tid + i*256;
    int d = idx >> 4, sc = (idx & 15) * 4;
    us4_t v1, v2, v3;
    #pragma unroll
    for (int j = 0; j < 4; j++){
      u16 b1, b2, b3; split3v(t[d][sc+j], b1, b2, b3);
      v1[j]=b1; v2[j]=b2; v3[j]=b3;
    }
    size_t base = ((size_t)bh*64 + d)*SEQ + st0 + sc;
    *(us4_t*)&t1[base] = v1; *(us4_t*)&t2[base] = v2; *(us4_t*)&t3[base] = v3;
  }
}

// ---------- flash attention, split-precision (causal), f32 out ----------

__global__ __launch_bounds__(256)
void fattn3_k(const u16* __restrict__ q1, const u16* __restrict__ q2, const u16* __restrict__ q3,
              const u16* __restrict__ k1, const u16* __restrict__ k2, const u16* __restrict__ k3,
              const u16* __restrict__ v1, const u16* __restrict__ v2, const u16* __restrict__ v3,
              float* __restrict__ aof)
{
  __shared__ u16 Ks[3][64*64];     // 24KB
  __shared__ u16 Vs[3][64*64];     // 24KB
  __shared__ u16 Ps[2][4][16*64];  // 16KB  -> 64KB total
  const int bh = blockIdx.x, qt = blockIdx.y;
  const int b = bh >> 5, h = bh & 31;
  const int tid = threadIdx.x, lane = tid & 63, wave = tid >> 6;
  const int fr = lane & 15, fg = lane >> 4;

  const size_t qrow = (size_t)(b*SEQ + qt*64 + wave*16 + fr);
  const u16* qp[3] = { q1 + qrow*HID + h*64, q2 + qrow*HID + h*64, q3 + qrow*HID + h*64 };
  bf16x8_t aq[3][2];
  #pragma unroll
  for (int t = 0; t < 3; t++)
    #pragma unroll
    for (int ks = 0; ks < 2; ks++) aq[t][ks] = ldfrag(qp[t] + ks*32 + fg*4);

  f32x4_t oacc[4] = {};
  float m_r[4], l_r[4];
  #pragma unroll
  for (int r = 0; r < 4; r++){ m_r[r] = -1e30f; l_r[r] = 0.f; }

  const int sr = tid >> 3, sp = (tid & 7) ^ (sr & 7);   // swizzled source chunk
  const u16* kb[3] = { k1 + ((size_t)(b*SEQ) + sr)*HID + h*64 + sp*8,
                       k2 + ((size_t)(b*SEQ) + sr)*HID + h*64 + sp*8,
                       k3 + ((size_t)(b*SEQ) + sr)*HID + h*64 + sp*8 };
  const u16* vb[3] = { v1 + ((size_t)bh*64 + sr)*SEQ + sp*8,
                       v2 + ((size_t)bh*64 + sr)*SEQ + sp*8,
                       v3 + ((size_t)bh*64 + sr)*SEQ + sp*8 };

  for (int kt = 0; kt <= qt; kt++){
    #pragma unroll
    for (int t = 0; t < 3; t++){
      gload16(kb[t] + (size_t)(kt*64) * HID,    &Ks[t][tid*8]);
      gload16(kb[t] + (size_t)(kt*64+32) * HID, &Ks[t][2048 + tid*8]);
      gload16(vb[t] + kt*64,                    &Vs[t][tid*8]);
      gload16(vb[t] + (size_t)32*SEQ + kt*64,   &Vs[t][2048 + tid*8]);
    }
    __syncthreads();

    f32x4_t sc[4] = {};
    #pragma unroll
    for (int nf = 0; nf < 4; nf++)
      #pragma unroll
      for (int ks = 0; ks < 2; ks++){
        int krow = nf*16 + fr, kcb = ks*64 + fg*8;
        bf16x8_t bk0 = ldfsw128(Ks[0], krow, kcb);
        bf16x8_t bk1 = ldfsw128(Ks[1], krow, kcb);
        bf16x8_t bk2 = ldfsw128(Ks[2], krow, kcb);
        sc[nf] = mfma16(aq[2][ks], bk0, sc[nf]);
        sc[nf] = mfma16(aq[1][ks], bk1, sc[nf]);
        sc[nf] = mfma16(aq[0][ks], bk2, sc[nf]);
        sc[nf] = mfma16(aq[1][ks], bk0, sc[nf]);
        sc[nf] = mfma16(aq[0][ks], bk1, sc[nf]);
        sc[nf] = mfma16(aq[0][ks], bk0, sc[nf]);
      }

    float nm[4] = {-1e30f,-1e30f,-1e30f,-1e30f};
    #pragma unroll
    for (int nf = 0; nf < 4; nf++)
      #pragma unroll
      for (int r = 0; r < 4; r++){
        float v = sc[nf][r] * 0.125f;
        if (kt == qt && nf*16 + fr > wave*16 + fg*4 + r) v = -1e30f;
        sc[nf][r] = v;
        nm[r] = fmaxf(nm[r], v);
      }
    #pragma unroll
    for (int r = 0; r < 4; r++)
      #pragma unroll
      for (int msk = 8; msk; msk >>= 1) nm[r] = fmaxf(nm[r], __shfl_xor(nm[r], msk));

    #pragma unroll
    for (int r = 0; r < 4; r++){
      float mn = fmaxf(m_r[r], nm[r]);
      float f = __expf(m_r[r] - mn);
      m_r[r] = mn;
      float rsum = 0.f;
      #pragma unroll
      for (int nf = 0; nf < 4; nf++){
        float pv = __expf(sc[nf][r] - mn);
        sc[nf][r] = pv;
        rsum += pv;
      }
      #pragma unroll
      for (int msk = 8; msk; msk >>= 1) rsum += __shfl_xor(rsum, msk);
      l_r[r] = l_r[r]*f + rsum;
      #pragma unroll
      for (int df = 0; df < 4; df++) oacc[df][r] *= f;
    }

    // P 2-way split to LDS (swizzled writes matching ldfsw128 reads)
    #pragma unroll
    for (int nf = 0; nf < 4; nf++)
      #pragma unroll
      for (int r = 0; r < 4; r++){
        float pv = sc[nf][r];
        u16 b1 = f2b(pv);
        float f1 = b2f(b1);
        u16 b2 = f2b(pv - f1);
        int prow = fg*4 + r;
        int pbyte = (nf*32 + fr*2) ^ ((prow & 7) << 4);
        *(u16*)((char*)&Ps[0][wave][0] + prow*128 + pbyte) = b1;
        *(u16*)((char*)&Ps[1][wave][0] + prow*128 + pbyte) = b2;
      }

    #pragma unroll
    for (int ks = 0; ks < 2; ks++){
      bf16x8_t pa0 = ldfsw128(&Ps[0][wave][0], fr, ks*64 + fg*8);
      bf16x8_t pa1 = ldfsw128(&Ps[1][wave][0], fr, ks*64 + fg*8);
      #pragma unroll
      for (int df = 0; df < 4; df++){
        int vrow = df*16 + fr, vcb = ks*64 + fg*8;
        bf16x8_t bv0 = ldfsw128(Vs[0], vrow, vcb);
        bf16x8_t bv1 = ldfsw128(Vs[1], vrow, vcb);
        bf16x8_t bv2 = ldfsw128(Vs[2], vrow, vcb);
        oacc[df] = mfma16(pa0, bv2, oacc[df]);   // p1 v3
        oacc[df] = mfma16(pa1, bv1, oacc[df]);   // p2 v2
        oacc[df] = mfma16(pa1, bv0, oacc[df]);   // p2 v1
        oacc[df] = mfma16(pa0, bv1, oacc[df]);   // p1 v2
        oacc[df] = mfma16(pa0, bv0, oacc[df]);   // p1 v1
      }
    }
    __syncthreads();
  }

  #pragma unroll
  for (int r = 0; r < 4; r++){
    float inv = 1.f / l_r[r];
    int orow = b*SEQ + qt*64 + wave*16 + fg*4 + r;
    #pragma unroll
    for (int df = 0; df < 4; df++)
      aof[(size_t)orow * HID + h*64 + df*16 + fr] = oacc[df][r] * inv;
  }
}

// ---------- router + scatter: f64 logits, top-2, compact per-expert lists ----------

__global__ __launch_bounds__(64)
void router_scatter_k(const float* __restrict__ yn, const float* __restrict__ Wr,
                      int* __restrict__ tok_list, float* __restrict__ w_list,
                      int* __restrict__ cur){
  int row = blockIdx.x;
  int lane = threadIdx.x;
  const float* xr = yn + (size_t)row * HID;
  double acc[8] = {};
  for (int j = lane; j < HID; j += 64){
    double xv = (double)xr[j];
    const float* wr = Wr + (size_t)j*8;
    float4 w0 = *(const float4*)wr;
    float4 w1 = *(const float4*)(wr + 4);
    acc[0] += xv*w0.x; acc[1] += xv*w0.y; acc[2] += xv*w0.z; acc[3] += xv*w0.w;
    acc[4] += xv*w1.x; acc[5] += xv*w1.y; acc[6] += xv*w1.z; acc[7] += xv*w1.w;
  }
  #pragma unroll
  for (int e = 0; e < 8; e++)
    #pragma unroll
    for (int off = 32; off; off >>= 1) acc[e] += __shfl_down(acc[e], off);
  if (lane == 0){
    double mx = acc[0];
    #pragma unroll
    for (int e = 1; e < 8; e++) mx = fmax(mx, acc[e]);
    double p[8];
    #pragma unroll
    for (int e = 0; e < 8; e++) p[e] = exp(acc[e] - mx);
    int i1 = 0;
    #pragma unroll
    for (int e = 1; e < 8; e++) if (p[e] > p[i1]) i1 = e;
    int i2 = (i1 == 0) ? 1 : 0;
    #pragma unroll
    for (int e = 0; e < 8; e++) if (e != i1 && p[e] > p[i2]) i2 = e;
    double s2 = p[i1] + p[i2];
    int pos1 = atomicAdd(&cur[i1], 1);
    tok_list[i1*T_TOK + pos1] = row;
    w_list[i1*T_TOK + pos1] = (float)(p[i1] / s2);
    int pos2 = atomicAdd(&cur[i2], 1);
    tok_list[i2*T_TOK + pos2] = row;
    w_list[i2*T_TOK + pos2] = (float)(p[i2] / s2);
  }
}

// pad each expert's list to a multiple of 128 with (token 0, weight 0)
__global__ __launch_bounds__(128)
void pad_k(const int* __restrict__ cur, int* __restrict__ tok_list,
           float* __restrict__ w_list, int* __restrict__ cnt_pad){
  int e = blockIdx.x;
  int c = cur[e];
  int cp = (c + 127) & ~127;
  for (int i = c + threadIdx.x; i < cp; i += 128){
    tok_list[e*T_TOK + i] = 0;
    w_list[e*T_TOK + i] = 0.f;
  }
  if (threadIdx.x == 0) cnt_pad[e] = cp;
}

// ---------- sparse fused gate+up GEMM: h = silu(g)*u*w over compact token lists ----------

__global__ __launch_bounds__(256, 2)
void gemm_gateup_sp(const u16* __restrict__ A, const u16* __restrict__ WgT, const u16* __restrict__ WuT,
                    const int* __restrict__ tok_list, const float* __restrict__ w_list,
                    const int* __restrict__ cnt_pad, u16* __restrict__ Hb)
{
  const int e = blockIdx.z;
  const int bm = blockIdx.y * 128;   // position within expert list
  if (bm >= cnt_pad[e]) return;
  __shared__ u16 As[128*32];
  __shared__ u16 Bg[64*32];
  __shared__ u16 Bu[64*32];
  const int tid = threadIdx.x;
  const int lane = tid & 63;
  const int wave = tid >> 6;
  const int wr = wave >> 1, wc = wave & 1;
  const int fr = lane & 15, fg = lane >> 4;
  const int bn = blockIdx.x * 64;    // M cols

  f32x4_t ag[4][2] = {}, au[4][2] = {};

  const int srow = tid >> 2, skb = (tid & 3) ^ (srow & 3);   // swizzled source chunk
  const int tok0 = tok_list[e*T_TOK + bm + srow];
  const int tok1 = tok_list[e*T_TOK + bm + srow + 64];
  const u16* ga0 = A + (size_t)tok0 * HID + skb * 8;
  const u16* ga1 = A + (size_t)tok1 * HID + skb * 8;
  const u16* gg0 = WgT + ((size_t)e*MDIM + bn + srow) * HID + skb * 8;
  const u16* gu0 = WuT + ((size_t)e*MDIM + bn + srow) * HID + skb * 8;

  for (int kk = 0; kk < HID; kk += 32){
    gload16(ga0 + kk, &As[tid*8]);
    gload16(ga1 + kk, &As[2048 + tid*8]);
    gload16(gg0 + kk, &Bg[tid*8]);
    gload16(gu0 + kk, &Bu[tid*8]);
    __syncthreads();
    bf16x8_t af[4], bg[2], bu[2];
    #pragma unroll
    for (int i = 0; i < 4; i++) af[i] = ldfsw64(As, wr*64 + i*16 + fr, fg*8);
    #pragma unroll
    for (int j = 0; j < 2; j++){
      bg[j] = ldfsw64(Bg, wc*32 + j*16 + fr, fg*8);
      bu[j] = ldfsw64(Bu, wc*32 + j*16 + fr, fg*8);
    }
    #pragma unroll
    for (int mi = 0; mi < 4; mi++)
      #pragma unroll
      for (int nj = 0; nj < 2; nj++){
        ag[mi][nj] = mfma16(af[mi], bg[nj], ag[mi][nj]);
        au[mi][nj] = mfma16(af[mi], bu[nj], au[mi][nj]);
      }
    __syncthreads();
  }

  #pragma unroll
  for (int mi = 0; mi < 4; mi++)
    #pragma unroll
    for (int nj = 0; nj < 2; nj++)
      #pragma unroll
      for (int r = 0; r < 4; r++){
        int pos = bm + wr*64 + mi*16 + fg*4 + r;
        int col = bn + wc*32 + nj*16 + fr;
        float g = ag[mi][nj][r], u = au[mi][nj][r];
        float h = g / (1.0f + __expf(-g)) * u * w_list[e*T_TOK + pos];
        Hb[((size_t)e*T_TOK + pos)*MDIM + col] = f2b(h);
      }
}

// ---------- sparse down GEMM: atomic-accumulate expert outputs onto Out ----------

__global__ __launch_bounds__(256, 2)
void gemm_down_sp(const u16* __restrict__ Hb, const u16* __restrict__ WdT,
                  const int* __restrict__ tok_list, const int* __restrict__ cnt_pad,
                  float* __restrict__ Out)
{
  const int e = blockIdx.z;
  const int bm = blockIdx.y * 128;
  if (bm >= cnt_pad[e]) return;
  __shared__ u16 As[128*32];
  __shared__ u16 Bs[128*32];
  const int tid = threadIdx.x;
  const int lane = tid & 63;
  const int wave = tid >> 6;
  const int wr = wave >> 1, wc = wave & 1;
  const int fr = lane & 15, fg = lane >> 4;
  const int bn = blockIdx.x * 128;
  const int srow = tid >> 2, skb = (tid & 3) ^ (srow & 3);

  f32x4_t acc[4][4] = {};

  const u16* A  = Hb  + (size_t)e * T_TOK * MDIM;
  const u16* Bt = WdT + (size_t)e * HID * MDIM;
  const u16* ga0 = A + (size_t)(bm + srow) * MDIM + skb * 8;
  const u16* gb0 = Bt + (size_t)(bn + srow) * MDIM + skb * 8;
  for (int kk = 0; kk < MDIM; kk += 32){
    gload16(ga0 + kk, &As[tid*8]);
    gload16(ga0 + (size_t)64*MDIM + kk, &As[2048 + tid*8]);
    gload16(gb0 + kk, &Bs[tid*8]);
    gload16(gb0 + (size_t)64*MDIM + kk, &Bs[2048 + tid*8]);
    __syncthreads();
    bf16x8_t af[4], bfv[4];
    #pragma unroll
    for (int i = 0; i < 4; i++) af[i]  = ldfsw64(As, wr*64 + i*16 + fr, fg*8);
    #pragma unroll
    for (int i = 0; i < 4; i++) bfv[i] = ldfsw64(Bs, wc*64 + i*16 + fr, fg*8);
    #pragma unroll
    for (int mi = 0; mi < 4; mi++)
      #pragma unroll
      for (int ni = 0; ni < 4; ni++)
        acc[mi][ni] = mfma16(af[mi], bfv[ni], acc[mi][ni]);
    __syncthreads();
  }

  #pragma unroll
  for (int mi = 0; mi < 4; mi++)
    #pragma unroll
    for (int r = 0; r < 4; r++){
      int pos = bm + wr*64 + mi*16 + fg*4 + r;
      int tok = tok_list[e*T_TOK + pos];
      #pragma unroll
      for (int ni = 0; ni < 4; ni++){
        int col = bn + wc*64 + ni*16 + fr;
        atomicAdd(&Out[(size_t)tok * HID + col], acc[mi][ni][r]);
      }
    }
}

// ---------- launch ----------
// Workspace plan (peak ~185 MB; ws budget ~256 MB):
//   R0  96MB: Wq/Wk/Wv/Wo 3-way splits  -> (after O-proj) WgT/WuT/WdT
//   R1  24MB: xn1..3 -> vt1..3 -> ynb(8MB)+yn(16MB f32)
//   R2  24MB: q1..3  -> hb[0..24MB)
//   R3  24MB: k1..3  -> ao1..3 -> hb[24..32MB)
//   R4  16MB: vf(f32) -> aof(f32) -> x1(f32, lives to end)
//   RS: tok_list/w_list/cur/cnt_pad/rope tables

extern "C" void kernel_launch(void* const* d_in, const int* in_sizes, int n_in,
                              void* d_out, int out_size, void* d_ws, size_t ws_size,
                              hipStream_t stream)
{
  const float* hs     = (const float*)d_in[0];
  const float* w_attn = (const float*)d_in[1];
  const float* Wq = (const float*)d_in[2];
  const float* Wk = (const float*)d_in[3];
  const float* Wv = (const float*)d_in[4];
  const float* Wo = (const float*)d_in[5];
  const float* w_moe = (const float*)d_in[6];
  const float* Wr = (const float*)d_in[7];
  const float* Wg = (const float*)d_in[8];
  const float* Wu = (const float*)d_in[9];
  const float* Wd = (const float*)d_in[10];
  float* out = (float*)d_out;
  (void)in_sizes; (void)n_in; (void)out_size; (void)ws_size;

  char* ws = (char*)d_ws;
  const size_t MB = 1024*1024;
  char* R0 = ws;                 // 96 MB
  char* R1 = ws + 96*MB;         // 24 MB
  char* R2 = ws + 120*MB;        // 24 MB
  char* R3 = ws + 144*MB;        // 24 MB
  char* R4 = ws + 168*MB;        // 16 MB
  char* RS = ws + 184*MB;        // small buffers

  // phase A pointers (attention)
  const size_t WSLB = (size_t)HID*HID;   // elements per split slab (8 MB)
  u16* W0 = (u16*)R0;
  u16 *Wq1 = W0,          *Wq2 = W0 + WSLB,    *Wq3 = W0 + 2*WSLB;
  u16 *Wk1 = W0 + 3*WSLB, *Wk2 = W0 + 4*WSLB,  *Wk3 = W0 + 5*WSLB;
  u16 *Wv1 = W0 + 6*WSLB, *Wv2 = W0 + 7*WSLB,  *Wv3 = W0 + 8*WSLB;
  u16 *Wo1 = W0 + 9*WSLB, *Wo2 = W0 + 10*WSLB, *Wo3 = W0 + 11*WSLB;
  const size_t TSLB = (size_t)T_TOK*HID;  // elements per activation slab (8 MB)
  u16 *xn1 = (u16*)R1, *xn2 = (u16*)R1 + TSLB, *xn3 = (u16*)R1 + 2*TSLB;
  u16 *q1  = (u16*)R2, *q2  = (u16*)R2 + TSLB, *q3  = (u16*)R2 + 2*TSLB;
  u16 *k1  = (u16*)R3, *k2  = (u16*)R3 + TSLB, *k3  = (u16*)R3 + 2*TSLB;
  u16 *vt1 = xn1, *vt2 = xn2, *vt3 = xn3;        // reuse R1 after xn is dead
  float* vf  = (float*)R4;
  float* aof = (float*)R4;                        // reuse after vtrans
  u16 *ao1 = k1, *ao2 = k2, *ao3 = k3;            // reuse R3 after fattn
  float* x1  = (float*)R4;                        // reuse after split3 (O-proj out)
  // phase B pointers (MoE)
  u16* WgT = (u16*)R0;                            // 32 MB
  u16* WuT = (u16*)R0 + (size_t)NEXP*MDIM*HID;    // 32 MB
  u16* WdT = (u16*)R0 + 2*(size_t)NEXP*MDIM*HID;  // 32 MB
  u16* ynb = (u16*)R1;                            // 8 MB
  float* yn = (float*)(R1 + 8*MB);                // 16 MB
  u16* hb  = (u16*)R2;                            // 32 MB spans R2 + first 8MB of R3
  int*   tok_list = (int*)RS;                     // 64 KB
  float* w_list   = (float*)(RS + 64*1024);       // 64 KB
  int*   cur      = (int*)(RS + 128*1024);
  int*   cnt_pad  = (int*)(RS + 132*1024);
  float* ct   = (float*)(RS + 256*1024);
  float* stab = (float*)(RS + 384*1024);

  dim3 blk256(256), blkT(32,8), g64(64,64), gMoE(16,16,8);

  rope_table_k<<<dim3(SEQ*32/256), blk256, 0, stream>>>(ct, stab);
  convT3<<<g64, blkT, 0, stream>>>(Wq, Wq1, Wq2, Wq3, HID, HID);
  convT3<<<g64, blkT, 0, stream>>>(Wk, Wk1, Wk2, Wk3, HID, HID);
  convT3<<<g64, blkT, 0, stream>>>(Wv, Wv1, Wv2, Wv3, HID, HID);
  convT3<<<g64, blkT, 0, stream>>>(Wo, Wo1, Wo2, Wo3, HID, HID);

  rmsnorm3_k<<<dim3(T_TOK), blk256, 0, stream>>>(hs, w_attn, xn1, xn2, xn3);

  // fused Q/K/V (rope+split for Q,K; f32 for V) — 768 blocks, 3/CU co-resident
  gemm_qkv<<<dim3(16,16,3), blk256, 0, stream>>>(xn1,xn2,xn3,
      Wq1,Wq2,Wq3, Wk1,Wk2,Wk3, Wv1,Wv2,Wv3,
      q1,q2,q3, k1,k2,k3, vf, ct, stab);

  vtrans3_k<<<dim3(SEQ/64, BATCH*NHEAD), blk256, 0, stream>>>(vf, vt1, vt2, vt3);   // xn dead

  fattn3_k<<<dim3(BATCH*NHEAD, SEQ/64), blk256, 0, stream>>>(q1,q2,q3, k1,k2,k3, vt1,vt2,vt3, aof);  // vf dead

  split3_k<<<dim3(T_TOK*HID/1024), blk256, 0, stream>>>(aof, ao1, ao2, ao3);        // k dead

  // O-projection, 128x64 tiles — 512 blocks, 2/CU co-resident
  gemm_o<<<dim3(32,16), blk256, 0, stream>>>(ao1,ao2,ao3, Wo1,Wo2,Wo3, x1, hs);     // aof dead

  // attention weights dead -> convert MoE weights into R0
  convT<<<dim3(MDIM/32, HID/32, NEXP), blkT, 0, stream>>>(Wg, WgT, HID, MDIM);
  convT<<<dim3(MDIM/32, HID/32, NEXP), blkT, 0, stream>>>(Wu, WuT, HID, MDIM);
  convT<<<dim3(HID/32, MDIM/32, NEXP), blkT, 0, stream>>>(Wd, WdT, MDIM, HID);

  // MoE norm also initializes Out with the residual x1
  rmsnorm_k<<<dim3(T_TOK), blk256, 0, stream>>>(x1, w_moe, ynb, yn, out);   // vt dead

  hipMemsetAsync(cur, 0, NEXP*sizeof(int), stream);
  router_scatter_k<<<dim3(T_TOK), dim3(64), 0, stream>>>(yn, Wr, tok_list, w_list, cur);
  pad_k<<<dim3(NEXP), dim3(128), 0, stream>>>(cur, tok_list, w_list, cnt_pad);

  gemm_gateup_sp<<<gMoE, blk256, 0, stream>>>(ynb, WgT, WuT, tok_list, w_list, cnt_pad, hb);  // q, ao dead
  gemm_down_sp<<<gMoE, blk256, 0, stream>>>(hb, WdT, tok_list, cnt_pad, out);
}

// Round 7
// 1087.448 us; speedup vs baseline: 2.2683x; 1.0134x over previous
//
#include <hip/hip_runtime.h>
#include <hip/hip_bf16.h>
#include <cstdint>

typedef unsigned short u16;
typedef __bf16 bf16x4_t __attribute__((ext_vector_type(4)));
typedef __bf16 bf16x8_t __attribute__((ext_vector_type(8)));
typedef float f32x4_t __attribute__((ext_vector_type(4)));
typedef unsigned short us4_t __attribute__((ext_vector_type(4)));

#define BATCH 2
#define SEQ 1024
#define HID 2048
#define NHEAD 32
#define NEXP 8
#define MDIM 1024
#define T_TOK (BATCH*SEQ)   // 2048

// ---------- helpers ----------

__device__ __forceinline__ void gload16(const void* g, void* l){
  __builtin_amdgcn_global_load_lds((__attribute__((address_space(1))) void*)(uintptr_t)g,
                                   (__attribute__((address_space(3))) void*)l, 16, 0, 0);
}

// 8-bf16 MFMA fragment as two b64 halves (k = fg*4+e and +16; bijective k-map
// used identically on A and B sides -> product invariant).
__device__ __forceinline__ bf16x8_t ldfrag(const u16* lo){
  bf16x4_t a = *(const bf16x4_t*)lo;
  bf16x4_t b = *(const bf16x4_t*)(lo + 16);
  return __builtin_shufflevector(a, b, 0,1,2,3,4,5,6,7);
}

// Swizzled fragment read, 128B LDS rows (fattn K/V/P): byte ^= (row&7)<<4.
__device__ __forceinline__ bf16x8_t ldfsw128(const u16* base, int row, int colbyte){
  const char* p = (const char*)base + row*128;
  int sw = (row & 7) << 4;
  bf16x4_t a = *(const bf16x4_t*)(p + (colbyte ^ sw));
  bf16x4_t b = *(const bf16x4_t*)(p + ((colbyte + 32) ^ sw));
  return __builtin_shufflevector(a, b, 0,1,2,3,4,5,6,7);
}

// Swizzled fragment read, 64B LDS rows (GEMM tiles, BK=32): byte ^= (row&3)<<4.
__device__ __forceinline__ bf16x8_t ldfsw64(const u16* base, int row, int colbyte){
  const char* p = (const char*)base + row*64;
  int sw = (row & 3) << 4;
  bf16x4_t a = *(const bf16x4_t*)(p + (colbyte ^ sw));
  bf16x4_t b = *(const bf16x4_t*)(p + ((colbyte + 32) ^ sw));
  return __builtin_shufflevector(a, b, 0,1,2,3,4,5,6,7);
}

__device__ __forceinline__ f32x4_t mfma16(bf16x8_t a, bf16x8_t b, f32x4_t c){
  return __builtin_amdgcn_mfma_f32_16x16x32_bf16(a, b, c, 0, 0, 0);
}

__device__ __forceinline__ u16 f2b(float f){
  __hip_bfloat16 h = __float2bfloat16(f);
  return __builtin_bit_cast(u16, h);
}
__device__ __forceinline__ float b2f(u16 b){
  return __builtin_bit_cast(float, (unsigned int)b << 16);
}
// 3-way bf16 split: v ~= b1 + b2 + b3 with |residual| <= 2^-27 |v|
__device__ __forceinline__ void split3v(float v, u16& b1, u16& b2, u16& b3){
  b1 = f2b(v); float f1 = b2f(b1);
  float r1 = v - f1;
  b2 = f2b(r1); float f2 = b2f(b2);
  b3 = f2b(r1 - f2);
}

// ---------- weight convert+transpose (single bf16, MoE): f32 [R][C] -> bf16 [C][R] ----------
// 64x64 tile, 256 threads, float4 loads / us4 writes.

__global__ __launch_bounds__(256)
void convT(const float* __restrict__ in, u16* __restrict__ out, int R, int C)
{
  __shared__ float t[64][65];
  int bz = blockIdx.z;
  const float* ip = in + (size_t)bz * R * C;
  u16* op = out + (size_t)bz * R * C;
  int r0 = blockIdx.y*64, c0 = blockIdx.x*64;
  int tid = threadIdx.x;
  int lr = tid >> 4;          // 0..15
  int lc = (tid & 15) * 4;    // 0..60
  #pragma unroll
  for (int i = 0; i < 4; i++){
    int r = lr + i*16;
    float4 v = *(const float4*)&ip[(size_t)(r0 + r) * C + c0 + lc];
    t[r][lc] = v.x; t[r][lc+1] = v.y; t[r][lc+2] = v.z; t[r][lc+3] = v.w;
  }
  __syncthreads();
  #pragma unroll
  for (int i = 0; i < 4; i++){
    int c = lr + i*16;
    us4_t o;
    o.x = f2b(t[lc+0][c]); o.y = f2b(t[lc+1][c]);
    o.z = f2b(t[lc+2][c]); o.w = f2b(t[lc+3][c]);
    *(us4_t*)&op[(size_t)(c0 + c) * R + r0 + lc] = o;
  }
}

// ---------- weight convert+transpose, 3-way split (attention weights) ----------

__global__ __launch_bounds__(256)
void convT3(const float* __restrict__ in, u16* __restrict__ o1, u16* __restrict__ o2,
            u16* __restrict__ o3, int R, int C)
{
  __shared__ float t[64][65];
  int r0 = blockIdx.y*64, c0 = blockIdx.x*64;
  int tid = threadIdx.x;
  int lr = tid >> 4;
  int lc = (tid & 15) * 4;
  #pragma unroll
  for (int i = 0; i < 4; i++){
    int r = lr + i*16;
    float4 v = *(const float4*)&in[(size_t)(r0 + r) * C + c0 + lc];
    t[r][lc] = v.x; t[r][lc+1] = v.y; t[r][lc+2] = v.z; t[r][lc+3] = v.w;
  }
  __syncthreads();
  #pragma unroll
  for (int i = 0; i < 4; i++){
    int c = lr + i*16;
    us4_t v1, v2, v3;
    #pragma unroll
    for (int j = 0; j < 4; j++){
      u16 b1, b2, b3; split3v(t[lc+j][c], b1, b2, b3);
      v1[j] = b1; v2[j] = b2; v3[j] = b3;
    }
    size_t idx = (size_t)(c0 + c) * R + r0 + lc;
    *(us4_t*)&o1[idx] = v1; *(us4_t*)&o2[idx] = v2; *(us4_t*)&o3[idx] = v3;
  }
}

// ---------- RMSNorm -> 3-way split (attention input) ----------

__global__ __launch_bounds__(256)
void rmsnorm3_k(const float* __restrict__ x, const float* __restrict__ w,
                u16* __restrict__ o1, u16* __restrict__ o2, u16* __restrict__ o3)
{
  int row = blockIdx.x;
  const float* xr = x + (size_t)row * HID;
  int base = threadIdx.x * 8;
  float4 a = *(const float4*)(xr + base);
  float4 b = *(const float4*)(xr + base + 4);
  float ss = a.x*a.x + a.y*a.y + a.z*a.z + a.w*a.w
           + b.x*b.x + b.y*b.y + b.z*b.z + b.w*b.w;
  #pragma unroll
  for (int off = 32; off; off >>= 1) ss += __shfl_down(ss, off);
  __shared__ float red[4];
  if ((threadIdx.x & 63) == 0) red[threadIdx.x >> 6] = ss;
  __syncthreads();
  float tot = red[0] + red[1] + red[2] + red[3];
  float rs = (float)(1.0 / sqrt((double)tot * (1.0/2048.0) + 1e-5));
  float4 wa = *(const float4*)(w + base);
  float4 wb = *(const float4*)(w + base + 4);
  float o[8];
  o[0]=a.x*rs*wa.x; o[1]=a.y*rs*wa.y; o[2]=a.z*rs*wa.z; o[3]=a.w*rs*wa.w;
  o[4]=b.x*rs*wb.x; o[5]=b.y*rs*wb.y; o[6]=b.z*rs*wb.z; o[7]=b.w*rs*wb.w;
  us4_t v1[2], v2[2], v3[2];
  #pragma unroll
  for (int j = 0; j < 8; j++){
    u16 b1, b2, b3; split3v(o[j], b1, b2, b3);
    v1[j>>2][j&3] = b1; v2[j>>2][j&3] = b2; v3[j>>2][j&3] = b3;
  }
  size_t idx = (size_t)row*HID + base;
  *(us4_t*)&o1[idx] = v1[0]; *(us4_t*)&o1[idx+4] = v1[1];
  *(us4_t*)&o2[idx] = v2[0]; *(us4_t*)&o2[idx+4] = v2[1];
  *(us4_t*)&o3[idx] = v3[0]; *(us4_t*)&o3[idx+4] = v3[1];
}

// ---------- RMSNorm (MoE): bf16 out + f32 out + residual passthrough to Out ----------

__global__ __launch_bounds__(256)
void rmsnorm_k(const float* __restrict__ x, const float* __restrict__ w,
               u16* __restrict__ ob, float* __restrict__ of, float* __restrict__ oi)
{
  int row = blockIdx.x;
  const float* xr = x + (size_t)row * HID;
  int base = threadIdx.x * 8;
  float4 a = *(const float4*)(xr + base);
  float4 b = *(const float4*)(xr + base + 4);
  float ss = a.x*a.x + a.y*a.y + a.z*a.z + a.w*a.w
           + b.x*b.x + b.y*b.y + b.z*b.z + b.w*b.w;
  #pragma unroll
  for (int off = 32; off; off >>= 1) ss += __shfl_down(ss, off);
  __shared__ float red[4];
  if ((threadIdx.x & 63) == 0) red[threadIdx.x >> 6] = ss;
  __syncthreads();
  float tot = red[0] + red[1] + red[2] + red[3];
  float rs = (float)(1.0 / sqrt((double)tot * (1.0/2048.0) + 1e-5));
  float4 wa = *(const float4*)(w + base);
  float4 wb = *(const float4*)(w + base + 4);
  float o[8];
  o[0]=a.x*rs*wa.x; o[1]=a.y*rs*wa.y; o[2]=a.z*rs*wa.z; o[3]=a.w*rs*wa.w;
  o[4]=b.x*rs*wb.x; o[5]=b.y*rs*wb.y; o[6]=b.z*rs*wb.z; o[7]=b.w*rs*wb.w;
  us4_t p0, p1;
  p0.x=f2b(o[0]); p0.y=f2b(o[1]); p0.z=f2b(o[2]); p0.w=f2b(o[3]);
  p1.x=f2b(o[4]); p1.y=f2b(o[5]); p1.z=f2b(o[6]); p1.w=f2b(o[7]);
  *(us4_t*)&ob[(size_t)row*HID + base] = p0;
  *(us4_t*)&ob[(size_t)row*HID + base + 4] = p1;
  float* orow = of + (size_t)row*HID + base;
  *(float4*)orow = make_float4(o[0],o[1],o[2],o[3]);
  *(float4*)(orow+4) = make_float4(o[4],o[5],o[6],o[7]);
  float* irow = oi + (size_t)row*HID + base;
  *(float4*)irow = a;
  *(float4*)(irow+4) = b;
}

// ---------- RoPE table (f64 math -> f32) ----------

__global__ void rope_table_k(float* ct, float* st){
  int i = blockIdx.x*256 + threadIdx.x;   // SEQ*32
  int s = i >> 5, j = i & 31;
  double invf = exp(-(double)j / 32.0 * log(10000.0));
  double ang = (double)s * invf;
  ct[i] = (float)cos(ang);
  st[i] = (float)sin(ang);
}

// ---------- fused Q/K/V split GEMM: z=0 -> Q(rope+split), z=1 -> K(rope+split), z=2 -> V(f32) ----------
// 768 blocks -> 3 co-resident blocks/CU. XCD-bijective block swizzle (768 = 8*96).
// mi-major 6-product schedule: 24 fragment loads/wave/kstep (minimal), per-acc
// accumulation order identical to previous rounds (bit-identical output).

__global__ __launch_bounds__(256, 2)
void gemm_qkv(const u16* __restrict__ A1, const u16* __restrict__ A2, const u16* __restrict__ A3,
              const u16* __restrict__ Wq1, const u16* __restrict__ Wq2, const u16* __restrict__ Wq3,
              const u16* __restrict__ Wk1, const u16* __restrict__ Wk2, const u16* __restrict__ Wk3,
              const u16* __restrict__ Wv1, const u16* __restrict__ Wv2, const u16* __restrict__ Wv3,
              u16* __restrict__ oq1, u16* __restrict__ oq2, u16* __restrict__ oq3,
              u16* __restrict__ ok1, u16* __restrict__ ok2, u16* __restrict__ ok3,
              float* __restrict__ vf,
              const float* __restrict__ ct, const float* __restrict__ st)
{
  __shared__ u16 As[3][128*32];
  __shared__ u16 Bs[3][128*32];
  const int flat = blockIdx.x + 16*blockIdx.y + 256*blockIdx.z;
  const int logical = (flat & 7) * 96 + (flat >> 3);   // XCD-contiguous chunks
  const int z  = logical >> 8;
  const int bm = ((logical >> 4) & 15) * 128;
  const int bn = (logical & 15) * 128;
  const int tid = threadIdx.x;
  const int lane = tid & 63;
  const int wave = tid >> 6;
  const int wr = wave >> 1, wc = wave & 1;
  const int fr = lane & 15, fg = lane >> 4;

  f32x4_t acc[4][4] = {};

  const int srow = tid >> 2, skb = (tid & 3) ^ (srow & 3);   // swizzled source chunk
  const u16* Ap[3] = {A1, A2, A3};
  const u16* Bp[3];
  if (z == 0)      { Bp[0] = Wq1; Bp[1] = Wq2; Bp[2] = Wq3; }
  else if (z == 1) { Bp[0] = Wk1; Bp[1] = Wk2; Bp[2] = Wk3; }
  else             { Bp[0] = Wv1; Bp[1] = Wv2; Bp[2] = Wv3; }
  const u16* gA[3]; const u16* gB[3];
  #pragma unroll
  for (int t = 0; t < 3; t++){
    gA[t] = Ap[t] + (size_t)(bm + srow) * HID + skb * 8;
    gB[t] = Bp[t] + (size_t)(bn + srow) * HID + skb * 8;
  }

  for (int kk = 0; kk < HID; kk += 32){
    #pragma unroll
    for (int t = 0; t < 3; t++){
      gload16(gA[t] + kk,                    &As[t][tid*8]);
      gload16(gA[t] + (size_t)64*HID + kk,   &As[t][2048 + tid*8]);
      gload16(gB[t] + kk,                    &Bs[t][tid*8]);
      gload16(gB[t] + (size_t)64*HID + kk,   &Bs[t][2048 + tid*8]);
    }
    __syncthreads();
    bf16x8_t bfv[3][4];
    #pragma unroll
    for (int t = 0; t < 3; t++)
      #pragma unroll
      for (int i = 0; i < 4; i++)
        bfv[t][i] = ldfsw64(Bs[t], wc*64 + i*16 + fr, fg*8);
    #pragma unroll
    for (int mi = 0; mi < 4; mi++){
      const int arow = wr*64 + mi*16 + fr;
      bf16x8_t a1 = ldfsw64(As[0], arow, fg*8);
      bf16x8_t a2 = ldfsw64(As[1], arow, fg*8);
      bf16x8_t a3 = ldfsw64(As[2], arow, fg*8);
      #pragma unroll
      for (int ni = 0; ni < 4; ni++){
        f32x4_t c = acc[mi][ni];
        c = mfma16(a3, bfv[0][ni], c);   // a3b1
        c = mfma16(a2, bfv[1][ni], c);   // a2b2
        c = mfma16(a1, bfv[2][ni], c);   // a1b3
        c = mfma16(a2, bfv[0][ni], c);   // a2b1
        c = mfma16(a1, bfv[1][ni], c);   // a1b2
        c = mfma16(a1, bfv[0][ni], c);   // a1b1
        acc[mi][ni] = c;
      }
    }
    __syncthreads();
  }

  if (z < 2){
    u16* O1 = z ? ok1 : oq1;
    u16* O2 = z ? ok2 : oq2;
    u16* O3 = z ? ok3 : oq3;
    #pragma unroll
    for (int mi = 0; mi < 4; mi++)
      #pragma unroll
      for (int r = 0; r < 4; r++){
        int row = bm + wr*64 + mi*16 + fg*4 + r;
        int s = row & (SEQ-1);
        #pragma unroll
        for (int ni = 0; ni < 2; ni++){
          int dlo = ni*16 + fr;   // 0..31 within head
          float c  = ct[s*32 + dlo];
          float sn = st[s*32 + dlo];
          float xl = acc[mi][ni][r], xh = acc[mi][ni+2][r];
          float ol = xl*c - xh*sn;
          float oh = xh*c + xl*sn;
          size_t idx = (size_t)row * HID + bn + wc*64 + ni*16 + fr;
          u16 b1, b2, b3;
          split3v(ol, b1, b2, b3); O1[idx] = b1;    O2[idx] = b2;    O3[idx] = b3;
          split3v(oh, b1, b2, b3); O1[idx+32] = b1; O2[idx+32] = b2; O3[idx+32] = b3;
        }
      }
  } else {
    #pragma unroll
    for (int mi = 0; mi < 4; mi++)
      #pragma unroll
      for (int ni = 0; ni < 4; ni++)
        #pragma unroll
        for (int r = 0; r < 4; r++){
          int row = bm + wr*64 + mi*16 + fg*4 + r;
          int col = bn + wc*64 + ni*16 + fr;
          vf[(size_t)row * HID + col] = acc[mi][ni][r];
        }
  }
}

// ---------- O-projection split GEMM, 128x64 tiles (512 blocks -> 2/CU), +residual ----------

__global__ __launch_bounds__(256, 2)
void gemm_o(const u16* __restrict__ A1, const u16* __restrict__ A2, const u16* __restrict__ A3,
            const u16* __restrict__ B1, const u16* __restrict__ B2, const u16* __restrict__ B3,
            float* __restrict__ Cf, const float* __restrict__ Res)
{
  __shared__ u16 As[3][128*32];   // 24KB
  __shared__ u16 Bs[3][64*32];    // 12KB
  const int flat = blockIdx.x + 32*blockIdx.y;
  const int logical = (flat & 7) * 64 + (flat >> 3);   // 512 = 8*64
  const int bn = (logical & 31) * 64;
  const int bm = (logical >> 5) * 128;
  const int tid = threadIdx.x;
  const int lane = tid & 63;
  const int wave = tid >> 6;
  const int wr = wave >> 1, wc = wave & 1;
  const int fr = lane & 15, fg = lane >> 4;

  f32x4_t acc[4][2] = {};

  const int srow = tid >> 2, skb = (tid & 3) ^ (srow & 3);
  const u16* Ap[3] = {A1, A2, A3};
  const u16* Bp[3] = {B1, B2, B3};
  const u16* gA[3]; const u16* gB[3];
  #pragma unroll
  for (int t = 0; t < 3; t++){
    gA[t] = Ap[t] + (size_t)(bm + srow) * HID + skb * 8;
    gB[t] = Bp[t] + (size_t)(bn + srow) * HID + skb * 8;
  }

  for (int kk = 0; kk < HID; kk += 32){
    #pragma unroll
    for (int t = 0; t < 3; t++){
      gload16(gA[t] + kk,                    &As[t][tid*8]);
      gload16(gA[t] + (size_t)64*HID + kk,   &As[t][2048 + tid*8]);
      gload16(gB[t] + kk,                    &Bs[t][tid*8]);
    }
    __syncthreads();
    bf16x8_t bfv[3][2];
    #pragma unroll
    for (int t = 0; t < 3; t++)
      #pragma unroll
      for (int j = 0; j < 2; j++)
        bfv[t][j] = ldfsw64(Bs[t], wc*32 + j*16 + fr, fg*8);
    #pragma unroll
    for (int mi = 0; mi < 4; mi++){
      const int arow = wr*64 + mi*16 + fr;
      bf16x8_t a1 = ldfsw64(As[0], arow, fg*8);
      bf16x8_t a2 = ldfsw64(As[1], arow, fg*8);
      bf16x8_t a3 = ldfsw64(As[2], arow, fg*8);
      #pragma unroll
      for (int nj = 0; nj < 2; nj++){
        f32x4_t c = acc[mi][nj];
        c = mfma16(a3, bfv[0][nj], c);
        c = mfma16(a2, bfv[1][nj], c);
        c = mfma16(a1, bfv[2][nj], c);
        c = mfma16(a2, bfv[0][nj], c);
        c = mfma16(a1, bfv[1][nj], c);
        c = mfma16(a1, bfv[0][nj], c);
        acc[mi][nj] = c;
      }
    }
    __syncthreads();
  }

  #pragma unroll
  for (int mi = 0; mi < 4; mi++)
    #pragma unroll
    for (int nj = 0; nj < 2; nj++)
      #pragma unroll
      for (int r = 0; r < 4; r++){
        int row = bm + wr*64 + mi*16 + fg*4 + r;
        int col = bn + wc*32 + nj*16 + fr;
        size_t idx = (size_t)row * HID + col;
        Cf[idx] = acc[mi][nj][r] + Res[idx];
      }
}

// ---------- elementwise 3-way split (attention output) ----------

__global__ __launch_bounds__(256)
void split3_k(const float* __restrict__ in, u16* __restrict__ o1, u16* __restrict__ o2,
              u16* __restrict__ o3)
{
  size_t i = ((size_t)blockIdx.x*256 + threadIdx.x) * 4;
  float4 v = *(const float4*)(in + i);
  us4_t v1, v2, v3;
  u16 b1, b2, b3;
  split3v(v.x, b1,b2,b3); v1.x=b1; v2.x=b2; v3.x=b3;
  split3v(v.y, b1,b2,b3); v1.y=b1; v2.y=b2; v3.y=b3;
  split3v(v.z, b1,b2,b3); v1.z=b1; v2.z=b2; v3.z=b3;
  split3v(v.w, b1,b2,b3); v1.w=b1; v2.w=b2; v3.w=b3;
  *(us4_t*)&o1[i] = v1; *(us4_t*)&o2[i] = v2; *(us4_t*)&o3[i] = v3;
}

// ---------- V transpose + split: f32 [T][H] -> per (b,h) bf16x3 [64 d][1024 s] ----------

__global__ __launch_bounds__(256)
void vtrans3_k(const float* __restrict__ vf, u16* __restrict__ t1, u16* __restrict__ t2,
               u16* __restrict__ t3)
{
  __shared__ float t[64][65];
  int st0 = blockIdx.x * 64;
  int bh = blockIdx.y;
  int b = bh >> 5, h = bh & 31;
  int tid = threadIdx.x;
  #pragma unroll
  for (int i = 0; i < 4; i++){
    int idx = tid + i*256;                // 1024 float4 chunks
    int s = idx >> 4, dc = (idx & 15) * 4;
    float4 v = *(const float4*)&vf[(size_t)(b*SEQ + st0 + s) * HID + h*64 + dc];
    t[dc+0][s] = v.x; t[dc+1][s] = v.y; t[dc+2][s] = v.z; t[dc+3][s] = v.w;
  }
  __syncthreads();
  #pragma unroll
  for (int i = 0; i < 4; i++){
    int idx = tid + i*256;
    int d = idx >> 4, sc = (idx & 15) * 4;
    us4_t v1, v2, v3;
    #pragma unroll
    for (int j = 0; j < 4; j++){
      u16 b1, b2, b3; split3v(t[d][sc+j], b1, b2, b3);
      v1[j]=b1; v2[j]=b2; v3[j]=b3;
    }
    size_t base = ((size_t)bh*64 + d)*SEQ + st0 + sc;
    *(us4_t*)&t1[base] = v1; *(us4_t*)&t2[base] = v2; *(us4_t*)&t3[base] = v3;
  }
}

// ---------- flash attention, split-precision (causal), f32 out ----------

__global__ __launch_bounds__(256)
void fattn3_k(const u16* __restrict__ q1, const u16* __restrict__ q2, const u16* __restrict__ q3,
              const u16* __restrict__ k1, const u16* __restrict__ k2, const u16* __restrict__ k3,
              const u16* __restrict__ v1, const u16* __restrict__ v2, const u16* __restrict__ v3,
              float* __restrict__ aof)
{
  __shared__ u16 Ks[3][64*64];     // 24KB
  __shared__ u16 Vs[3][64*64];     // 24KB
  __shared__ u16 Ps[2][4][16*64];  // 16KB  -> 64KB total
  const int bh = blockIdx.x, qt = blockIdx.y;
  const int b = bh >> 5, h = bh & 31;
  const int tid = threadIdx.x, lane = tid & 63, wave = tid >> 6;
  const int fr = lane & 15, fg = lane >> 4;

  const size_t qrow = (size_t)(b*SEQ + qt*64 + wave*16 + fr);
  const u16* qp[3] = { q1 + qrow*HID + h*64, q2 + qrow*HID + h*64, q3 + qrow*HID + h*64 };
  bf16x8_t aq[3][2];
  #pragma unroll
  for (int t = 0; t < 3; t++)
    #pragma unroll
    for (int ks = 0; ks < 2; ks++) aq[t][ks] = ldfrag(qp[t] + ks*32 + fg*4);

  f32x4_t oacc[4] = {};
  float m_r[4], l_r[4];
  #pragma unroll
  for (int r = 0; r < 4; r++){ m_r[r] = -1e30f; l_r[r] = 0.f; }

  const int sr = tid >> 3, sp = (tid & 7) ^ (sr & 7);   // swizzled source chunk
  const u16* kb[3] = { k1 + ((size_t)(b*SEQ) + sr)*HID + h*64 + sp*8,
                       k2 + ((size_t)(b*SEQ) + sr)*HID + h*64 + sp*8,
                       k3 + ((size_t)(b*SEQ) + sr)*HID + h*64 + sp*8 };
  const u16* vb[3] = { v1 + ((size_t)bh*64 + sr)*SEQ + sp*8,
                       v2 + ((size_t)bh*64 + sr)*SEQ + sp*8,
                       v3 + ((size_t)bh*64 + sr)*SEQ + sp*8 };

  for (int kt = 0; kt <= qt; kt++){
    #pragma unroll
    for (int t = 0; t < 3; t++){
      gload16(kb[t] + (size_t)(kt*64) * HID,    &Ks[t][tid*8]);
      gload16(kb[t] + (size_t)(kt*64+32) * HID, &Ks[t][2048 + tid*8]);
      gload16(vb[t] + kt*64,                    &Vs[t][tid*8]);
      gload16(vb[t] + (size_t)32*SEQ + kt*64,   &Vs[t][2048 + tid*8]);
    }
    __syncthreads();

    f32x4_t sc[4] = {};
    #pragma unroll
    for (int nf = 0; nf < 4; nf++)
      #pragma unroll
      for (int ks = 0; ks < 2; ks++){
        int krow = nf*16 + fr, kcb = ks*64 + fg*8;
        bf16x8_t bk0 = ldfsw128(Ks[0], krow, kcb);
        bf16x8_t bk1 = ldfsw128(Ks[1], krow, kcb);
        bf16x8_t bk2 = ldfsw128(Ks[2], krow, kcb);
        sc[nf] = mfma16(aq[2][ks], bk0, sc[nf]);
        sc[nf] = mfma16(aq[1][ks], bk1, sc[nf]);
        sc[nf] = mfma16(aq[0][ks], bk2, sc[nf]);
        sc[nf] = mfma16(aq[1][ks], bk0, sc[nf]);
        sc[nf] = mfma16(aq[0][ks], bk1, sc[nf]);
        sc[nf] = mfma16(aq[0][ks], bk0, sc[nf]);
      }

    float nm[4] = {-1e30f,-1e30f,-1e30f,-1e30f};
    #pragma unroll
    for (int nf = 0; nf < 4; nf++)
      #pragma unroll
      for (int r = 0; r < 4; r++){
        float v = sc[nf][r] * 0.125f;
        if (kt == qt && nf*16 + fr > wave*16 + fg*4 + r) v = -1e30f;
        sc[nf][r] = v;
        nm[r] = fmaxf(nm[r], v);
      }
    #pragma unroll
    for (int r = 0; r < 4; r++)
      #pragma unroll
      for (int msk = 8; msk; msk >>= 1) nm[r] = fmaxf(nm[r], __shfl_xor(nm[r], msk));

    #pragma unroll
    for (int r = 0; r < 4; r++){
      float mn = fmaxf(m_r[r], nm[r]);
      float f = __expf(m_r[r] - mn);
      m_r[r] = mn;
      float rsum = 0.f;
      #pragma unroll
      for (int nf = 0; nf < 4; nf++){
        float pv = __expf(sc[nf][r] - mn);
        sc[nf][r] = pv;
        rsum += pv;
      }
      #pragma unroll
      for (int msk = 8; msk; msk >>= 1) rsum += __shfl_xor(rsum, msk);
      l_r[r] = l_r[r]*f + rsum;
      #pragma unroll
      for (int df = 0; df < 4; df++) oacc[df][r] *= f;
    }

    // P 2-way split to LDS (swizzled writes matching ldfsw128 reads)
    #pragma unroll
    for (int nf = 0; nf < 4; nf++)
      #pragma unroll
      for (int r = 0; r < 4; r++){
        float pv = sc[nf][r];
        u16 b1 = f2b(pv);
        float f1 = b2f(b1);
        u16 b2 = f2b(pv - f1);
        int prow = fg*4 + r;
        int pbyte = (nf*32 + fr*2) ^ ((prow & 7) << 4);
        *(u16*)((char*)&Ps[0][wave][0] + prow*128 + pbyte) = b1;
        *(u16*)((char*)&Ps[1][wave][0] + prow*128 + pbyte) = b2;
      }

    #pragma unroll
    for (int ks = 0; ks < 2; ks++){
      bf16x8_t pa0 = ldfsw128(&Ps[0][wave][0], fr, ks*64 + fg*8);
      bf16x8_t pa1 = ldfsw128(&Ps[1][wave][0], fr, ks*64 + fg*8);
      #pragma unroll
      for (int df = 0; df < 4; df++){
        int vrow = df*16 + fr, vcb = ks*64 + fg*8;
        bf16x8_t bv0 = ldfsw128(Vs[0], vrow, vcb);
        bf16x8_t bv1 = ldfsw128(Vs[1], vrow, vcb);
        bf16x8_t bv2 = ldfsw128(Vs[2], vrow, vcb);
        oacc[df] = mfma16(pa0, bv2, oacc[df]);   // p1 v3
        oacc[df] = mfma16(pa1, bv1, oacc[df]);   // p2 v2
        oacc[df] = mfma16(pa1, bv0, oacc[df]);   // p2 v1
        oacc[df] = mfma16(pa0, bv1, oacc[df]);   // p1 v2
        oacc[df] = mfma16(pa0, bv0, oacc[df]);   // p1 v1
      }
    }
    __syncthreads();
  }

  #pragma unroll
  for (int r = 0; r < 4; r++){
    float inv = 1.f / l_r[r];
    int orow = b*SEQ + qt*64 + wave*16 + fg*4 + r;
    #pragma unroll
    for (int df = 0; df < 4; df++)
      aof[(size_t)orow * HID + h*64 + df*16 + fr] = oacc[df][r] * inv;
  }
}

// ---------- router + scatter: f64 logits, top-2, compact per-expert lists ----------

__global__ __launch_bounds__(64)
void router_scatter_k(const float* __restrict__ yn, const float* __restrict__ Wr,
                      int* __restrict__ tok_list, float* __restrict__ w_list,
                      int* __restrict__ cur){
  int row = blockIdx.x;
  int lane = threadIdx.x;
  const float* xr = yn + (size_t)row * HID;
  double acc[8] = {};
  for (int j = lane; j < HID; j += 64){
    double xv = (double)xr[j];
    const float* wr = Wr + (size_t)j*8;
    float4 w0 = *(const float4*)wr;
    float4 w1 = *(const float4*)(wr + 4);
    acc[0] += xv*w0.x; acc[1] += xv*w0.y; acc[2] += xv*w0.z; acc[3] += xv*w0.w;
    acc[4] += xv*w1.x; acc[5] += xv*w1.y; acc[6] += xv*w1.z; acc[7] += xv*w1.w;
  }
  #pragma unroll
  for (int e = 0; e < 8; e++)
    #pragma unroll
    for (int off = 32; off; off >>= 1) acc[e] += __shfl_down(acc[e], off);
  if (lane == 0){
    double mx = acc[0];
    #pragma unroll
    for (int e = 1; e < 8; e++) mx = fmax(mx, acc[e]);
    double p[8];
    #pragma unroll
    for (int e = 0; e < 8; e++) p[e] = exp(acc[e] - mx);
    int i1 = 0;
    #pragma unroll
    for (int e = 1; e < 8; e++) if (p[e] > p[i1]) i1 = e;
    int i2 = (i1 == 0) ? 1 : 0;
    #pragma unroll
    for (int e = 0; e < 8; e++) if (e != i1 && p[e] > p[i2]) i2 = e;
    double s2 = p[i1] + p[i2];
    int pos1 = atomicAdd(&cur[i1], 1);
    tok_list[i1*T_TOK + pos1] = row;
    w_list[i1*T_TOK + pos1] = (float)(p[i1] / s2);
    int pos2 = atomicAdd(&cur[i2], 1);
    tok_list[i2*T_TOK + pos2] = row;
    w_list[i2*T_TOK + pos2] = (float)(p[i2] / s2);
  }
}

// pad each expert's list to a multiple of 128 with (token 0, weight 0)
__global__ __launch_bounds__(128)
void pad_k(const int* __restrict__ cur, int* __restrict__ tok_list,
           float* __restrict__ w_list, int* __restrict__ cnt_pad){
  int e = blockIdx.x;
  int c = cur[e];
  int cp = (c + 127) & ~127;
  for (int i = c + threadIdx.x; i < cp; i += 128){
    tok_list[e*T_TOK + i] = 0;
    w_list[e*T_TOK + i] = 0.f;
  }
  if (threadIdx.x == 0) cnt_pad[e] = cp;
}

// ---------- sparse fused gate+up GEMM: h = silu(g)*u*w over compact token lists ----------

__global__ __launch_bounds__(256, 2)
void gemm_gateup_sp(const u16* __restrict__ A, const u16* __restrict__ WgT, const u16* __restrict__ WuT,
                    const int* __restrict__ tok_list, const float* __restrict__ w_list,
                    const int* __restrict__ cnt_pad, u16* __restrict__ Hb)
{
  const int e = blockIdx.z;
  const int bm = blockIdx.y * 128;   // position within expert list
  if (bm >= cnt_pad[e]) return;
  __shared__ u16 As[128*32];
  __shared__ u16 Bg[64*32];
  __shared__ u16 Bu[64*32];
  const int tid = threadIdx.x;
  const int lane = tid & 63;
  const int wave = tid >> 6;
  const int wr = wave >> 1, wc = wave & 1;
  const int fr = lane & 15, fg = lane >> 4;
  const int bn = blockIdx.x * 64;    // M cols

  f32x4_t ag[4][2] = {}, au[4][2] = {};

  const int srow = tid >> 2, skb = (tid & 3) ^ (srow & 3);   // swizzled source chunk
  const int tok0 = tok_list[e*T_TOK + bm + srow];
  const int tok1 = tok_list[e*T_TOK + bm + srow + 64];
  const u16* ga0 = A + (size_t)tok0 * HID + skb * 8;
  const u16* ga1 = A + (size_t)tok1 * HID + skb * 8;
  const u16* gg0 = WgT + ((size_t)e*MDIM + bn + srow) * HID + skb * 8;
  const u16* gu0 = WuT + ((size_t)e*MDIM + bn + srow) * HID + skb * 8;

  for (int kk = 0; kk < HID; kk += 32){
    gload16(ga0 + kk, &As[tid*8]);
    gload16(ga1 + kk, &As[2048 + tid*8]);
    gload16(gg0 + kk, &Bg[tid*8]);
    gload16(gu0 + kk, &Bu[tid*8]);
    __syncthreads();
    bf16x8_t af[4], bg[2], bu[2];
    #pragma unroll
    for (int i = 0; i < 4; i++) af[i] = ldfsw64(As, wr*64 + i*16 + fr, fg*8);
    #pragma unroll
    for (int j = 0; j < 2; j++){
      bg[j] = ldfsw64(Bg, wc*32 + j*16 + fr, fg*8);
      bu[j] = ldfsw64(Bu, wc*32 + j*16 + fr, fg*8);
    }
    #pragma unroll
    for (int mi = 0; mi < 4; mi++)
      #pragma unroll
      for (int nj = 0; nj < 2; nj++){
        ag[mi][nj] = mfma16(af[mi], bg[nj], ag[mi][nj]);
        au[mi][nj] = mfma16(af[mi], bu[nj], au[mi][nj]);
      }
    __syncthreads();
  }

  #pragma unroll
  for (int mi = 0; mi < 4; mi++)
    #pragma unroll
    for (int nj = 0; nj < 2; nj++)
      #pragma unroll
      for (int r = 0; r < 4; r++){
        int pos = bm + wr*64 + mi*16 + fg*4 + r;
        int col = bn + wc*32 + nj*16 + fr;
        float g = ag[mi][nj][r], u = au[mi][nj][r];
        float h = g / (1.0f + __expf(-g)) * u * w_list[e*T_TOK + pos];
        Hb[((size_t)e*T_TOK + pos)*MDIM + col] = f2b(h);
      }
}

// ---------- sparse down GEMM: atomic-accumulate expert outputs onto Out ----------

__global__ __launch_bounds__(256, 2)
void gemm_down_sp(const u16* __restrict__ Hb, const u16* __restrict__ WdT,
                  const int* __restrict__ tok_list, const int* __restrict__ cnt_pad,
                  float* __restrict__ Out)
{
  const int e = blockIdx.z;
  const int bm = blockIdx.y * 128;
  if (bm >= cnt_pad[e]) return;
  __shared__ u16 As[128*32];
  __shared__ u16 Bs[128*32];
  const int tid = threadIdx.x;
  const int lane = tid & 63;
  const int wave = tid >> 6;
  const int wr = wave >> 1, wc = wave & 1;
  const int fr = lane & 15, fg = lane >> 4;
  const int bn = blockIdx.x * 128;
  const int srow = tid >> 2, skb = (tid & 3) ^ (srow & 3);

  f32x4_t acc[4][4] = {};

  const u16* A  = Hb  + (size_t)e * T_TOK * MDIM;
  const u16* Bt = WdT + (size_t)e * HID * MDIM;
  const u16* ga0 = A + (size_t)(bm + srow) * MDIM + skb * 8;
  const u16* gb0 = Bt + (size_t)(bn + srow) * MDIM + skb * 8;
  for (int kk = 0; kk < MDIM; kk += 32){
    gload16(ga0 + kk, &As[tid*8]);
    gload16(ga0 + (size_t)64*MDIM + kk, &As[2048 + tid*8]);
    gload16(gb0 + kk, &Bs[tid*8]);
    gload16(gb0 + (size_t)64*MDIM + kk, &Bs[2048 + tid*8]);
    __syncthreads();
    bf16x8_t af[4], bfv[4];
    #pragma unroll
    for (int i = 0; i < 4; i++) af[i]  = ldfsw64(As, wr*64 + i*16 + fr, fg*8);
    #pragma unroll
    for (int i = 0; i < 4; i++) bfv[i] = ldfsw64(Bs, wc*64 + i*16 + fr, fg*8);
    #pragma unroll
    for (int mi = 0; mi < 4; mi++)
      #pragma unroll
      for (int ni = 0; ni < 4; ni++)
        acc[mi][ni] = mfma16(af[mi], bfv[ni], acc[mi][ni]);
    __syncthreads();
  }

  #pragma unroll
  for (int mi = 0; mi < 4; mi++)
    #pragma unroll
    for (int r = 0; r < 4; r++){
      int pos = bm + wr*64 + mi*16 + fg*4 + r;
      int tok = tok_list[e*T_TOK + pos];
      #pragma unroll
      for (int ni = 0; ni < 4; ni++){
        int col = bn + wc*64 + ni*16 + fr;
        atomicAdd(&Out[(size_t)tok * HID + col], acc[mi][ni][r]);
      }
    }
}

// ---------- launch ----------
// Workspace plan (peak ~185 MB; ws budget ~256 MB):
//   R0  96MB: Wq/Wk/Wv/Wo 3-way splits  -> (after O-proj) WgT/WuT/WdT
//   R1  24MB: xn1..3 -> vt1..3 -> ynb(8MB)+yn(16MB f32)
//   R2  24MB: q1..3  -> hb[0..24MB)
//   R3  24MB: k1..3  -> ao1..3 -> hb[24..32MB)
//   R4  16MB: vf(f32) -> aof(f32) -> x1(f32, lives to end)
//   RS: tok_list/w_list/cur/cnt_pad/rope tables

extern "C" void kernel_launch(void* const* d_in, const int* in_sizes, int n_in,
                              void* d_out, int out_size, void* d_ws, size_t ws_size,
                              hipStream_t stream)
{
  const float* hs     = (const float*)d_in[0];
  const float* w_attn = (const float*)d_in[1];
  const float* Wq = (const float*)d_in[2];
  const float* Wk = (const float*)d_in[3];
  const float* Wv = (const float*)d_in[4];
  const float* Wo = (const float*)d_in[5];
  const float* w_moe = (const float*)d_in[6];
  const float* Wr = (const float*)d_in[7];
  const float* Wg = (const float*)d_in[8];
  const float* Wu = (const float*)d_in[9];
  const float* Wd = (const float*)d_in[10];
  float* out = (float*)d_out;
  (void)in_sizes; (void)n_in; (void)out_size; (void)ws_size;

  char* ws = (char*)d_ws;
  const size_t MB = 1024*1024;
  char* R0 = ws;                 // 96 MB
  char* R1 = ws + 96*MB;         // 24 MB
  char* R2 = ws + 120*MB;        // 24 MB
  char* R3 = ws + 144*MB;        // 24 MB
  char* R4 = ws + 168*MB;        // 16 MB
  char* RS = ws + 184*MB;        // small buffers

  // phase A pointers (attention)
  const size_t WSLB = (size_t)HID*HID;   // elements per split slab (8 MB)
  u16* W0 = (u16*)R0;
  u16 *Wq1 = W0,          *Wq2 = W0 + WSLB,    *Wq3 = W0 + 2*WSLB;
  u16 *Wk1 = W0 + 3*WSLB, *Wk2 = W0 + 4*WSLB,  *Wk3 = W0 + 5*WSLB;
  u16 *Wv1 = W0 + 6*WSLB, *Wv2 = W0 + 7*WSLB,  *Wv3 = W0 + 8*WSLB;
  u16 *Wo1 = W0 + 9*WSLB, *Wo2 = W0 + 10*WSLB, *Wo3 = W0 + 11*WSLB;
  const size_t TSLB = (size_t)T_TOK*HID;  // elements per activation slab (8 MB)
  u16 *xn1 = (u16*)R1, *xn2 = (u16*)R1 + TSLB, *xn3 = (u16*)R1 + 2*TSLB;
  u16 *q1  = (u16*)R2, *q2  = (u16*)R2 + TSLB, *q3  = (u16*)R2 + 2*TSLB;
  u16 *k1  = (u16*)R3, *k2  = (u16*)R3 + TSLB, *k3  = (u16*)R3 + 2*TSLB;
  u16 *vt1 = xn1, *vt2 = xn2, *vt3 = xn3;        // reuse R1 after xn is dead
  float* vf  = (float*)R4;
  float* aof = (float*)R4;                        // reuse after vtrans
  u16 *ao1 = k1, *ao2 = k2, *ao3 = k3;            // reuse R3 after fattn
  float* x1  = (float*)R4;                        // reuse after split3 (O-proj out)
  // phase B pointers (MoE)
  u16* WgT = (u16*)R0;                            // 32 MB
  u16* WuT = (u16*)R0 + (size_t)NEXP*MDIM*HID;    // 32 MB
  u16* WdT = (u16*)R0 + 2*(size_t)NEXP*MDIM*HID;  // 32 MB
  u16* ynb = (u16*)R1;                            // 8 MB
  float* yn = (float*)(R1 + 8*MB);                // 16 MB
  u16* hb  = (u16*)R2;                            // 32 MB spans R2 + first 8MB of R3
  int*   tok_list = (int*)RS;                     // 64 KB
  float* w_list   = (float*)(RS + 64*1024);       // 64 KB
  int*   cur      = (int*)(RS + 128*1024);
  int*   cnt_pad  = (int*)(RS + 132*1024);
  float* ct   = (float*)(RS + 256*1024);
  float* stab = (float*)(RS + 384*1024);

  dim3 blk256(256), gMoE(16,16,8);

  rope_table_k<<<dim3(SEQ*32/256), blk256, 0, stream>>>(ct, stab);
  convT3<<<dim3(HID/64, HID/64), blk256, 0, stream>>>(Wq, Wq1, Wq2, Wq3, HID, HID);
  convT3<<<dim3(HID/64, HID/64), blk256, 0, stream>>>(Wk, Wk1, Wk2, Wk3, HID, HID);
  convT3<<<dim3(HID/64, HID/64), blk256, 0, stream>>>(Wv, Wv1, Wv2, Wv3, HID, HID);
  convT3<<<dim3(HID/64, HID/64), blk256, 0, stream>>>(Wo, Wo1, Wo2, Wo3, HID, HID);

  rmsnorm3_k<<<dim3(T_TOK), blk256, 0, stream>>>(hs, w_attn, xn1, xn2, xn3);

  // fused Q/K/V (rope+split for Q,K; f32 for V) — 768 blocks, 3/CU co-resident
  gemm_qkv<<<dim3(16,16,3), blk256, 0, stream>>>(xn1,xn2,xn3,
      Wq1,Wq2,Wq3, Wk1,Wk2,Wk3, Wv1,Wv2,Wv3,
      q1,q2,q3, k1,k2,k3, vf, ct, stab);

  vtrans3_k<<<dim3(SEQ/64, BATCH*NHEAD), blk256, 0, stream>>>(vf, vt1, vt2, vt3);   // xn dead

  fattn3_k<<<dim3(BATCH*NHEAD, SEQ/64), blk256, 0, stream>>>(q1,q2,q3, k1,k2,k3, vt1,vt2,vt3, aof);  // vf dead

  split3_k<<<dim3(T_TOK*HID/1024), blk256, 0, stream>>>(aof, ao1, ao2, ao3);        // k dead

  // O-projection, 128x64 tiles — 512 blocks, 2/CU co-resident
  gemm_o<<<dim3(32,16), blk256, 0, stream>>>(ao1,ao2,ao3, Wo1,Wo2,Wo3, x1, hs);     // aof dead

  // attention weights dead -> convert MoE weights into R0
  convT<<<dim3(MDIM/64, HID/64, NEXP), blk256, 0, stream>>>(Wg, WgT, HID, MDIM);
  convT<<<dim3(MDIM/64, HID/64, NEXP), blk256, 0, stream>>>(Wu, WuT, HID, MDIM);
  convT<<<dim3(HID/64, MDIM/64, NEXP), blk256, 0, stream>>>(Wd, WdT, MDIM, HID);

  // MoE norm also initializes Out with the residual x1
  rmsnorm_k<<<dim3(T_TOK), blk256, 0, stream>>>(x1, w_moe, ynb, yn, out);   // vt dead

  hipMemsetAsync(cur, 0, NEXP*sizeof(int), stream);
  router_scatter_k<<<dim3(T_TOK), dim3(64), 0, stream>>>(yn, Wr, tok_list, w_list, cur);
  pad_k<<<dim3(NEXP), dim3(128), 0, stream>>>(cur, tok_list, w_list, cnt_pad);

  gemm_gateup_sp<<<gMoE, blk256, 0, stream>>>(ynb, WgT, WuT, tok_list, w_list, cnt_pad, hb);  // q, ao dead
  gemm_down_sp<<<gMoE, blk256, 0, stream>>>(hb, WdT, tok_list, cnt_pad, out);
}

// Round 8
// 922.141 us; speedup vs baseline: 2.6749x; 1.1793x over previous
//
#include <hip/hip_runtime.h>
#include <hip/hip_bf16.h>
#include <cstdint>

typedef unsigned short u16;
typedef __bf16 bf16x4_t __attribute__((ext_vector_type(4)));
typedef __bf16 bf16x8_t __attribute__((ext_vector_type(8)));
typedef float f32x4_t __attribute__((ext_vector_type(4)));
typedef unsigned short us4_t __attribute__((ext_vector_type(4)));
typedef unsigned short us8_t __attribute__((ext_vector_type(8)));

#define BATCH 2
#define SEQ 1024
#define HID 2048
#define NHEAD 32
#define NEXP 8
#define MDIM 1024
#define T_TOK (BATCH*SEQ)   // 2048

// ---------- helpers ----------

__device__ __forceinline__ void gload16(const void* g, void* l){
  __builtin_amdgcn_global_load_lds((__attribute__((address_space(1))) void*)(uintptr_t)g,
                                   (__attribute__((address_space(3))) void*)l, 16, 0, 0);
}

// 8-bf16 MFMA fragment as two b64 halves (k = fg*4+e and +16)
__device__ __forceinline__ bf16x8_t ldfrag(const u16* lo){
  bf16x4_t a = *(const bf16x4_t*)lo;
  bf16x4_t b = *(const bf16x4_t*)(lo + 16);
  return __builtin_shufflevector(a, b, 0,1,2,3,4,5,6,7);
}

// Swizzled fragment read, 128B LDS rows (fattn K/V/P): byte ^= (row&7)<<4.
__device__ __forceinline__ bf16x8_t ldfsw128(const u16* base, int row, int colbyte){
  const char* p = (const char*)base + row*128;
  int sw = (row & 7) << 4;
  bf16x4_t a = *(const bf16x4_t*)(p + (colbyte ^ sw));
  bf16x4_t b = *(const bf16x4_t*)(p + ((colbyte + 32) ^ sw));
  return __builtin_shufflevector(a, b, 0,1,2,3,4,5,6,7);
}

// Swizzled fragment read, 64B LDS rows (MoE GEMM tiles, BK=32): byte ^= (row&3)<<4.
__device__ __forceinline__ bf16x8_t ldfsw64(const u16* base, int row, int colbyte){
  const char* p = (const char*)base + row*64;
  int sw = (row & 3) << 4;
  bf16x4_t a = *(const bf16x4_t*)(p + (colbyte ^ sw));
  bf16x4_t b = *(const bf16x4_t*)(p + ((colbyte + 32) ^ sw));
  return __builtin_shufflevector(a, b, 0,1,2,3,4,5,6,7);
}

__device__ __forceinline__ f32x4_t mfma16(bf16x8_t a, bf16x8_t b, f32x4_t c){
  return __builtin_amdgcn_mfma_f32_16x16x32_bf16(a, b, c, 0, 0, 0);
}

__device__ __forceinline__ u16 f2b(float f){
  __hip_bfloat16 h = __float2bfloat16(f);
  return __builtin_bit_cast(u16, h);
}
__device__ __forceinline__ float b2f(u16 b){
  return __builtin_bit_cast(float, (unsigned int)b << 16);
}
// 3-way bf16 split: v ~= b1 + b2 + b3 with |residual| <= 2^-27 |v|
__device__ __forceinline__ void split3v(float v, u16& b1, u16& b2, u16& b3){
  b1 = f2b(v); float f1 = b2f(b1);
  float r1 = v - f1;
  b2 = f2b(r1); float f2 = b2f(b2);
  b3 = f2b(r1 - f2);
}

// Fragment-linear slab addressing (u16 index) for a [2048 rows][2048 k] matrix:
//   rb=row>>7, sub=(row>>4)&7, fr=row&15, kb=k>>5, fg=((k&31)&15)>>2
//   frag u16 offset = (((rb*64 + kb)*8 + sub)*64 + fr*4 + fg) * 8
// 16B frag holds k = fg*4+{0..3} then fg*4+16+{0..3}  (same order as ldfrag).

// ---------- weight convert+transpose (single bf16, MoE): f32 [R][C] -> bf16 [C][R] ----------

__global__ __launch_bounds__(256)
void convT(const float* __restrict__ in, u16* __restrict__ out, int R, int C)
{
  __shared__ float t[64][65];
  int bz = blockIdx.z;
  const float* ip = in + (size_t)bz * R * C;
  u16* op = out + (size_t)bz * R * C;
  int r0 = blockIdx.y*64, c0 = blockIdx.x*64;
  int tid = threadIdx.x;
  int lr = tid >> 4;          // 0..15
  int lc = (tid & 15) * 4;    // 0..60
  #pragma unroll
  for (int i = 0; i < 4; i++){
    int r = lr + i*16;
    float4 v = *(const float4*)&ip[(size_t)(r0 + r) * C + c0 + lc];
    t[r][lc] = v.x; t[r][lc+1] = v.y; t[r][lc+2] = v.z; t[r][lc+3] = v.w;
  }
  __syncthreads();
  #pragma unroll
  for (int i = 0; i < 4; i++){
    int c = lr + i*16;
    us4_t o;
    o.x = f2b(t[lc+0][c]); o.y = f2b(t[lc+1][c]);
    o.z = f2b(t[lc+2][c]); o.w = f2b(t[lc+3][c]);
    *(us4_t*)&op[(size_t)(c0 + c) * R + r0 + lc] = o;
  }
}

// ---------- weight convert+transpose, 3-way split -> FRAGMENT-LINEAR slabs ----------
// Output B[n][k] = in[k][n]; written in frag-linear layout (R=C=2048).

__global__ __launch_bounds__(256)
void convT3(const float* __restrict__ in, u16* __restrict__ o1, u16* __restrict__ o2,
            u16* __restrict__ o3)
{
  __shared__ float t[64][65];
  int r0 = blockIdx.y*64, c0 = blockIdx.x*64;   // r = k dim, c = n dim
  int tid = threadIdx.x;
  int lr = tid >> 4;
  int lc = (tid & 15) * 4;
  #pragma unroll
  for (int i = 0; i < 4; i++){
    int r = lr + i*16;
    float4 v = *(const float4*)&in[(size_t)(r0 + r) * HID + c0 + lc];
    t[r][lc] = v.x; t[r][lc+1] = v.y; t[r][lc+2] = v.z; t[r][lc+3] = v.w;
  }
  __syncthreads();
  if (tid < 128){
    int n  = tid & 63;            // local n
    int kb2 = tid >> 6;           // 0..1 (two 32-k blocks in this 64-row tile)
    int gn = c0 + n;
    int nb = gn >> 7, sub = (gn >> 4) & 7, fr = gn & 15;
    int kb = (r0 >> 5) + kb2;
    size_t fo = (((size_t)(nb*64 + kb)*8 + sub)*64 + fr*4) * 8;   // u16 idx, fg=0
    #pragma unroll
    for (int fg = 0; fg < 4; fg++){
      us8_t w1, w2, w3;
      #pragma unroll
      for (int j = 0; j < 4; j++){
        u16 b1, b2, b3;
        split3v(t[kb2*32 + fg*4 + j][n], b1, b2, b3);
        w1[j] = b1; w2[j] = b2; w3[j] = b3;
        split3v(t[kb2*32 + fg*4 + 16 + j][n], b1, b2, b3);
        w1[j+4] = b1; w2[j+4] = b2; w3[j+4] = b3;
      }
      *(us8_t*)&o1[fo + fg*8] = w1;
      *(us8_t*)&o2[fo + fg*8] = w2;
      *(us8_t*)&o3[fo + fg*8] = w3;
    }
  }
}

// ---------- RMSNorm -> 3-way split, FRAGMENT-LINEAR (attention input) ----------

__global__ __launch_bounds__(256)
void rmsnorm3_k(const float* __restrict__ x, const float* __restrict__ w,
                u16* __restrict__ o1, u16* __restrict__ o2, u16* __restrict__ o3)
{
  int row = blockIdx.x;
  const float* xr = x + (size_t)row * HID;
  int tid = threadIdx.x;
  int kb = tid >> 2, fg = tid & 3;
  int kbase = kb*32 + fg*4;
  float4 a = *(const float4*)(xr + kbase);
  float4 b = *(const float4*)(xr + kbase + 16);
  float ss = a.x*a.x + a.y*a.y + a.z*a.z + a.w*a.w
           + b.x*b.x + b.y*b.y + b.z*b.z + b.w*b.w;
  #pragma unroll
  for (int off = 32; off; off >>= 1) ss += __shfl_down(ss, off);
  __shared__ float red[4];
  if ((tid & 63) == 0) red[tid >> 6] = ss;
  __syncthreads();
  float tot = red[0] + red[1] + red[2] + red[3];
  float rs = (float)(1.0 / sqrt((double)tot * (1.0/2048.0) + 1e-5));
  float4 wa = *(const float4*)(w + kbase);
  float4 wb = *(const float4*)(w + kbase + 16);
  float o[8];
  o[0]=a.x*rs*wa.x; o[1]=a.y*rs*wa.y; o[2]=a.z*rs*wa.z; o[3]=a.w*rs*wa.w;
  o[4]=b.x*rs*wb.x; o[5]=b.y*rs*wb.y; o[6]=b.z*rs*wb.z; o[7]=b.w*rs*wb.w;
  us8_t w1, w2, w3;
  #pragma unroll
  for (int j = 0; j < 8; j++){
    u16 b1, b2, b3; split3v(o[j], b1, b2, b3);
    w1[j] = b1; w2[j] = b2; w3[j] = b3;
  }
  int rb = row >> 7, sub = (row >> 4) & 7, fr = row & 15;
  size_t fo = (((size_t)(rb*64 + kb)*8 + sub)*64 + fr*4 + fg) * 8;
  *(us8_t*)&o1[fo] = w1; *(us8_t*)&o2[fo] = w2; *(us8_t*)&o3[fo] = w3;
}

// ---------- RMSNorm (MoE): bf16 out + f32 out + residual passthrough to Out ----------

__global__ __launch_bounds__(256)
void rmsnorm_k(const float* __restrict__ x, const float* __restrict__ w,
               u16* __restrict__ ob, float* __restrict__ of, float* __restrict__ oi)
{
  int row = blockIdx.x;
  const float* xr = x + (size_t)row * HID;
  int base = threadIdx.x * 8;
  float4 a = *(const float4*)(xr + base);
  float4 b = *(const float4*)(xr + base + 4);
  float ss = a.x*a.x + a.y*a.y + a.z*a.z + a.w*a.w
           + b.x*b.x + b.y*b.y + b.z*b.z + b.w*b.w;
  #pragma unroll
  for (int off = 32; off; off >>= 1) ss += __shfl_down(ss, off);
  __shared__ float red[4];
  if ((threadIdx.x & 63) == 0) red[threadIdx.x >> 6] = ss;
  __syncthreads();
  float tot = red[0] + red[1] + red[2] + red[3];
  float rs = (float)(1.0 / sqrt((double)tot * (1.0/2048.0) + 1e-5));
  float4 wa = *(const float4*)(w + base);
  float4 wb = *(const float4*)(w + base + 4);
  float o[8];
  o[0]=a.x*rs*wa.x; o[1]=a.y*rs*wa.y; o[2]=a.z*rs*wa.z; o[3]=a.w*rs*wa.w;
  o[4]=b.x*rs*wb.x; o[5]=b.y*rs*wb.y; o[6]=b.z*rs*wb.z; o[7]=b.w*rs*wb.w;
  us4_t p0, p1;
  p0.x=f2b(o[0]); p0.y=f2b(o[1]); p0.z=f2b(o[2]); p0.w=f2b(o[3]);
  p1.x=f2b(o[4]); p1.y=f2b(o[5]); p1.z=f2b(o[6]); p1.w=f2b(o[7]);
  *(us4_t*)&ob[(size_t)row*HID + base] = p0;
  *(us4_t*)&ob[(size_t)row*HID + base + 4] = p1;
  float* orow = of + (size_t)row*HID + base;
  *(float4*)orow = make_float4(o[0],o[1],o[2],o[3]);
  *(float4*)(orow+4) = make_float4(o[4],o[5],o[6],o[7]);
  float* irow = oi + (size_t)row*HID + base;
  *(float4*)irow = a;
  *(float4*)(irow+4) = b;
}

// ---------- RoPE table (f64 math -> f32) ----------

__global__ void rope_table_k(float* ct, float* st){
  int i = blockIdx.x*256 + threadIdx.x;   // SEQ*32
  int s = i >> 5, j = i & 31;
  double invf = exp(-(double)j / 32.0 * log(10000.0));
  double ang = (double)s * invf;
  ct[i] = (float)cos(ang);
  st[i] = (float)sin(ang);
}

// ---------- fused Q/K/V split GEMM (frag-linear inputs, conflict-free b128 reads) ----------
// z=0 -> Q(rope+split), z=1 -> K(rope+split), z=2 -> V(f32). 768 blocks, 3/CU.

__global__ __launch_bounds__(256, 2)
void gemm_qkv(const u16* __restrict__ A1, const u16* __restrict__ A2, const u16* __restrict__ A3,
              const u16* __restrict__ Wq1, const u16* __restrict__ Wq2, const u16* __restrict__ Wq3,
              const u16* __restrict__ Wk1, const u16* __restrict__ Wk2, const u16* __restrict__ Wk3,
              const u16* __restrict__ Wv1, const u16* __restrict__ Wv2, const u16* __restrict__ Wv3,
              u16* __restrict__ oq1, u16* __restrict__ oq2, u16* __restrict__ oq3,
              u16* __restrict__ ok1, u16* __restrict__ ok2, u16* __restrict__ ok3,
              float* __restrict__ vf,
              const float* __restrict__ ct, const float* __restrict__ st)
{
  __shared__ u16 As[3][128*32];
  __shared__ u16 Bs[3][128*32];
  const int flat = blockIdx.x + 16*blockIdx.y + 256*blockIdx.z;
  const int logical = (flat & 7) * 96 + (flat >> 3);   // XCD-contiguous chunks
  const int z  = logical >> 8;
  const int bm = ((logical >> 4) & 15) * 128;
  const int bn = (logical & 15) * 128;
  const int tid = threadIdx.x;
  const int lane = tid & 63;
  const int wave = tid >> 6;
  const int wr = wave >> 1, wc = wave & 1;
  const int fr = lane & 15, fg = lane >> 4;

  f32x4_t acc[4][4] = {};

  const u16* Ap[3] = {A1, A2, A3};
  const u16* Bp[3];
  if (z == 0)      { Bp[0] = Wq1; Bp[1] = Wq2; Bp[2] = Wq3; }
  else if (z == 1) { Bp[0] = Wk1; Bp[1] = Wk2; Bp[2] = Wk3; }
  else             { Bp[0] = Wv1; Bp[1] = Wv2; Bp[2] = Wv3; }
  const u16* gA[3]; const u16* gB[3];
  #pragma unroll
  for (int t = 0; t < 3; t++){
    gA[t] = Ap[t] + (size_t)(bm >> 7) * 64 * 4096 + tid*8;
    gB[t] = Bp[t] + (size_t)(bn >> 7) * 64 * 4096 + tid*8;
  }

  for (int kb = 0; kb < 64; kb++){
    const size_t o = (size_t)kb * 4096;
    #pragma unroll
    for (int t = 0; t < 3; t++){
      gload16(gA[t] + o,        &As[t][tid*8]);
      gload16(gA[t] + o + 2048, &As[t][2048 + tid*8]);
      gload16(gB[t] + o,        &Bs[t][tid*8]);
      gload16(gB[t] + o + 2048, &Bs[t][2048 + tid*8]);
    }
    __syncthreads();
    bf16x8_t bfv[3][4];
    #pragma unroll
    for (int t = 0; t < 3; t++)
      #pragma unroll
      for (int ni = 0; ni < 4; ni++)
        bfv[t][ni] = *(const bf16x8_t*)&Bs[t][(((wc*4 + ni)*64) + fr*4 + fg)*8];
    #pragma unroll
    for (int mi = 0; mi < 4; mi++){
      const int ao = (((wr*4 + mi)*64) + fr*4 + fg)*8;
      bf16x8_t a1 = *(const bf16x8_t*)&As[0][ao];
      bf16x8_t a2 = *(const bf16x8_t*)&As[1][ao];
      bf16x8_t a3 = *(const bf16x8_t*)&As[2][ao];
      #pragma unroll
      for (int ni = 0; ni < 4; ni++){
        f32x4_t c = acc[mi][ni];
        c = mfma16(a3, bfv[0][ni], c);   // a3b1
        c = mfma16(a2, bfv[1][ni], c);   // a2b2
        c = mfma16(a1, bfv[2][ni], c);   // a1b3
        c = mfma16(a2, bfv[0][ni], c);   // a2b1
        c = mfma16(a1, bfv[1][ni], c);   // a1b2
        c = mfma16(a1, bfv[0][ni], c);   // a1b1
        acc[mi][ni] = c;
      }
    }
    __syncthreads();
  }

  if (z < 2){
    u16* O1 = z ? ok1 : oq1;
    u16* O2 = z ? ok2 : oq2;
    u16* O3 = z ? ok3 : oq3;
    #pragma unroll
    for (int mi = 0; mi < 4; mi++)
      #pragma unroll
      for (int r = 0; r < 4; r++){
        int row = bm + wr*64 + mi*16 + fg*4 + r;
        int s = row & (SEQ-1);
        #pragma unroll
        for (int ni = 0; ni < 2; ni++){
          int dlo = ni*16 + fr;   // 0..31 within head
          float c  = ct[s*32 + dlo];
          float sn = st[s*32 + dlo];
          float xl = acc[mi][ni][r], xh = acc[mi][ni+2][r];
          float ol = xl*c - xh*sn;
          float oh = xh*c + xl*sn;
          size_t idx = (size_t)row * HID + bn + wc*64 + ni*16 + fr;
          u16 b1, b2, b3;
          split3v(ol, b1, b2, b3); O1[idx] = b1;    O2[idx] = b2;    O3[idx] = b3;
          split3v(oh, b1, b2, b3); O1[idx+32] = b1; O2[idx+32] = b2; O3[idx+32] = b3;
        }
      }
  } else {
    #pragma unroll
    for (int mi = 0; mi < 4; mi++)
      #pragma unroll
      for (int ni = 0; ni < 4; ni++)
        #pragma unroll
        for (int r = 0; r < 4; r++){
          int row = bm + wr*64 + mi*16 + fg*4 + r;
          int col = bn + wc*64 + ni*16 + fr;
          vf[(size_t)row * HID + col] = acc[mi][ni][r];
        }
  }
}

// ---------- O-projection split GEMM, 128x64 tiles (frag-linear), +residual ----------

__global__ __launch_bounds__(256, 2)
void gemm_o(const u16* __restrict__ A1, const u16* __restrict__ A2, const u16* __restrict__ A3,
            const u16* __restrict__ B1, const u16* __restrict__ B2, const u16* __restrict__ B3,
            float* __restrict__ Cf, const float* __restrict__ Res)
{
  __shared__ u16 As[3][128*32];   // 24KB
  __shared__ u16 Bs[3][64*32];    // 12KB
  const int flat = blockIdx.x + 32*blockIdx.y;
  const int logical = (flat & 7) * 64 + (flat >> 3);   // 512 = 8*64
  const int bn = (logical & 31) * 64;
  const int bm = (logical >> 5) * 128;
  const int tid = threadIdx.x;
  const int lane = tid & 63;
  const int wave = tid >> 6;
  const int wr = wave >> 1, wc = wave & 1;
  const int fr = lane & 15, fg = lane >> 4;

  f32x4_t acc[4][2] = {};

  const u16* Ap[3] = {A1, A2, A3};
  const u16* Bp[3] = {B1, B2, B3};
  const u16* gA[3]; const u16* gB[3];
  const int sb0 = (bn >> 4) & 7;   // 0 or 4
  #pragma unroll
  for (int t = 0; t < 3; t++){
    gA[t] = Ap[t] + (size_t)(bm >> 7) * 64 * 4096 + tid*8;
    gB[t] = Bp[t] + (size_t)(bn >> 7) * 64 * 4096 + sb0*512 + tid*8;
  }

  for (int kb = 0; kb < 64; kb++){
    const size_t o = (size_t)kb * 4096;
    #pragma unroll
    for (int t = 0; t < 3; t++){
      gload16(gA[t] + o,        &As[t][tid*8]);
      gload16(gA[t] + o + 2048, &As[t][2048 + tid*8]);
      gload16(gB[t] + o,        &Bs[t][tid*8]);
    }
    __syncthreads();
    bf16x8_t bfv[3][2];
    #pragma unroll
    for (int t = 0; t < 3; t++)
      #pragma unroll
      for (int nj = 0; nj < 2; nj++)
        bfv[t][nj] = *(const bf16x8_t*)&Bs[t][(((wc*2 + nj)*64) + fr*4 + fg)*8];
    #pragma unroll
    for (int mi = 0; mi < 4; mi++){
      const int ao = (((wr*4 + mi)*64) + fr*4 + fg)*8;
      bf16x8_t a1 = *(const bf16x8_t*)&As[0][ao];
      bf16x8_t a2 = *(const bf16x8_t*)&As[1][ao];
      bf16x8_t a3 = *(const bf16x8_t*)&As[2][ao];
      #pragma unroll
      for (int nj = 0; nj < 2; nj++){
        f32x4_t c = acc[mi][nj];
        c = mfma16(a3, bfv[0][nj], c);
        c = mfma16(a2, bfv[1][nj], c);
        c = mfma16(a1, bfv[2][nj], c);
        c = mfma16(a2, bfv[0][nj], c);
        c = mfma16(a1, bfv[1][nj], c);
        c = mfma16(a1, bfv[0][nj], c);
        acc[mi][nj] = c;
      }
    }
    __syncthreads();
  }

  #pragma unroll
  for (int mi = 0; mi < 4; mi++)
    #pragma unroll
    for (int nj = 0; nj < 2; nj++)
      #pragma unroll
      for (int r = 0; r < 4; r++){
        int row = bm + wr*64 + mi*16 + fg*4 + r;
        int col = bn + wc*32 + nj*16 + fr;
        size_t idx = (size_t)row * HID + col;
        Cf[idx] = acc[mi][nj][r] + Res[idx];
      }
}

// ---------- 3-way split (attention output) -> FRAGMENT-LINEAR ----------

__global__ __launch_bounds__(256)
void split3_k(const float* __restrict__ in, u16* __restrict__ o1, u16* __restrict__ o2,
              u16* __restrict__ o3)
{
  int row = blockIdx.x;
  int tid = threadIdx.x;
  int kb = tid >> 2, fg = tid & 3;
  int kbase = kb*32 + fg*4;
  const float* xr = in + (size_t)row * HID;
  float4 a = *(const float4*)(xr + kbase);
  float4 b = *(const float4*)(xr + kbase + 16);
  float o[8] = {a.x, a.y, a.z, a.w, b.x, b.y, b.z, b.w};
  us8_t w1, w2, w3;
  #pragma unroll
  for (int j = 0; j < 8; j++){
    u16 b1, b2, b3; split3v(o[j], b1, b2, b3);
    w1[j] = b1; w2[j] = b2; w3[j] = b3;
  }
  int rb = row >> 7, sub = (row >> 4) & 7, fr = row & 15;
  size_t fo = (((size_t)(rb*64 + kb)*8 + sub)*64 + fr*4 + fg) * 8;
  *(us8_t*)&o1[fo] = w1; *(us8_t*)&o2[fo] = w2; *(us8_t*)&o3[fo] = w3;
}

// ---------- V transpose + split: f32 [T][H] -> per (b,h) bf16x3 [64 d][1024 s] ----------

__global__ __launch_bounds__(256)
void vtrans3_k(const float* __restrict__ vf, u16* __restrict__ t1, u16* __restrict__ t2,
               u16* __restrict__ t3)
{
  __shared__ float t[64][65];
  int st0 = blockIdx.x * 64;
  int bh = blockIdx.y;
  int b = bh >> 5, h = bh & 31;
  int tid = threadIdx.x;
  #pragma unroll
  for (int i = 0; i < 4; i++){
    int idx = tid + i*256;                // 1024 float4 chunks
    int s = idx >> 4, dc = (idx & 15) * 4;
    float4 v = *(const float4*)&vf[(size_t)(b*SEQ + st0 + s) * HID + h*64 + dc];
    t[dc+0][s] = v.x; t[dc+1][s] = v.y; t[dc+2][s] = v.z; t[dc+3][s] = v.w;
  }
  __syncthreads();
  #pragma unroll
  for (int i = 0; i < 4; i++){
    int idx = tid + i*256;
    int d = idx >> 4, sc = (idx & 15) * 4;
    us4_t v1, v2, v3;
    #pragma unroll
    for (int j = 0; j < 4; j++){
      u16 b1, b2, b3; split3v(t[d][sc+j], b1, b2, b3);
      v1[j]=b1; v2[j]=b2; v3[j]=b3;
    }
    size_t base = ((size_t)bh*64 + d)*SEQ + st0 + sc;
    *(us4_t*)&t1[base] = v1; *(us4_t*)&t2[base] = v2; *(us4_t*)&t3[base] = v3;
  }
}

// ---------- flash attention, split-precision (causal), f32 out ----------

__global__ __launch_bounds__(256)
void fattn3_k(const u16* __restrict__ q1, const u16* __restrict__ q2, const u16* __restrict__ q3,
              const u16* __restrict__ k1, const u16* __restrict__ k2, const u16* __restrict__ k3,
              const u16* __restrict__ v1, const u16* __restrict__ v2, const u16* __restrict__ v3,
              float* __restrict__ aof)
{
  __shared__ u16 Ks[3][64*64];     // 24KB
  __shared__ u16 Vs[3][64*64];     // 24KB
  __shared__ u16 Ps[2][4][16*64];  // 16KB  -> 64KB total
  const int bh = blockIdx.x, qt = blockIdx.y;
  const int b = bh >> 5, h = bh & 31;
  const int tid = threadIdx.x, lane = tid & 63, wave = tid >> 6;
  const int fr = lane & 15, fg = lane >> 4;

  const size_t qrow = (size_t)(b*SEQ + qt*64 + wave*16 + fr);
  const u16* qp[3] = { q1 + qrow*HID + h*64, q2 + qrow*HID + h*64, q3 + qrow*HID + h*64 };
  bf16x8_t aq[3][2];
  #pragma unroll
  for (int t = 0; t < 3; t++)
    #pragma unroll
    for (int ks = 0; ks < 2; ks++) aq[t][ks] = ldfrag(qp[t] + ks*32 + fg*4);

  f32x4_t oacc[4] = {};
  float m_r[4], l_r[4];
  #pragma unroll
  for (int r = 0; r < 4; r++){ m_r[r] = -1e30f; l_r[r] = 0.f; }

  const int sr = tid >> 3, sp = (tid & 7) ^ (sr & 7);   // swizzled source chunk
  const u16* kb[3] = { k1 + ((size_t)(b*SEQ) + sr)*HID + h*64 + sp*8,
                       k2 + ((size_t)(b*SEQ) + sr)*HID + h*64 + sp*8,
                       k3 + ((size_t)(b*SEQ) + sr)*HID + h*64 + sp*8 };
  const u16* vb[3] = { v1 + ((size_t)bh*64 + sr)*SEQ + sp*8,
                       v2 + ((size_t)bh*64 + sr)*SEQ + sp*8,
                       v3 + ((size_t)bh*64 + sr)*SEQ + sp*8 };

  for (int kt = 0; kt <= qt; kt++){
    #pragma unroll
    for (int t = 0; t < 3; t++){
      gload16(kb[t] + (size_t)(kt*64) * HID,    &Ks[t][tid*8]);
      gload16(kb[t] + (size_t)(kt*64+32) * HID, &Ks[t][2048 + tid*8]);
      gload16(vb[t] + kt*64,                    &Vs[t][tid*8]);
      gload16(vb[t] + (size_t)32*SEQ + kt*64,   &Vs[t][2048 + tid*8]);
    }
    __syncthreads();

    f32x4_t sc[4] = {};
    #pragma unroll
    for (int nf = 0; nf < 4; nf++)
      #pragma unroll
      for (int ks = 0; ks < 2; ks++){
        int krow = nf*16 + fr, kcb = ks*64 + fg*8;
        bf16x8_t bk0 = ldfsw128(Ks[0], krow, kcb);
        bf16x8_t bk1 = ldfsw128(Ks[1], krow, kcb);
        bf16x8_t bk2 = ldfsw128(Ks[2], krow, kcb);
        sc[nf] = mfma16(aq[2][ks], bk0, sc[nf]);
        sc[nf] = mfma16(aq[1][ks], bk1, sc[nf]);
        sc[nf] = mfma16(aq[0][ks], bk2, sc[nf]);
        sc[nf] = mfma16(aq[1][ks], bk0, sc[nf]);
        sc[nf] = mfma16(aq[0][ks], bk1, sc[nf]);
        sc[nf] = mfma16(aq[0][ks], bk0, sc[nf]);
      }

    float nm[4] = {-1e30f,-1e30f,-1e30f,-1e30f};
    #pragma unroll
    for (int nf = 0; nf < 4; nf++)
      #pragma unroll
      for (int r = 0; r < 4; r++){
        float v = sc[nf][r] * 0.125f;
        if (kt == qt && nf*16 + fr > wave*16 + fg*4 + r) v = -1e30f;
        sc[nf][r] = v;
        nm[r] = fmaxf(nm[r], v);
      }
    #pragma unroll
    for (int r = 0; r < 4; r++)
      #pragma unroll
      for (int msk = 8; msk; msk >>= 1) nm[r] = fmaxf(nm[r], __shfl_xor(nm[r], msk));

    #pragma unroll
    for (int r = 0; r < 4; r++){
      float mn = fmaxf(m_r[r], nm[r]);
      float f = __expf(m_r[r] - mn);
      m_r[r] = mn;
      float rsum = 0.f;
      #pragma unroll
      for (int nf = 0; nf < 4; nf++){
        float pv = __expf(sc[nf][r] - mn);
        sc[nf][r] = pv;
        rsum += pv;
      }
      #pragma unroll
      for (int msk = 8; msk; msk >>= 1) rsum += __shfl_xor(rsum, msk);
      l_r[r] = l_r[r]*f + rsum;
      #pragma unroll
      for (int df = 0; df < 4; df++) oacc[df][r] *= f;
    }

    // P 2-way split to LDS (swizzled writes matching ldfsw128 reads)
    #pragma unroll
    for (int nf = 0; nf < 4; nf++)
      #pragma unroll
      for (int r = 0; r < 4; r++){
        float pv = sc[nf][r];
        u16 b1 = f2b(pv);
        float f1 = b2f(b1);
        u16 b2 = f2b(pv - f1);
        int prow = fg*4 + r;
        int pbyte = (nf*32 + fr*2) ^ ((prow & 7) << 4);
        *(u16*)((char*)&Ps[0][wave][0] + prow*128 + pbyte) = b1;
        *(u16*)((char*)&Ps[1][wave][0] + prow*128 + pbyte) = b2;
      }

    #pragma unroll
    for (int ks = 0; ks < 2; ks++){
      bf16x8_t pa0 = ldfsw128(&Ps[0][wave][0], fr, ks*64 + fg*8);
      bf16x8_t pa1 = ldfsw128(&Ps[1][wave][0], fr, ks*64 + fg*8);
      #pragma unroll
      for (int df = 0; df < 4; df++){
        int vrow = df*16 + fr, vcb = ks*64 + fg*8;
        bf16x8_t bv0 = ldfsw128(Vs[0], vrow, vcb);
        bf16x8_t bv1 = ldfsw128(Vs[1], vrow, vcb);
        bf16x8_t bv2 = ldfsw128(Vs[2], vrow, vcb);
        oacc[df] = mfma16(pa0, bv2, oacc[df]);   // p1 v3
        oacc[df] = mfma16(pa1, bv1, oacc[df]);   // p2 v2
        oacc[df] = mfma16(pa1, bv0, oacc[df]);   // p2 v1
        oacc[df] = mfma16(pa0, bv1, oacc[df]);   // p1 v2
        oacc[df] = mfma16(pa0, bv0, oacc[df]);   // p1 v1
      }
    }
    __syncthreads();
  }

  #pragma unroll
  for (int r = 0; r < 4; r++){
    float inv = 1.f / l_r[r];
    int orow = b*SEQ + qt*64 + wave*16 + fg*4 + r;
    #pragma unroll
    for (int df = 0; df < 4; df++)
      aof[(size_t)orow * HID + h*64 + df*16 + fr] = oacc[df][r] * inv;
  }
}

// ---------- router + scatter: f64 logits, top-2, compact per-expert lists ----------

__global__ __launch_bounds__(64)
void router_scatter_k(const float* __restrict__ yn, const float* __restrict__ Wr,
                      int* __restrict__ tok_list, float* __restrict__ w_list,
                      int* __restrict__ cur){
  int row = blockIdx.x;
  int lane = threadIdx.x;
  const float* xr = yn + (size_t)row * HID;
  double acc[8] = {};
  for (int j = lane; j < HID; j += 64){
    double xv = (double)xr[j];
    const float* wr = Wr + (size_t)j*8;
    float4 w0 = *(const float4*)wr;
    float4 w1 = *(const float4*)(wr + 4);
    acc[0] += xv*w0.x; acc[1] += xv*w0.y; acc[2] += xv*w0.z; acc[3] += xv*w0.w;
    acc[4] += xv*w1.x; acc[5] += xv*w1.y; acc[6] += xv*w1.z; acc[7] += xv*w1.w;
  }
  #pragma unroll
  for (int e = 0; e < 8; e++)
    #pragma unroll
    for (int off = 32; off; off >>= 1) acc[e] += __shfl_down(acc[e], off);
  if (lane == 0){
    double mx = acc[0];
    #pragma unroll
    for (int e = 1; e < 8; e++) mx = fmax(mx, acc[e]);
    double p[8];
    #pragma unroll
    for (int e = 0; e < 8; e++) p[e] = exp(acc[e] - mx);
    int i1 = 0;
    #pragma unroll
    for (int e = 1; e < 8; e++) if (p[e] > p[i1]) i1 = e;
    int i2 = (i1 == 0) ? 1 : 0;
    #pragma unroll
    for (int e = 0; e < 8; e++) if (e != i1 && p[e] > p[i2]) i2 = e;
    double s2 = p[i1] + p[i2];
    int pos1 = atomicAdd(&cur[i1], 1);
    tok_list[i1*T_TOK + pos1] = row;
    w_list[i1*T_TOK + pos1] = (float)(p[i1] / s2);
    int pos2 = atomicAdd(&cur[i2], 1);
    tok_list[i2*T_TOK + pos2] = row;
    w_list[i2*T_TOK + pos2] = (float)(p[i2] / s2);
  }
}

// pad each expert's list to a multiple of 128 with (token 0, weight 0)
__global__ __launch_bounds__(128)
void pad_k(const int* __restrict__ cur, int* __restrict__ tok_list,
           float* __restrict__ w_list, int* __restrict__ cnt_pad){
  int e = blockIdx.x;
  int c = cur[e];
  int cp = (c + 127) & ~127;
  for (int i = c + threadIdx.x; i < cp; i += 128){
    tok_list[e*T_TOK + i] = 0;
    w_list[e*T_TOK + i] = 0.f;
  }
  if (threadIdx.x == 0) cnt_pad[e] = cp;
}

// ---------- sparse fused gate+up GEMM: h = silu(g)*u*w over compact token lists ----------

__global__ __launch_bounds__(256, 2)
void gemm_gateup_sp(const u16* __restrict__ A, const u16* __restrict__ WgT, const u16* __restrict__ WuT,
                    const int* __restrict__ tok_list, const float* __restrict__ w_list,
                    const int* __restrict__ cnt_pad, u16* __restrict__ Hb)
{
  const int e = blockIdx.z;
  const int bm = blockIdx.y * 128;   // position within expert list
  if (bm >= cnt_pad[e]) return;
  __shared__ u16 As[128*32];
  __shared__ u16 Bg[64*32];
  __shared__ u16 Bu[64*32];
  const int tid = threadIdx.x;
  const int lane = tid & 63;
  const int wave = tid >> 6;
  const int wr = wave >> 1, wc = wave & 1;
  const int fr = lane & 15, fg = lane >> 4;
  const int bn = blockIdx.x * 64;    // M cols

  f32x4_t ag[4][2] = {}, au[4][2] = {};

  const int srow = tid >> 2, skb = (tid & 3) ^ (srow & 3);   // swizzled source chunk
  const int tok0 = tok_list[e*T_TOK + bm + srow];
  const int tok1 = tok_list[e*T_TOK + bm + srow + 64];
  const u16* ga0 = A + (size_t)tok0 * HID + skb * 8;
  const u16* ga1 = A + (size_t)tok1 * HID + skb * 8;
  const u16* gg0 = WgT + ((size_t)e*MDIM + bn + srow) * HID + skb * 8;
  const u16* gu0 = WuT + ((size_t)e*MDIM + bn + srow) * HID + skb * 8;

  for (int kk = 0; kk < HID; kk += 32){
    gload16(ga0 + kk, &As[tid*8]);
    gload16(ga1 + kk, &As[2048 + tid*8]);
    gload16(gg0 + kk, &Bg[tid*8]);
    gload16(gu0 + kk, &Bu[tid*8]);
    __syncthreads();
    bf16x8_t af[4], bg[2], bu[2];
    #pragma unroll
    for (int i = 0; i < 4; i++) af[i] = ldfsw64(As, wr*64 + i*16 + fr, fg*8);
    #pragma unroll
    for (int j = 0; j < 2; j++){
      bg[j] = ldfsw64(Bg, wc*32 + j*16 + fr, fg*8);
      bu[j] = ldfsw64(Bu, wc*32 + j*16 + fr, fg*8);
    }
    #pragma unroll
    for (int mi = 0; mi < 4; mi++)
      #pragma unroll
      for (int nj = 0; nj < 2; nj++){
        ag[mi][nj] = mfma16(af[mi], bg[nj], ag[mi][nj]);
        au[mi][nj] = mfma16(af[mi], bu[nj], au[mi][nj]);
      }
    __syncthreads();
  }

  #pragma unroll
  for (int mi = 0; mi < 4; mi++)
    #pragma unroll
    for (int nj = 0; nj < 2; nj++)
      #pragma unroll
      for (int r = 0; r < 4; r++){
        int pos = bm + wr*64 + mi*16 + fg*4 + r;
        int col = bn + wc*32 + nj*16 + fr;
        float g = ag[mi][nj][r], u = au[mi][nj][r];
        float h = g / (1.0f + __expf(-g)) * u * w_list[e*T_TOK + pos];
        Hb[((size_t)e*T_TOK + pos)*MDIM + col] = f2b(h);
      }
}

// ---------- sparse down GEMM: atomic-accumulate expert outputs onto Out ----------

__global__ __launch_bounds__(256, 2)
void gemm_down_sp(const u16* __restrict__ Hb, const u16* __restrict__ WdT,
                  const int* __restrict__ tok_list, const int* __restrict__ cnt_pad,
                  float* __restrict__ Out)
{
  const int e = blockIdx.z;
  const int bm = blockIdx.y * 128;
  if (bm >= cnt_pad[e]) return;
  __shared__ u16 As[128*32];
  __shared__ u16 Bs[128*32];
  const int tid = threadIdx.x;
  const int lane = tid & 63;
  const int wave = tid >> 6;
  const int wr = wave >> 1, wc = wave & 1;
  const int fr = lane & 15, fg = lane >> 4;
  const int bn = blockIdx.x * 128;
  const int srow = tid >> 2, skb = (tid & 3) ^ (srow & 3);

  f32x4_t acc[4][4] = {};

  const u16* A  = Hb  + (size_t)e * T_TOK * MDIM;
  const u16* Bt = WdT + (size_t)e * HID * MDIM;
  const u16* ga0 = A + (size_t)(bm + srow) * MDIM + skb * 8;
  const u16* gb0 = Bt + (size_t)(bn + srow) * MDIM + skb * 8;
  for (int kk = 0; kk < MDIM; kk += 32){
    gload16(ga0 + kk, &As[tid*8]);
    gload16(ga0 + (size_t)64*MDIM + kk, &As[2048 + tid*8]);
    gload16(gb0 + kk, &Bs[tid*8]);
    gload16(gb0 + (size_t)64*MDIM + kk, &Bs[2048 + tid*8]);
    __syncthreads();
    bf16x8_t af[4], bfv[4];
    #pragma unroll
    for (int i = 0; i < 4; i++) af[i]  = ldfsw64(As, wr*64 + i*16 + fr, fg*8);
    #pragma unroll
    for (int i = 0; i < 4; i++) bfv[i] = ldfsw64(Bs, wc*64 + i*16 + fr, fg*8);
    #pragma unroll
    for (int mi = 0; mi < 4; mi++)
      #pragma unroll
      for (int ni = 0; ni < 4; ni++)
        acc[mi][ni] = mfma16(af[mi], bfv[ni], acc[mi][ni]);
    __syncthreads();
  }

  #pragma unroll
  for (int mi = 0; mi < 4; mi++)
    #pragma unroll
    for (int r = 0; r < 4; r++){
      int pos = bm + wr*64 + mi*16 + fg*4 + r;
      int tok = tok_list[e*T_TOK + pos];
      #pragma unroll
      for (int ni = 0; ni < 4; ni++){
        int col = bn + wc*64 + ni*16 + fr;
        atomicAdd(&Out[(size_t)tok * HID + col], acc[mi][ni][r]);
      }
    }
}

// ---------- launch ----------
// Workspace plan (peak ~185 MB):
//   R0  96MB: Wq/Wk/Wv/Wo 3-way frag-linear splits -> (after O-proj) WgT/WuT/WdT
//   R1  24MB: xn1..3 (frag-linear) -> vt1..3 -> ynb(8MB)+yn(16MB f32)
//   R2  24MB: q1..3  -> hb[0..24MB)
//   R3  24MB: k1..3  -> ao1..3 (frag-linear) -> hb[24..32MB)
//   R4  16MB: vf(f32) -> aof(f32) -> x1(f32, lives to end)
//   RS: tok_list/w_list/cur/cnt_pad/rope tables

extern "C" void kernel_launch(void* const* d_in, const int* in_sizes, int n_in,
                              void* d_out, int out_size, void* d_ws, size_t ws_size,
                              hipStream_t stream)
{
  const float* hs     = (const float*)d_in[0];
  const float* w_attn = (const float*)d_in[1];
  const float* Wq = (const float*)d_in[2];
  const float* Wk = (const float*)d_in[3];
  const float* Wv = (const float*)d_in[4];
  const float* Wo = (const float*)d_in[5];
  const float* w_moe = (const float*)d_in[6];
  const float* Wr = (const float*)d_in[7];
  const float* Wg = (const float*)d_in[8];
  const float* Wu = (const float*)d_in[9];
  const float* Wd = (const float*)d_in[10];
  float* out = (float*)d_out;
  (void)in_sizes; (void)n_in; (void)out_size; (void)ws_size;

  char* ws = (char*)d_ws;
  const size_t MB = 1024*1024;
  char* R0 = ws;                 // 96 MB
  char* R1 = ws + 96*MB;         // 24 MB
  char* R2 = ws + 120*MB;        // 24 MB
  char* R3 = ws + 144*MB;        // 24 MB
  char* R4 = ws + 168*MB;        // 16 MB
  char* RS = ws + 184*MB;        // small buffers

  // phase A pointers (attention)
  const size_t WSLB = (size_t)HID*HID;   // elements per split slab (8 MB)
  u16* W0 = (u16*)R0;
  u16 *Wq1 = W0,          *Wq2 = W0 + WSLB,    *Wq3 = W0 + 2*WSLB;
  u16 *Wk1 = W0 + 3*WSLB, *Wk2 = W0 + 4*WSLB,  *Wk3 = W0 + 5*WSLB;
  u16 *Wv1 = W0 + 6*WSLB, *Wv2 = W0 + 7*WSLB,  *Wv3 = W0 + 8*WSLB;
  u16 *Wo1 = W0 + 9*WSLB, *Wo2 = W0 + 10*WSLB, *Wo3 = W0 + 11*WSLB;
  const size_t TSLB = (size_t)T_TOK*HID;  // elements per activation slab (8 MB)
  u16 *xn1 = (u16*)R1, *xn2 = (u16*)R1 + TSLB, *xn3 = (u16*)R1 + 2*TSLB;
  u16 *q1  = (u16*)R2, *q2  = (u16*)R2 + TSLB, *q3  = (u16*)R2 + 2*TSLB;
  u16 *k1  = (u16*)R3, *k2  = (u16*)R3 + TSLB, *k3  = (u16*)R3 + 2*TSLB;
  u16 *vt1 = xn1, *vt2 = xn2, *vt3 = xn3;        // reuse R1 after xn is dead
  float* vf  = (float*)R4;
  float* aof = (float*)R4;                        // reuse after vtrans
  u16 *ao1 = k1, *ao2 = k2, *ao3 = k3;            // reuse R3 after fattn
  float* x1  = (float*)R4;                        // reuse after split3 (O-proj out)
  // phase B pointers (MoE)
  u16* WgT = (u16*)R0;                            // 32 MB
  u16* WuT = (u16*)R0 + (size_t)NEXP*MDIM*HID;    // 32 MB
  u16* WdT = (u16*)R0 + 2*(size_t)NEXP*MDIM*HID;  // 32 MB
  u16* ynb = (u16*)R1;                            // 8 MB
  float* yn = (float*)(R1 + 8*MB);                // 16 MB
  u16* hb  = (u16*)R2;                            // 32 MB spans R2 + first 8MB of R3
  int*   tok_list = (int*)RS;                     // 64 KB
  float* w_list   = (float*)(RS + 64*1024);       // 64 KB
  int*   cur      = (int*)(RS + 128*1024);
  int*   cnt_pad  = (int*)(RS + 132*1024);
  float* ct   = (float*)(RS + 256*1024);
  float* stab = (float*)(RS + 384*1024);

  dim3 blk256(256), gMoE(16,16,8);

  rope_table_k<<<dim3(SEQ*32/256), blk256, 0, stream>>>(ct, stab);
  convT3<<<dim3(HID/64, HID/64), blk256, 0, stream>>>(Wq, Wq1, Wq2, Wq3);
  convT3<<<dim3(HID/64, HID/64), blk256, 0, stream>>>(Wk, Wk1, Wk2, Wk3);
  convT3<<<dim3(HID/64, HID/64), blk256, 0, stream>>>(Wv, Wv1, Wv2, Wv3);
  convT3<<<dim3(HID/64, HID/64), blk256, 0, stream>>>(Wo, Wo1, Wo2, Wo3);

  rmsnorm3_k<<<dim3(T_TOK), blk256, 0, stream>>>(hs, w_attn, xn1, xn2, xn3);

  // fused Q/K/V (rope+split for Q,K; f32 for V) — 768 blocks, 3/CU co-resident
  gemm_qkv<<<dim3(16,16,3), blk256, 0, stream>>>(xn1,xn2,xn3,
      Wq1,Wq2,Wq3, Wk1,Wk2,Wk3, Wv1,Wv2,Wv3,
      q1,q2,q3, k1,k2,k3, vf, ct, stab);

  vtrans3_k<<<dim3(SEQ/64, BATCH*NHEAD), blk256, 0, stream>>>(vf, vt1, vt2, vt3);   // xn dead

  fattn3_k<<<dim3(BATCH*NHEAD, SEQ/64), blk256, 0, stream>>>(q1,q2,q3, k1,k2,k3, vt1,vt2,vt3, aof);  // vf dead

  split3_k<<<dim3(T_TOK), blk256, 0, stream>>>(aof, ao1, ao2, ao3);                 // k dead

  // O-projection, 128x64 tiles — 512 blocks, 2/CU co-resident
  gemm_o<<<dim3(32,16), blk256, 0, stream>>>(ao1,ao2,ao3, Wo1,Wo2,Wo3, x1, hs);     // aof dead

  // attention weights dead -> convert MoE weights into R0
  convT<<<dim3(MDIM/64, HID/64, NEXP), blk256, 0, stream>>>(Wg, WgT, HID, MDIM);
  convT<<<dim3(MDIM/64, HID/64, NEXP), blk256, 0, stream>>>(Wu, WuT, HID, MDIM);
  convT<<<dim3(HID/64, MDIM/64, NEXP), blk256, 0, stream>>>(Wd, WdT, MDIM, HID);

  // MoE norm also initializes Out with the residual x1
  rmsnorm_k<<<dim3(T_TOK), blk256, 0, stream>>>(x1, w_moe, ynb, yn, out);   // vt dead

  hipMemsetAsync(cur, 0, NEXP*sizeof(int), stream);
  router_scatter_k<<<dim3(T_TOK), dim3(64), 0, stream>>>(yn, Wr, tok_list, w_list, cur);
  pad_k<<<dim3(NEXP), dim3(128), 0, stream>>>(cur, tok_list, w_list, cnt_pad);

  gemm_gateup_sp<<<gMoE, blk256, 0, stream>>>(ynb, WgT, WuT, tok_list, w_list, cnt_pad, hb);  // q, ao dead
  gemm_down_sp<<<gMoE, blk256, 0, stream>>>(hb, WdT, tok_list, cnt_pad, out);
}

// Round 9
// 843.773 us; speedup vs baseline: 2.9234x; 1.0929x over previous
//
#include <hip/hip_runtime.h>
#include <hip/hip_bf16.h>
#include <cstdint>

typedef unsigned short u16;
typedef __bf16 bf16x4_t __attribute__((ext_vector_type(4)));
typedef __bf16 bf16x8_t __attribute__((ext_vector_type(8)));
typedef float f32x4_t __attribute__((ext_vector_type(4)));
typedef unsigned short us4_t __attribute__((ext_vector_type(4)));
typedef unsigned short us8_t __attribute__((ext_vector_type(8)));

#define BATCH 2
#define SEQ 1024
#define HID 2048
#define NHEAD 32
#define NEXP 8
#define MDIM 1024
#define T_TOK (BATCH*SEQ)   // 2048

// ---------- helpers ----------

__device__ __forceinline__ void gload16(const void* g, void* l){
  __builtin_amdgcn_global_load_lds((__attribute__((address_space(1))) void*)(uintptr_t)g,
                                   (__attribute__((address_space(3))) void*)l, 16, 0, 0);
}

// Swizzled fragment read, 64B LDS rows (MoE A-side, BK=32): byte ^= (row&3)<<4.
__device__ __forceinline__ bf16x8_t ldfsw64(const u16* base, int row, int colbyte){
  const char* p = (const char*)base + row*64;
  int sw = (row & 3) << 4;
  bf16x4_t a = *(const bf16x4_t*)(p + (colbyte ^ sw));
  bf16x4_t b = *(const bf16x4_t*)(p + ((colbyte + 32) ^ sw));
  return __builtin_shufflevector(a, b, 0,1,2,3,4,5,6,7);
}

__device__ __forceinline__ f32x4_t mfma16(bf16x8_t a, bf16x8_t b, f32x4_t c){
  return __builtin_amdgcn_mfma_f32_16x16x32_bf16(a, b, c, 0, 0, 0);
}

__device__ __forceinline__ u16 f2b(float f){
  __hip_bfloat16 h = __float2bfloat16(f);
  return __builtin_bit_cast(u16, h);
}
__device__ __forceinline__ float b2f(u16 b){
  return __builtin_bit_cast(float, (unsigned int)b << 16);
}
// 3-way bf16 split: v ~= b1 + b2 + b3
__device__ __forceinline__ void split3v(float v, u16& b1, u16& b2, u16& b3){
  b1 = f2b(v); float f1 = b2f(b1);
  float r1 = v - f1;
  b2 = f2b(r1); float f2 = b2f(b2);
  b3 = f2b(r1 - f2);
}

// Standard frag-linear slab (rows x k, k-blocked by 32):
//   rec u16 off = (((row>>7)*KB + kb)*8 + (row>>4)&7)*512 + ((row&15)*4 + fg)*8 + half*4 + e
//   where kb=k>>5, fg=(k&15)>>2, half=(k>>4)&1, e=k&3.
// Per-head Q/K slab (64 d): off = ((tb*2+kb)*64 + (tok&15)*4 + (d&15)>>2)*8 + ((d>>4)&1)*4 + (d&3), tb=tok>>4
// Per-head V slab: off = (((tok>>5)*4 + d>>4)*64 + (d&15)*4 + (tok&15)>>2)*8 + ((tok>>4)&1)*4 + (tok&3)

// ---------- MoE weight convert+transpose -> FRAGMENT-LINEAR: f32 [C k][R n] -> slabs ----------

__global__ __launch_bounds__(256)
void convT_fl(const float* __restrict__ in, u16* __restrict__ out, int R, int C)
{
  __shared__ float t[64][65];
  const int KB = C >> 5;
  int bz = blockIdx.z;
  const float* ip = in + (size_t)bz * R * C;
  u16* op = out + (size_t)bz * R * C;
  int r0 = blockIdx.y*64, c0 = blockIdx.x*64;   // r = k dim, c = n dim
  int tid = threadIdx.x;
  int lr = tid >> 4;
  int lc = (tid & 15) * 4;
  #pragma unroll
  for (int i = 0; i < 4; i++){
    int r = lr + i*16;
    float4 v = *(const float4*)&ip[(size_t)(r0 + r) * R + c0 + lc];
    t[r][lc] = v.x; t[r][lc+1] = v.y; t[r][lc+2] = v.z; t[r][lc+3] = v.w;
  }
  __syncthreads();
  if (tid < 128){
    int n_l = tid & 63;
    int kb2 = tid >> 6;
    int gn = c0 + n_l;
    int rb = gn >> 7, sub = (gn >> 4) & 7, frn = gn & 15;
    int kb = (r0 >> 5) + kb2;
    size_t fo = (((size_t)(rb*KB + kb)*8 + sub)*64 + frn*4) * 8;
    #pragma unroll
    for (int fg = 0; fg < 4; fg++){
      us8_t w;
      #pragma unroll
      for (int j = 0; j < 4; j++){
        w[j]   = f2b(t[kb2*32 + fg*4 + j][n_l]);
        w[j+4] = f2b(t[kb2*32 + fg*4 + 16 + j][n_l]);
      }
      *(us8_t*)&op[fo + fg*8] = w;
    }
  }
}

// ---------- attention weight convert+transpose, 3-way split -> standard frag-linear ----------

__global__ __launch_bounds__(256)
void convT3(const float* __restrict__ in, u16* __restrict__ o1, u16* __restrict__ o2,
            u16* __restrict__ o3)
{
  __shared__ float t[64][65];
  int r0 = blockIdx.y*64, c0 = blockIdx.x*64;   // r = k dim, c = n dim
  int tid = threadIdx.x;
  int lr = tid >> 4;
  int lc = (tid & 15) * 4;
  #pragma unroll
  for (int i = 0; i < 4; i++){
    int r = lr + i*16;
    float4 v = *(const float4*)&in[(size_t)(r0 + r) * HID + c0 + lc];
    t[r][lc] = v.x; t[r][lc+1] = v.y; t[r][lc+2] = v.z; t[r][lc+3] = v.w;
  }
  __syncthreads();
  if (tid < 128){
    int n  = tid & 63;
    int kb2 = tid >> 6;
    int gn = c0 + n;
    int nb = gn >> 7, sub = (gn >> 4) & 7, fr = gn & 15;
    int kb = (r0 >> 5) + kb2;
    size_t fo = (((size_t)(nb*64 + kb)*8 + sub)*64 + fr*4) * 8;
    #pragma unroll
    for (int fg = 0; fg < 4; fg++){
      us8_t w1, w2, w3;
      #pragma unroll
      for (int j = 0; j < 4; j++){
        u16 b1, b2, b3;
        split3v(t[kb2*32 + fg*4 + j][n], b1, b2, b3);
        w1[j] = b1; w2[j] = b2; w3[j] = b3;
        split3v(t[kb2*32 + fg*4 + 16 + j][n], b1, b2, b3);
        w1[j+4] = b1; w2[j+4] = b2; w3[j+4] = b3;
      }
      *(us8_t*)&o1[fo + fg*8] = w1;
      *(us8_t*)&o2[fo + fg*8] = w2;
      *(us8_t*)&o3[fo + fg*8] = w3;
    }
  }
}

// ---------- RMSNorm -> 3-way split, standard frag-linear (attention input) ----------

__global__ __launch_bounds__(256)
void rmsnorm3_k(const float* __restrict__ x, const float* __restrict__ w,
                u16* __restrict__ o1, u16* __restrict__ o2, u16* __restrict__ o3)
{
  int row = blockIdx.x;
  const float* xr = x + (size_t)row * HID;
  int tid = threadIdx.x;
  int kb = tid >> 2, fg = tid & 3;
  int kbase = kb*32 + fg*4;
  float4 a = *(const float4*)(xr + kbase);
  float4 b = *(const float4*)(xr + kbase + 16);
  float ss = a.x*a.x + a.y*a.y + a.z*a.z + a.w*a.w
           + b.x*b.x + b.y*b.y + b.z*b.z + b.w*b.w;
  #pragma unroll
  for (int off = 32; off; off >>= 1) ss += __shfl_down(ss, off);
  __shared__ float red[4];
  if ((tid & 63) == 0) red[tid >> 6] = ss;
  __syncthreads();
  float tot = red[0] + red[1] + red[2] + red[3];
  float rs = (float)(1.0 / sqrt((double)tot * (1.0/2048.0) + 1e-5));
  float4 wa = *(const float4*)(w + kbase);
  float4 wb = *(const float4*)(w + kbase + 16);
  float o[8];
  o[0]=a.x*rs*wa.x; o[1]=a.y*rs*wa.y; o[2]=a.z*rs*wa.z; o[3]=a.w*rs*wa.w;
  o[4]=b.x*rs*wb.x; o[5]=b.y*rs*wb.y; o[6]=b.z*rs*wb.z; o[7]=b.w*rs*wb.w;
  us8_t w1, w2, w3;
  #pragma unroll
  for (int j = 0; j < 8; j++){
    u16 b1, b2, b3; split3v(o[j], b1, b2, b3);
    w1[j] = b1; w2[j] = b2; w3[j] = b3;
  }
  int rb = row >> 7, sub = (row >> 4) & 7, fr = row & 15;
  size_t fo = (((size_t)(rb*64 + kb)*8 + sub)*64 + fr*4 + fg) * 8;
  *(us8_t*)&o1[fo] = w1; *(us8_t*)&o2[fo] = w2; *(us8_t*)&o3[fo] = w3;
}

// ---------- RMSNorm (MoE): bf16 out + f32 out + residual passthrough to Out ----------

__global__ __launch_bounds__(256)
void rmsnorm_k(const float* __restrict__ x, const float* __restrict__ w,
               u16* __restrict__ ob, float* __restrict__ of, float* __restrict__ oi)
{
  int row = blockIdx.x;
  const float* xr = x + (size_t)row * HID;
  int base = threadIdx.x * 8;
  float4 a = *(const float4*)(xr + base);
  float4 b = *(const float4*)(xr + base + 4);
  float ss = a.x*a.x + a.y*a.y + a.z*a.z + a.w*a.w
           + b.x*b.x + b.y*b.y + b.z*b.z + b.w*b.w;
  #pragma unroll
  for (int off = 32; off; off >>= 1) ss += __shfl_down(ss, off);
  __shared__ float red[4];
  if ((threadIdx.x & 63) == 0) red[threadIdx.x >> 6] = ss;
  __syncthreads();
  float tot = red[0] + red[1] + red[2] + red[3];
  float rs = (float)(1.0 / sqrt((double)tot * (1.0/2048.0) + 1e-5));
  float4 wa = *(const float4*)(w + base);
  float4 wb = *(const float4*)(w + base + 4);
  float o[8];
  o[0]=a.x*rs*wa.x; o[1]=a.y*rs*wa.y; o[2]=a.z*rs*wa.z; o[3]=a.w*rs*wa.w;
  o[4]=b.x*rs*wb.x; o[5]=b.y*rs*wb.y; o[6]=b.z*rs*wb.z; o[7]=b.w*rs*wb.w;
  us4_t p0, p1;
  p0.x=f2b(o[0]); p0.y=f2b(o[1]); p0.z=f2b(o[2]); p0.w=f2b(o[3]);
  p1.x=f2b(o[4]); p1.y=f2b(o[5]); p1.z=f2b(o[6]); p1.w=f2b(o[7]);
  *(us4_t*)&ob[(size_t)row*HID + base] = p0;
  *(us4_t*)&ob[(size_t)row*HID + base + 4] = p1;
  float* orow = of + (size_t)row*HID + base;
  *(float4*)orow = make_float4(o[0],o[1],o[2],o[3]);
  *(float4*)(orow+4) = make_float4(o[4],o[5],o[6],o[7]);
  float* irow = oi + (size_t)row*HID + base;
  *(float4*)irow = a;
  *(float4*)(irow+4) = b;
}

// ---------- RoPE table (f64 math -> f32) ----------

__global__ void rope_table_k(float* ct, float* st){
  int i = blockIdx.x*256 + threadIdx.x;   // SEQ*32
  int s = i >> 5, j = i & 31;
  double invf = exp(-(double)j / 32.0 * log(10000.0));
  double ang = (double)s * invf;
  ct[i] = (float)cos(ang);
  st[i] = (float)sin(ang);
}

// ---------- fused Q/K/V split GEMM (frag-linear in; Q/K out per-head frag-linear) ----------

__global__ __launch_bounds__(256, 2)
void gemm_qkv(const u16* __restrict__ A1, const u16* __restrict__ A2, const u16* __restrict__ A3,
              const u16* __restrict__ Wq1, const u16* __restrict__ Wq2, const u16* __restrict__ Wq3,
              const u16* __restrict__ Wk1, const u16* __restrict__ Wk2, const u16* __restrict__ Wk3,
              const u16* __restrict__ Wv1, const u16* __restrict__ Wv2, const u16* __restrict__ Wv3,
              u16* __restrict__ oq1, u16* __restrict__ oq2, u16* __restrict__ oq3,
              u16* __restrict__ ok1, u16* __restrict__ ok2, u16* __restrict__ ok3,
              float* __restrict__ vf,
              const float* __restrict__ ct, const float* __restrict__ st)
{
  __shared__ u16 As[3][128*32];
  __shared__ u16 Bs[3][128*32];
  const int flat = blockIdx.x + 16*blockIdx.y + 256*blockIdx.z;
  const int logical = (flat & 7) * 96 + (flat >> 3);   // XCD-contiguous chunks
  const int z  = logical >> 8;
  const int bm = ((logical >> 4) & 15) * 128;
  const int bn = (logical & 15) * 128;
  const int tid = threadIdx.x;
  const int lane = tid & 63;
  const int wave = tid >> 6;
  const int wr = wave >> 1, wc = wave & 1;
  const int fr = lane & 15, fg = lane >> 4;

  f32x4_t acc[4][4] = {};

  const u16* Ap[3] = {A1, A2, A3};
  const u16* Bp[3];
  if (z == 0)      { Bp[0] = Wq1; Bp[1] = Wq2; Bp[2] = Wq3; }
  else if (z == 1) { Bp[0] = Wk1; Bp[1] = Wk2; Bp[2] = Wk3; }
  else             { Bp[0] = Wv1; Bp[1] = Wv2; Bp[2] = Wv3; }
  const u16* gA[3]; const u16* gB[3];
  #pragma unroll
  for (int t = 0; t < 3; t++){
    gA[t] = Ap[t] + (size_t)(bm >> 7) * 64 * 4096 + tid*8;
    gB[t] = Bp[t] + (size_t)(bn >> 7) * 64 * 4096 + tid*8;
  }

  for (int kb = 0; kb < 64; kb++){
    const size_t o = (size_t)kb * 4096;
    #pragma unroll
    for (int t = 0; t < 3; t++){
      gload16(gA[t] + o,        &As[t][tid*8]);
      gload16(gA[t] + o + 2048, &As[t][2048 + tid*8]);
      gload16(gB[t] + o,        &Bs[t][tid*8]);
      gload16(gB[t] + o + 2048, &Bs[t][2048 + tid*8]);
    }
    __syncthreads();
    bf16x8_t bfv[3][4];
    #pragma unroll
    for (int t = 0; t < 3; t++)
      #pragma unroll
      for (int ni = 0; ni < 4; ni++)
        bfv[t][ni] = *(const bf16x8_t*)&Bs[t][(((wc*4 + ni)*64) + fr*4 + fg)*8];
    #pragma unroll
    for (int mi = 0; mi < 4; mi++){
      const int ao = (((wr*4 + mi)*64) + fr*4 + fg)*8;
      bf16x8_t a1 = *(const bf16x8_t*)&As[0][ao];
      bf16x8_t a2 = *(const bf16x8_t*)&As[1][ao];
      bf16x8_t a3 = *(const bf16x8_t*)&As[2][ao];
      #pragma unroll
      for (int ni = 0; ni < 4; ni++){
        f32x4_t c = acc[mi][ni];
        c = mfma16(a3, bfv[0][ni], c);   // a3b1
        c = mfma16(a2, bfv[1][ni], c);   // a2b2
        c = mfma16(a1, bfv[2][ni], c);   // a1b3
        c = mfma16(a2, bfv[0][ni], c);   // a2b1
        c = mfma16(a1, bfv[1][ni], c);   // a1b2
        c = mfma16(a1, bfv[0][ni], c);   // a1b1
        acc[mi][ni] = c;
      }
    }
    __syncthreads();
  }

  if (z < 2){
    u16* O1 = z ? ok1 : oq1;
    u16* O2 = z ? ok2 : oq2;
    u16* O3 = z ? ok3 : oq3;
    const int h = (bn + wc*64) >> 6;
    #pragma unroll
    for (int mi = 0; mi < 4; mi++)
      #pragma unroll
      for (int r = 0; r < 4; r++){
        int row = bm + wr*64 + mi*16 + fg*4 + r;
        int s = row & (SEQ-1);
        int b = row >> 10;
        int tok = row & 1023;
        int tb = tok >> 4;
        int frk = fg*4 + r;   // tok & 15
        size_t sb = (size_t)(b*NHEAD + h) * 65536;
        #pragma unroll
        for (int ni = 0; ni < 2; ni++){
          int dlo = ni*16 + fr;   // 0..31 within head
          float c  = ct[s*32 + dlo];
          float sn = st[s*32 + dlo];
          float xl = acc[mi][ni][r], xh = acc[mi][ni+2][r];
          float ol = xl*c - xh*sn;   // d = dlo   (kb 0)
          float oh = xh*c + xl*sn;   // d = dlo+32 (kb 1)
          size_t a0 = sb + ((size_t)(tb*2 + 0)*64 + frk*4 + (fr>>2))*8 + ni*4 + (fr&3);
          size_t a1 = sb + ((size_t)(tb*2 + 1)*64 + frk*4 + (fr>>2))*8 + ni*4 + (fr&3);
          u16 b1, b2, b3;
          split3v(ol, b1, b2, b3); O1[a0] = b1; O2[a0] = b2; O3[a0] = b3;
          split3v(oh, b1, b2, b3); O1[a1] = b1; O2[a1] = b2; O3[a1] = b3;
        }
      }
  } else {
    #pragma unroll
    for (int mi = 0; mi < 4; mi++)
      #pragma unroll
      for (int ni = 0; ni < 4; ni++)
        #pragma unroll
        for (int r = 0; r < 4; r++){
          int row = bm + wr*64 + mi*16 + fg*4 + r;
          int col = bn + wc*64 + ni*16 + fr;
          vf[(size_t)row * HID + col] = acc[mi][ni][r];
        }
  }
}

// ---------- O-projection split GEMM, 128x64 tiles (frag-linear), +residual ----------

__global__ __launch_bounds__(256, 2)
void gemm_o(const u16* __restrict__ A1, const u16* __restrict__ A2, const u16* __restrict__ A3,
            const u16* __restrict__ B1, const u16* __restrict__ B2, const u16* __restrict__ B3,
            float* __restrict__ Cf, const float* __restrict__ Res)
{
  __shared__ u16 As[3][128*32];   // 24KB
  __shared__ u16 Bs[3][64*32];    // 12KB
  const int flat = blockIdx.x + 32*blockIdx.y;
  const int logical = (flat & 7) * 64 + (flat >> 3);   // 512 = 8*64
  const int bn = (logical & 31) * 64;
  const int bm = (logical >> 5) * 128;
  const int tid = threadIdx.x;
  const int lane = tid & 63;
  const int wave = tid >> 6;
  const int wr = wave >> 1, wc = wave & 1;
  const int fr = lane & 15, fg = lane >> 4;

  f32x4_t acc[4][2] = {};

  const u16* Ap[3] = {A1, A2, A3};
  const u16* Bp[3] = {B1, B2, B3};
  const u16* gA[3]; const u16* gB[3];
  const int sb0 = (bn >> 4) & 7;   // 0 or 4
  #pragma unroll
  for (int t = 0; t < 3; t++){
    gA[t] = Ap[t] + (size_t)(bm >> 7) * 64 * 4096 + tid*8;
    gB[t] = Bp[t] + (size_t)(bn >> 7) * 64 * 4096 + sb0*512 + tid*8;
  }

  for (int kb = 0; kb < 64; kb++){
    const size_t o = (size_t)kb * 4096;
    #pragma unroll
    for (int t = 0; t < 3; t++){
      gload16(gA[t] + o,        &As[t][tid*8]);
      gload16(gA[t] + o + 2048, &As[t][2048 + tid*8]);
      gload16(gB[t] + o,        &Bs[t][tid*8]);
    }
    __syncthreads();
    bf16x8_t bfv[3][2];
    #pragma unroll
    for (int t = 0; t < 3; t++)
      #pragma unroll
      for (int nj = 0; nj < 2; nj++)
        bfv[t][nj] = *(const bf16x8_t*)&Bs[t][(((wc*2 + nj)*64) + fr*4 + fg)*8];
    #pragma unroll
    for (int mi = 0; mi < 4; mi++){
      const int ao = (((wr*4 + mi)*64) + fr*4 + fg)*8;
      bf16x8_t a1 = *(const bf16x8_t*)&As[0][ao];
      bf16x8_t a2 = *(const bf16x8_t*)&As[1][ao];
      bf16x8_t a3 = *(const bf16x8_t*)&As[2][ao];
      #pragma unroll
      for (int nj = 0; nj < 2; nj++){
        f32x4_t c = acc[mi][nj];
        c = mfma16(a3, bfv[0][nj], c);
        c = mfma16(a2, bfv[1][nj], c);
        c = mfma16(a1, bfv[2][nj], c);
        c = mfma16(a2, bfv[0][nj], c);
        c = mfma16(a1, bfv[1][nj], c);
        c = mfma16(a1, bfv[0][nj], c);
        acc[mi][nj] = c;
      }
    }
    __syncthreads();
  }

  #pragma unroll
  for (int mi = 0; mi < 4; mi++)
    #pragma unroll
    for (int nj = 0; nj < 2; nj++)
      #pragma unroll
      for (int r = 0; r < 4; r++){
        int row = bm + wr*64 + mi*16 + fg*4 + r;
        int col = bn + wc*32 + nj*16 + fr;
        size_t idx = (size_t)row * HID + col;
        Cf[idx] = acc[mi][nj][r] + Res[idx];
      }
}

// ---------- V transpose + split: f32 [T][H] -> per-head frag-linear V slabs ----------

__global__ __launch_bounds__(256)
void vtrans3_k(const float* __restrict__ vf, u16* __restrict__ t1, u16* __restrict__ t2,
               u16* __restrict__ t3)
{
  __shared__ float t[64][65];
  int st0 = blockIdx.x * 64;
  int bh = blockIdx.y;
  int b = bh >> 5, h = bh & 31;
  int tid = threadIdx.x;
  #pragma unroll
  for (int i = 0; i < 4; i++){
    int idx = tid + i*256;                // 1024 float4 chunks
    int s = idx >> 4, dc = (idx & 15) * 4;
    float4 v = *(const float4*)&vf[(size_t)(b*SEQ + st0 + s) * HID + h*64 + dc];
    t[dc+0][s] = v.x; t[dc+1][s] = v.y; t[dc+2][s] = v.z; t[dc+3][s] = v.w;
  }
  __syncthreads();
  #pragma unroll
  for (int it = 0; it < 2; it++){
    int rho = tid + it*256;          // 512 records per 64-token tile
    int kbv_l = rho >> 8;            // 0..1 (32-token blocks)
    int db    = (rho >> 6) & 3;      // d block of 16
    int lane  = rho & 63;
    int d = db*16 + (lane >> 2);
    int fgv = lane & 3;
    us8_t w1, w2, w3;
    #pragma unroll
    for (int j = 0; j < 8; j++){
      int half = j >> 2, e = j & 3;
      int tokl = kbv_l*32 + half*16 + fgv*4 + e;
      u16 b1, b2, b3; split3v(t[d][tokl], b1, b2, b3);
      w1[j] = b1; w2[j] = b2; w3[j] = b3;
    }
    size_t base = (size_t)bh*65536 + ((size_t)(((st0>>5) + kbv_l)*4 + db)*64 + lane)*8;
    *(us8_t*)&t1[base] = w1; *(us8_t*)&t2[base] = w2; *(us8_t*)&t3[base] = w3;
  }
}

// ---------- flash attention, split-precision (causal), frag-linear ao out ----------

__global__ __launch_bounds__(256)
void fattn3_k(const u16* __restrict__ q1, const u16* __restrict__ q2, const u16* __restrict__ q3,
              const u16* __restrict__ k1, const u16* __restrict__ k2, const u16* __restrict__ k3,
              const u16* __restrict__ v1, const u16* __restrict__ v2, const u16* __restrict__ v3,
              u16* __restrict__ ao1, u16* __restrict__ ao2, u16* __restrict__ ao3)
{
  __shared__ u16 Ks[3][4096];     // 8KB each
  __shared__ u16 Vs[3][4096];     // 8KB each
  __shared__ u16 Ps[2][4][1024];  // 16KB -> 64KB total
  const int bh = blockIdx.x, qt = blockIdx.y;
  const int b = bh >> 5, h = bh & 31;
  const int tid = threadIdx.x, lane = tid & 63, wave = tid >> 6;
  const int fr = lane & 15, fg = lane >> 4;
  const size_t hslab = (size_t)bh * 65536;

  // Q fragments direct from per-head frag-linear global
  bf16x8_t aq[3][2];
  {
    size_t qo = hslab + (size_t)(qt*4 + wave)*1024 + (size_t)(fr*4 + fg)*8;
    aq[0][0] = *(const bf16x8_t*)&q1[qo]; aq[0][1] = *(const bf16x8_t*)&q1[qo + 512];
    aq[1][0] = *(const bf16x8_t*)&q2[qo]; aq[1][1] = *(const bf16x8_t*)&q2[qo + 512];
    aq[2][0] = *(const bf16x8_t*)&q3[qo]; aq[2][1] = *(const bf16x8_t*)&q3[qo + 512];
  }

  f32x4_t oacc[4] = {};
  float m_r[4], l_r[4];
  #pragma unroll
  for (int r = 0; r < 4; r++){ m_r[r] = -1e30f; l_r[r] = 0.f; }

  const u16* kp[3] = { k1 + hslab, k2 + hslab, k3 + hslab };
  const u16* vp[3] = { v1 + hslab, v2 + hslab, v3 + hslab };

  for (int kt = 0; kt <= qt; kt++){
    const size_t o = (size_t)kt * 4096;
    #pragma unroll
    for (int t = 0; t < 3; t++){
      gload16(kp[t] + o + tid*8,        &Ks[t][tid*8]);
      gload16(kp[t] + o + 2048 + tid*8, &Ks[t][2048 + tid*8]);
      gload16(vp[t] + o + tid*8,        &Vs[t][tid*8]);
      gload16(vp[t] + o + 2048 + tid*8, &Vs[t][2048 + tid*8]);
    }
    __syncthreads();

    f32x4_t sc[4] = {};
    #pragma unroll
    for (int nf = 0; nf < 4; nf++)
      #pragma unroll
      for (int ks = 0; ks < 2; ks++){
        const int ko = ((nf*2 + ks)*64 + fr*4 + fg)*8;
        bf16x8_t bk0 = *(const bf16x8_t*)&Ks[0][ko];
        bf16x8_t bk1 = *(const bf16x8_t*)&Ks[1][ko];
        bf16x8_t bk2 = *(const bf16x8_t*)&Ks[2][ko];
        sc[nf] = mfma16(aq[2][ks], bk0, sc[nf]);
        sc[nf] = mfma16(aq[1][ks], bk1, sc[nf]);
        sc[nf] = mfma16(aq[0][ks], bk2, sc[nf]);
        sc[nf] = mfma16(aq[1][ks], bk0, sc[nf]);
        sc[nf] = mfma16(aq[0][ks], bk1, sc[nf]);
        sc[nf] = mfma16(aq[0][ks], bk0, sc[nf]);
      }

    float nm[4] = {-1e30f,-1e30f,-1e30f,-1e30f};
    #pragma unroll
    for (int nf = 0; nf < 4; nf++)
      #pragma unroll
      for (int r = 0; r < 4; r++){
        float v = sc[nf][r] * 0.125f;
        if (kt == qt && nf*16 + fr > wave*16 + fg*4 + r) v = -1e30f;
        sc[nf][r] = v;
        nm[r] = fmaxf(nm[r], v);
      }
    #pragma unroll
    for (int r = 0; r < 4; r++)
      #pragma unroll
      for (int msk = 8; msk; msk >>= 1) nm[r] = fmaxf(nm[r], __shfl_xor(nm[r], msk));

    #pragma unroll
    for (int r = 0; r < 4; r++){
      float mn = fmaxf(m_r[r], nm[r]);
      float f = __expf(m_r[r] - mn);
      m_r[r] = mn;
      float rsum = 0.f;
      #pragma unroll
      for (int nf = 0; nf < 4; nf++){
        float pv = __expf(sc[nf][r] - mn);
        sc[nf][r] = pv;
        rsum += pv;
      }
      #pragma unroll
      for (int msk = 8; msk; msk >>= 1) rsum += __shfl_xor(rsum, msk);
      l_r[r] = l_r[r]*f + rsum;
      #pragma unroll
      for (int df = 0; df < 4; df++) oacc[df][r] *= f;
    }

    // P 2-way split to frag-linear LDS
    #pragma unroll
    for (int nf = 0; nf < 4; nf++)
      #pragma unroll
      for (int r = 0; r < 4; r++){
        float pv = sc[nf][r];
        u16 b1 = f2b(pv);
        float f1 = b2f(b1);
        u16 b2 = f2b(pv - f1);
        int pa = ((nf>>1)*64 + (fg*4 + r)*4 + (fr>>2))*8 + (nf&1)*4 + (fr&3);
        Ps[0][wave][pa] = b1;
        Ps[1][wave][pa] = b2;
      }

    #pragma unroll
    for (int ks = 0; ks < 2; ks++){
      bf16x8_t pa0 = *(const bf16x8_t*)&Ps[0][wave][(ks*64 + fr*4 + fg)*8];
      bf16x8_t pa1 = *(const bf16x8_t*)&Ps[1][wave][(ks*64 + fr*4 + fg)*8];
      #pragma unroll
      for (int df = 0; df < 4; df++){
        const int vo = ((ks*4 + df)*64 + fr*4 + fg)*8;
        bf16x8_t bv0 = *(const bf16x8_t*)&Vs[0][vo];
        bf16x8_t bv1 = *(const bf16x8_t*)&Vs[1][vo];
        bf16x8_t bv2 = *(const bf16x8_t*)&Vs[2][vo];
        oacc[df] = mfma16(pa0, bv2, oacc[df]);   // p1 v3
        oacc[df] = mfma16(pa1, bv1, oacc[df]);   // p2 v2
        oacc[df] = mfma16(pa1, bv0, oacc[df]);   // p2 v1
        oacc[df] = mfma16(pa0, bv1, oacc[df]);   // p1 v2
        oacc[df] = mfma16(pa0, bv0, oacc[df]);   // p1 v1
      }
    }
    __syncthreads();
  }

  // output: 3-way split directly to standard frag-linear ao slabs
  #pragma unroll
  for (int r = 0; r < 4; r++){
    float inv = 1.f / l_r[r];
    int orow = b*SEQ + qt*64 + wave*16 + fg*4 + r;
    int rb = orow >> 7, sub = (orow >> 4) & 7, frA = orow & 15;
    #pragma unroll
    for (int df = 0; df < 4; df++){
      float val = oacc[df][r] * inv;
      int kb = h*2 + (df >> 1);
      size_t addr = ((((size_t)rb*64 + kb)*8 + sub)*64 + frA*4 + (fr>>2))*8 + (df&1)*4 + (fr&3);
      u16 b1, b2, b3; split3v(val, b1, b2, b3);
      ao1[addr] = b1; ao2[addr] = b2; ao3[addr] = b3;
    }
  }
}

// ---------- router + scatter: f64 logits, top-2, compact per-expert lists ----------

__global__ __launch_bounds__(64)
void router_scatter_k(const float* __restrict__ yn, const float* __restrict__ Wr,
                      int* __restrict__ tok_list, float* __restrict__ w_list,
                      int* __restrict__ cur){
  int row = blockIdx.x;
  int lane = threadIdx.x;
  const float* xr = yn + (size_t)row * HID;
  double acc[8] = {};
  for (int j = lane; j < HID; j += 64){
    double xv = (double)xr[j];
    const float* wr = Wr + (size_t)j*8;
    float4 w0 = *(const float4*)wr;
    float4 w1 = *(const float4*)(wr + 4);
    acc[0] += xv*w0.x; acc[1] += xv*w0.y; acc[2] += xv*w0.z; acc[3] += xv*w0.w;
    acc[4] += xv*w1.x; acc[5] += xv*w1.y; acc[6] += xv*w1.z; acc[7] += xv*w1.w;
  }
  #pragma unroll
  for (int e = 0; e < 8; e++)
    #pragma unroll
    for (int off = 32; off; off >>= 1) acc[e] += __shfl_down(acc[e], off);
  if (lane == 0){
    double mx = acc[0];
    #pragma unroll
    for (int e = 1; e < 8; e++) mx = fmax(mx, acc[e]);
    double p[8];
    #pragma unroll
    for (int e = 0; e < 8; e++) p[e] = exp(acc[e] - mx);
    int i1 = 0;
    #pragma unroll
    for (int e = 1; e < 8; e++) if (p[e] > p[i1]) i1 = e;
    int i2 = (i1 == 0) ? 1 : 0;
    #pragma unroll
    for (int e = 0; e < 8; e++) if (e != i1 && p[e] > p[i2]) i2 = e;
    double s2 = p[i1] + p[i2];
    int pos1 = atomicAdd(&cur[i1], 1);
    tok_list[i1*T_TOK + pos1] = row;
    w_list[i1*T_TOK + pos1] = (float)(p[i1] / s2);
    int pos2 = atomicAdd(&cur[i2], 1);
    tok_list[i2*T_TOK + pos2] = row;
    w_list[i2*T_TOK + pos2] = (float)(p[i2] / s2);
  }
}

// pad each expert's list to a multiple of 128 with (token 0, weight 0)
__global__ __launch_bounds__(128)
void pad_k(const int* __restrict__ cur, int* __restrict__ tok_list,
           float* __restrict__ w_list, int* __restrict__ cnt_pad){
  int e = blockIdx.x;
  int c = cur[e];
  int cp = (c + 127) & ~127;
  for (int i = c + threadIdx.x; i < cp; i += 128){
    tok_list[e*T_TOK + i] = 0;
    w_list[e*T_TOK + i] = 0.f;
  }
  if (threadIdx.x == 0) cnt_pad[e] = cp;
}

// ---------- sparse fused gate+up GEMM (frag-linear B): h = silu(g)*u*w ----------

__global__ __launch_bounds__(256, 2)
void gemm_gateup_sp(const u16* __restrict__ A, const u16* __restrict__ WgT, const u16* __restrict__ WuT,
                    const int* __restrict__ tok_list, const float* __restrict__ w_list,
                    const int* __restrict__ cnt_pad, u16* __restrict__ Hb)
{
  const int e = blockIdx.z;
  const int bm = blockIdx.y * 128;   // position within expert list
  if (bm >= cnt_pad[e]) return;
  __shared__ u16 As[128*32];
  __shared__ u16 Bg[64*32];
  __shared__ u16 Bu[64*32];
  const int tid = threadIdx.x;
  const int lane = tid & 63;
  const int wave = tid >> 6;
  const int wr = wave >> 1, wc = wave & 1;
  const int fr = lane & 15, fg = lane >> 4;
  const int bn = blockIdx.x * 64;    // M cols

  f32x4_t ag[4][2] = {}, au[4][2] = {};

  const int srow = tid >> 2, skb = (tid & 3) ^ (srow & 3);   // swizzled A-source chunk
  const int tok0 = tok_list[e*T_TOK + bm + srow];
  const int tok1 = tok_list[e*T_TOK + bm + srow + 64];
  const u16* ga0 = A + (size_t)tok0 * HID + skb * 8;
  const u16* ga1 = A + (size_t)tok1 * HID + skb * 8;
  const int sub0 = (bn >> 4) & 7;    // 0 or 4
  const u16* gg = WgT + (size_t)e*MDIM*HID + ((size_t)(bn>>7)*512 + sub0)*512 + tid*8;
  const u16* gu = WuT + (size_t)e*MDIM*HID + ((size_t)(bn>>7)*512 + sub0)*512 + tid*8;

  for (int kb = 0; kb < 64; kb++){
    gload16(ga0 + kb*32, &As[tid*8]);
    gload16(ga1 + kb*32, &As[2048 + tid*8]);
    gload16(gg + (size_t)kb*4096, &Bg[tid*8]);
    gload16(gu + (size_t)kb*4096, &Bu[tid*8]);
    __syncthreads();
    bf16x8_t af[4], bg[2], bu[2];
    #pragma unroll
    for (int i = 0; i < 4; i++) af[i] = ldfsw64(As, wr*64 + i*16 + fr, fg*8);
    #pragma unroll
    for (int j = 0; j < 2; j++){
      bg[j] = *(const bf16x8_t*)&Bg[((wc*2 + j)*64 + fr*4 + fg)*8];
      bu[j] = *(const bf16x8_t*)&Bu[((wc*2 + j)*64 + fr*4 + fg)*8];
    }
    #pragma unroll
    for (int mi = 0; mi < 4; mi++)
      #pragma unroll
      for (int nj = 0; nj < 2; nj++){
        ag[mi][nj] = mfma16(af[mi], bg[nj], ag[mi][nj]);
        au[mi][nj] = mfma16(af[mi], bu[nj], au[mi][nj]);
      }
    __syncthreads();
  }

  #pragma unroll
  for (int mi = 0; mi < 4; mi++)
    #pragma unroll
    for (int nj = 0; nj < 2; nj++)
      #pragma unroll
      for (int r = 0; r < 4; r++){
        int pos = bm + wr*64 + mi*16 + fg*4 + r;
        int col = bn + wc*32 + nj*16 + fr;
        float g = ag[mi][nj][r], u = au[mi][nj][r];
        float h = g / (1.0f + __expf(-g)) * u * w_list[e*T_TOK + pos];
        Hb[((size_t)e*T_TOK + pos)*MDIM + col] = f2b(h);
      }
}

// ---------- sparse down GEMM (frag-linear B): atomic-accumulate onto Out ----------

__global__ __launch_bounds__(256, 2)
void gemm_down_sp(const u16* __restrict__ Hb, const u16* __restrict__ WdT,
                  const int* __restrict__ tok_list, const int* __restrict__ cnt_pad,
                  float* __restrict__ Out)
{
  const int e = blockIdx.z;
  const int bm = blockIdx.y * 128;
  if (bm >= cnt_pad[e]) return;
  __shared__ u16 As[128*32];
  __shared__ u16 Bs[128*32];
  const int tid = threadIdx.x;
  const int lane = tid & 63;
  const int wave = tid >> 6;
  const int wr = wave >> 1, wc = wave & 1;
  const int fr = lane & 15, fg = lane >> 4;
  const int bn = blockIdx.x * 128;
  const int srow = tid >> 2, skb = (tid & 3) ^ (srow & 3);

  f32x4_t acc[4][4] = {};

  const u16* A  = Hb  + (size_t)e * T_TOK * MDIM;
  const u16* ga0 = A + (size_t)(bm + srow) * MDIM + skb * 8;
  const u16* gB = WdT + (size_t)e*HID*MDIM + (size_t)(bn>>7)*131072 + tid*8;
  for (int kb = 0; kb < 32; kb++){
    gload16(ga0 + kb*32, &As[tid*8]);
    gload16(ga0 + (size_t)64*MDIM + kb*32, &As[2048 + tid*8]);
    gload16(gB + (size_t)kb*4096,        &Bs[tid*8]);
    gload16(gB + (size_t)kb*4096 + 2048, &Bs[2048 + tid*8]);
    __syncthreads();
    bf16x8_t af[4], bfv[4];
    #pragma unroll
    for (int i = 0; i < 4; i++) af[i]  = ldfsw64(As, wr*64 + i*16 + fr, fg*8);
    #pragma unroll
    for (int i = 0; i < 4; i++) bfv[i] = *(const bf16x8_t*)&Bs[((wc*4 + i)*64 + fr*4 + fg)*8];
    #pragma unroll
    for (int mi = 0; mi < 4; mi++)
      #pragma unroll
      for (int ni = 0; ni < 4; ni++)
        acc[mi][ni] = mfma16(af[mi], bfv[ni], acc[mi][ni]);
    __syncthreads();
  }

  #pragma unroll
  for (int mi = 0; mi < 4; mi++)
    #pragma unroll
    for (int r = 0; r < 4; r++){
      int pos = bm + wr*64 + mi*16 + fg*4 + r;
      int tok = tok_list[e*T_TOK + pos];
      #pragma unroll
      for (int ni = 0; ni < 4; ni++){
        int col = bn + wc*64 + ni*16 + fr;
        atomicAdd(&Out[(size_t)tok * HID + col], acc[mi][ni][r]);
      }
    }
}

// ---------- launch ----------
// Workspace plan (peak ~209 MB):
//   R0  96MB: Wq/Wk/Wv/Wo frag-linear splits -> (after O-proj) WgT/WuT/WdT (frag-linear)
//   R1  24MB: xn1..3 -> vt1..3 (per-head frag-linear) -> ynb(8MB)+yn(16MB f32)
//   R2  24MB: q1..3 (per-head frag-linear) -> hb[0..24MB)
//   R3  24MB: k1..3 (per-head frag-linear) -> hb[24..32MB)
//   R4  16MB: vf(f32) -> x1(f32, lives to end)
//   R5  24MB: ao1..3 (standard frag-linear, written by fattn)
//   RS: tok_list/w_list/cur/cnt_pad/rope tables

extern "C" void kernel_launch(void* const* d_in, const int* in_sizes, int n_in,
                              void* d_out, int out_size, void* d_ws, size_t ws_size,
                              hipStream_t stream)
{
  const float* hs     = (const float*)d_in[0];
  const float* w_attn = (const float*)d_in[1];
  const float* Wq = (const float*)d_in[2];
  const float* Wk = (const float*)d_in[3];
  const float* Wv = (const float*)d_in[4];
  const float* Wo = (const float*)d_in[5];
  const float* w_moe = (const float*)d_in[6];
  const float* Wr = (const float*)d_in[7];
  const float* Wg = (const float*)d_in[8];
  const float* Wu = (const float*)d_in[9];
  const float* Wd = (const float*)d_in[10];
  float* out = (float*)d_out;
  (void)in_sizes; (void)n_in; (void)out_size; (void)ws_size;

  char* ws = (char*)d_ws;
  const size_t MB = 1024*1024;
  char* R0 = ws;                 // 96 MB
  char* R1 = ws + 96*MB;         // 24 MB
  char* R2 = ws + 120*MB;        // 24 MB
  char* R3 = ws + 144*MB;        // 24 MB
  char* R4 = ws + 168*MB;        // 16 MB
  char* R5 = ws + 184*MB;        // 24 MB
  char* RS = ws + 208*MB;        // small buffers

  const size_t WSLB = (size_t)HID*HID;   // 8 MB slabs
  u16* W0 = (u16*)R0;
  u16 *Wq1 = W0,          *Wq2 = W0 + WSLB,    *Wq3 = W0 + 2*WSLB;
  u16 *Wk1 = W0 + 3*WSLB, *Wk2 = W0 + 4*WSLB,  *Wk3 = W0 + 5*WSLB;
  u16 *Wv1 = W0 + 6*WSLB, *Wv2 = W0 + 7*WSLB,  *Wv3 = W0 + 8*WSLB;
  u16 *Wo1 = W0 + 9*WSLB, *Wo2 = W0 + 10*WSLB, *Wo3 = W0 + 11*WSLB;
  const size_t TSLB = (size_t)T_TOK*HID;
  u16 *xn1 = (u16*)R1, *xn2 = (u16*)R1 + TSLB, *xn3 = (u16*)R1 + 2*TSLB;
  u16 *q1  = (u16*)R2, *q2  = (u16*)R2 + TSLB, *q3  = (u16*)R2 + 2*TSLB;
  u16 *k1  = (u16*)R3, *k2  = (u16*)R3 + TSLB, *k3  = (u16*)R3 + 2*TSLB;
  u16 *vt1 = xn1, *vt2 = xn2, *vt3 = xn3;        // reuse R1 after xn dead
  float* vf  = (float*)R4;
  float* x1  = (float*)R4;                        // reuse after vtrans/fattn
  u16 *ao1 = (u16*)R5, *ao2 = (u16*)R5 + TSLB, *ao3 = (u16*)R5 + 2*TSLB;
  // phase B pointers (MoE)
  u16* WgT = (u16*)R0;
  u16* WuT = (u16*)R0 + (size_t)NEXP*MDIM*HID;
  u16* WdT = (u16*)R0 + 2*(size_t)NEXP*MDIM*HID;
  u16* ynb = (u16*)R1;
  float* yn = (float*)(R1 + 8*MB);
  u16* hb  = (u16*)R2;                            // 32 MB spans R2 + first 8MB of R3
  int*   tok_list = (int*)RS;
  float* w_list   = (float*)(RS + 64*1024);
  int*   cur      = (int*)(RS + 128*1024);
  int*   cnt_pad  = (int*)(RS + 132*1024);
  float* ct   = (float*)(RS + 256*1024);
  float* stab = (float*)(RS + 384*1024);

  dim3 blk256(256), gMoE(16,16,8);

  rope_table_k<<<dim3(SEQ*32/256), blk256, 0, stream>>>(ct, stab);
  convT3<<<dim3(HID/64, HID/64), blk256, 0, stream>>>(Wq, Wq1, Wq2, Wq3);
  convT3<<<dim3(HID/64, HID/64), blk256, 0, stream>>>(Wk, Wk1, Wk2, Wk3);
  convT3<<<dim3(HID/64, HID/64), blk256, 0, stream>>>(Wv, Wv1, Wv2, Wv3);
  convT3<<<dim3(HID/64, HID/64), blk256, 0, stream>>>(Wo, Wo1, Wo2, Wo3);

  rmsnorm3_k<<<dim3(T_TOK), blk256, 0, stream>>>(hs, w_attn, xn1, xn2, xn3);

  gemm_qkv<<<dim3(16,16,3), blk256, 0, stream>>>(xn1,xn2,xn3,
      Wq1,Wq2,Wq3, Wk1,Wk2,Wk3, Wv1,Wv2,Wv3,
      q1,q2,q3, k1,k2,k3, vf, ct, stab);

  vtrans3_k<<<dim3(SEQ/64, BATCH*NHEAD), blk256, 0, stream>>>(vf, vt1, vt2, vt3);   // xn dead

  fattn3_k<<<dim3(BATCH*NHEAD, SEQ/64), blk256, 0, stream>>>(q1,q2,q3, k1,k2,k3,
      vt1,vt2,vt3, ao1,ao2,ao3);   // vf dead

  gemm_o<<<dim3(32,16), blk256, 0, stream>>>(ao1,ao2,ao3, Wo1,Wo2,Wo3, x1, hs);

  // attention weights dead -> convert MoE weights (frag-linear) into R0
  convT_fl<<<dim3(MDIM/64, HID/64, NEXP), blk256, 0, stream>>>(Wg, WgT, MDIM, HID);
  convT_fl<<<dim3(MDIM/64, HID/64, NEXP), blk256, 0, stream>>>(Wu, WuT, MDIM, HID);
  convT_fl<<<dim3(HID/64, MDIM/64, NEXP), blk256, 0, stream>>>(Wd, WdT, HID, MDIM);

  rmsnorm_k<<<dim3(T_TOK), blk256, 0, stream>>>(x1, w_moe, ynb, yn, out);   // vt dead

  hipMemsetAsync(cur, 0, NEXP*sizeof(int), stream);
  router_scatter_k<<<dim3(T_TOK), dim3(64), 0, stream>>>(yn, Wr, tok_list, w_list, cur);
  pad_k<<<dim3(NEXP), dim3(128), 0, stream>>>(cur, tok_list, w_list, cnt_pad);

  gemm_gateup_sp<<<gMoE, blk256, 0, stream>>>(ynb, WgT, WuT, tok_list, w_list, cnt_pad, hb);  // q dead
  gemm_down_sp<<<gMoE, blk256, 0, stream>>>(hb, WdT, tok_list, cnt_pad, out);
}